// Round 6
// baseline (453.203 us; speedup 1.0000x reference)
//
#include <hip/hip_runtime.h>
#include <math.h>

// ---------------- constants ----------------
#define N_NODES 20000
#define NPAD    20096          // 157*128
#define N_EDGES 200000
#define N_PAIRS 10000
#define PAIR_PAD 10368         // 162*64
#define DM_TILES 162
#define NBLK    79             // 79*256 = 20224 >= N_NODES

typedef __attribute__((ext_vector_type(8))) short s16x8;
typedef __attribute__((ext_vector_type(4))) float f32x4;

__device__ inline float wave_max(float v){
  for (int o = 32; o > 0; o >>= 1) v = fmaxf(v, __shfl_xor(v, o));
  return v;
}
__device__ inline float wave_sum(float v){
  for (int o = 32; o > 0; o >>= 1) v += __shfl_xor(v, o);
  return v;
}
__device__ inline float half_max(float v){
  for (int o = 16; o > 0; o >>= 1) v = fmaxf(v, __shfl_xor(v, o));
  return v;
}
__device__ inline float half_sum(float v){
  for (int o = 16; o > 0; o >>= 1) v += __shfl_xor(v, o);
  return v;
}
__device__ inline short f2bf(float x){
  union { float f; unsigned u; } v; v.f = x;
  unsigned r = (v.u + 0x7FFFu + ((v.u >> 16) & 1u)) >> 16;
  return (short)r;
}
__device__ inline float bf2f(short s){
  union { unsigned u; float f; } v; v.u = ((unsigned)(unsigned short)s) << 16;
  return v.f;
}
__device__ inline int ntype(int s){ return (s < 8000) ? 0 : ((s < 14000) ? 1 : 2); }
__device__ inline float elu1(float x){ return (x > 0.f) ? x : expm1f(x); }

// mean/norm buffer slot: chunk-in-head c24 (0..23), elem i (0..7); stride 9 -> conflict-free
#define MB(c24, i) ((c24) * 9 + (i))

// ---------------- input linears (8 nodes/block) + ALL workspace zeroing + o_b slice 0 ----------------
__global__ void build_h(const float* __restrict__ f0, const float* __restrict__ w0, const float* __restrict__ b0,
                        const float* __restrict__ f1, const float* __restrict__ w1, const float* __restrict__ b1,
                        const float* __restrict__ f2, const float* __restrict__ w2, const float* __restrict__ b2,
                        short* __restrict__ Xb0, short* __restrict__ o_b,
                        int* __restrict__ cnt3, int* __restrict__ cnt5, int* __restrict__ pos5,
                        float* __restrict__ score, int* __restrict__ pairs,
                        float* __restrict__ eall, short* __restrict__ Xb12,
                        short* __restrict__ featb){
  const int blk = blockIdx.x, lane = threadIdx.x;
  const int gid = blk * 64 + lane;             // 0..159999
  // ---- zeroing (spread across grid) ----
  if (gid < 80000) cnt3[gid] = 0;
  if (gid < 5){ cnt5[gid * 16] = 0; pos5[gid * 16] = 0; }
  if (gid < 10016) score[gid] = 0.f;
  if (gid < PAIR_PAD) pairs[gid] = -1;
  for (int i = gid; i < 480000; i += 160000) eall[i] = 0.f;
  s16x8 z = {};
  if (gid < 4608){  // Xb12 pad rows: 3 * 96 * 256 shorts
    int t = (gid * 16) / 24576, off = (gid * 16) % 24576;
    short* p = Xb12 + ((size_t)(t * NPAD + N_NODES)) * 256 + off;
    *(s16x8*)p = z; *(s16x8*)(p + 8) = z;
  }
  if (gid < 1152){  // Xb0 pad rows
    int t = (gid * 16) / 6144, off = (gid * 16) % 6144;
    short* p = Xb0 + ((size_t)(t * NPAD + N_NODES)) * 64 + off;
    *(s16x8*)p = z; *(s16x8*)(p + 8) = z;
  }
  // ---- per-block type ----
  int t, C, nbase; const float *f, *w, *b;
  if (blk < 1000)       { t = 0; nbase = 0;     C = 256; f = f0; w = w0; b = b0; }
  else if (blk < 1750)  { t = 1; nbase = 8000;  C = 128; f = f1; w = w1; b = b1; }
  else                  { t = 2; nbase = 14000; C = 64;  f = f2; w = w2; b = b2; }
  const int n0 = blk * 8;
  const int n0l = n0 - nbase;
  __shared__ float xs[8 * 256];
  const float* fr = f + (size_t)n0l * C;
  for (int i = lane; i < 8 * C; i += 64) xs[i] = fr[i];
  __syncthreads();
  float acc[8];
#pragma unroll
  for (int j = 0; j < 8; j++) acc[j] = b[lane];
  for (int c = 0; c < C; c++){
    float wv = w[c * 64 + lane];
#pragma unroll
    for (int j = 0; j < 8; j++) acc[j] += xs[j * C + c] * wv;
  }
  for (int j = 0; j < 8; j++){
    int n = n0 + j;
    // off-slot feat_b zero (layer-0 typed proj skips those tiles; cnt>64 fallback reads full rows)
    {
      int h = lane >> 4, si = (lane >> 3) & 1, j8 = lane & 7;
      int s0 = (t == 0) ? 1 : 0;
      int s1 = (t == 2) ? 1 : 2;
      int toff = si ? s1 : s0;
      *(s16x8*)(featb + ((size_t)n * 4 + h) * 192 + toff * 64 + j8 * 8) = z;
    }
    for (int tt = 0; tt < 3; tt++)
      Xb0[((size_t)(tt * NPAD) + n) * 64 + lane] = f2bf((tt == t) ? acc[j] : 0.f);
    float ss = wave_sum(acc[j] * acc[j]);
    float sc = 1.f / fmaxf(sqrtf(ss), 1e-12f);
    for (int tt = 0; tt < 3; tt++)
      o_b[(size_t)n * 768 + tt * 256 + lane] = f2bf((tt == t) ? acc[j] * sc : 0.f);
  }
}

// ---------------- merged: typed edge/pair counting (blocks 0..781) + weight prep ----------------
__global__ void count_prep_k(const int* __restrict__ dst, const int* __restrict__ srcv,
                             int* __restrict__ cnt3,
                             const int* __restrict__ mid, int* __restrict__ cnt5,
                             const float* __restrict__ lW0, const float* __restrict__ lW1,
                             const float* __restrict__ lW2, const float* __restrict__ dmW,
                             short* __restrict__ Wt0, short* __restrict__ Wt1,
                             short* __restrict__ Wt2, short* __restrict__ Mt,
                             const float* __restrict__ ee0, const float* __restrict__ we0, const float* __restrict__ ae0,
                             const float* __restrict__ ee1, const float* __restrict__ we1, const float* __restrict__ ae1,
                             const float* __restrict__ ee2, const float* __restrict__ we2, const float* __restrict__ ae2,
                             float* __restrict__ ee5f){
  if (blockIdx.x < 782){
    int e = blockIdx.x * 256 + threadIdx.x;
    int lane = threadIdx.x & 63;
    if (e < N_EDGES){
      int tt = ntype(srcv[e]);
      atomicAdd(&cnt3[dst[e] * 4 + tt], 1);
    }
    int r_mine = (e < N_PAIRS) ? mid[e] : -1;
#pragma unroll
    for (int r = 0; r < 5; r++){
      unsigned long long mask = __ballot(r_mine == r);
      if (mask){
        int leader = __ffsll((long long)mask) - 1;
        if (lane == leader) atomicAdd(&cnt5[r * 16], __popcll(mask));
      }
    }
    return;
  }
  int lin = blockIdx.x - 782;
  int z = lin / 576;
  int rem = lin % 576;
  int by = rem / 24, bx = rem % 24;
  if (z == 10){
    int r = bx, L = by;
    if (r >= 5 || L >= 3) return;
    int H = (L == 2) ? 1 : 4;
    const float* eetab = (L == 0) ? ee0 : ((L == 1) ? ee1 : ee2);
    const float* We    = (L == 0) ? we0 : ((L == 1) ? we1 : we2);
    const float* ae    = (L == 0) ? ae0 : ((L == 1) ? ae1 : ae2);
    int h = threadIdx.x >> 6, lane = threadIdx.x & 63;
    if (h >= H) return;
    float v = 0.f;
    for (int k = 0; k < 64; k++) v += eetab[r * 64 + k] * We[k * H * 64 + h * 64 + lane];
    v *= ae[h * 64 + lane];
    v = wave_sum(v);
    if (lane == 0) ee5f[L * 32 + r * H + h] = v;
    return;
  }
  const float* s; short* d; int R, Cc, r0, c0;
  if (z < 5){
    s = dmW + (size_t)z * 589824; d = Mt + (size_t)z * 589824;
    R = 768; Cc = 768; r0 = bx * 32; c0 = by * 32;
  } else if (z < 8){
    if (bx >= 8 || by >= 8) return;
    int t = z - 5;
    s = lW1 + (size_t)t * 65536; d = Wt1 + (size_t)t * 65536;
    R = 256; Cc = 256; r0 = bx * 32; c0 = by * 32;
  } else if (z == 8){
    if (bx >= 6 || by >= 8) return;
    int t = bx >> 1;
    s = lW0 + (size_t)t * 16384; d = Wt0 + (size_t)t * 16384;
    R = 64; Cc = 256; r0 = (bx & 1) * 32; c0 = by * 32;
  } else {
    if (bx >= 8 || by >= 6) return;
    int t = by >> 1;
    s = lW2 + (size_t)t * 16384; d = Wt2 + (size_t)t * 16384;
    R = 256; Cc = 64; r0 = bx * 32; c0 = (by & 1) * 32;
  }
  __shared__ float tile[32][33];
  int tx = threadIdx.x & 31, ty = threadIdx.x >> 5;
  for (int i = 0; i < 32; i += 8){
    int r = r0 + ty + i;
    tile[ty + i][tx] = (r < R && c0 + tx < Cc) ? s[(size_t)r * Cc + c0 + tx] : 0.f;
  }
  __syncthreads();
  for (int i = 0; i < 32; i += 8){
    int c = c0 + ty + i;
    if (c < Cc && r0 + tx < R)
      d[(size_t)c * R + r0 + tx] = f2bf(tile[tx][ty + i]);
  }
}

// ---------------- hierarchical scan ----------------
__global__ void scan1_k(const int* __restrict__ cnt3, int* __restrict__ loc, int* __restrict__ bsum){
  __shared__ int s[256];
  int tid = threadIdx.x;
  int idx = blockIdx.x * 256 + tid;
  int v = (idx < N_NODES) ? (cnt3[idx * 4] + cnt3[idx * 4 + 1] + cnt3[idx * 4 + 2]) : 0;
  s[tid] = v;
  __syncthreads();
  for (int o = 1; o < 256; o <<= 1){
    int u = (tid >= o) ? s[tid - o] : 0;
    __syncthreads();
    s[tid] += u;
    __syncthreads();
  }
  if (idx < N_NODES) loc[idx] = s[tid] - v;
  if (tid == 255) bsum[blockIdx.x] = s[255];
}

__global__ void scan2_k(const int* __restrict__ bsum, int* __restrict__ bofs,
                        const int* __restrict__ cnt5, int* __restrict__ off5){
  __shared__ int s[128];
  int tid = threadIdx.x;
  int v = (tid < NBLK) ? bsum[tid] : 0;
  s[tid] = v;
  __syncthreads();
  for (int o = 1; o < 128; o <<= 1){
    int u = (tid >= o) ? s[tid - o] : 0;
    __syncthreads();
    s[tid] += u;
    __syncthreads();
  }
  if (tid < NBLK) bofs[tid] = s[tid] - v;
  if (tid == 0){
    int r0 = 0;
    for (int r = 0; r < 5; r++){ off5[r] = r0; r0 += ((cnt5[r * 16] + 63) >> 6) << 6; }
  }
}

__global__ void scan3_k(const int* __restrict__ loc, const int* __restrict__ bofs,
                        int* __restrict__ coff, int* __restrict__ cpos,
                        const int* __restrict__ cnt3){
  int idx = blockIdx.x * 256 + threadIdx.x;
  if (idx < N_NODES){
    int v = loc[idx] + bofs[blockIdx.x];
    coff[idx] = v;
    int c0 = cnt3[idx * 4], c1 = cnt3[idx * 4 + 1];
    cpos[idx * 4]     = v;
    cpos[idx * 4 + 1] = v + c0;
    cpos[idx * 4 + 2] = v + c0 + c1;
  }
  if (idx == 0) coff[N_NODES] = N_EDGES;
}

__global__ void scatter_k(const int* __restrict__ dst, const int* __restrict__ srcv,
                          const int* __restrict__ efeat, int* __restrict__ cpos,
                          int* __restrict__ src_sorted, int* __restrict__ et_sorted,
                          const int* __restrict__ mid, const int* __restrict__ off5,
                          int* __restrict__ pos5, int* __restrict__ pairs){
  int e = blockIdx.x * 256 + threadIdx.x;
  int lane = threadIdx.x & 63;
  if (e < N_EDGES){
    int s = srcv[e];
    int tt = ntype(s);
    int p = atomicAdd(&cpos[dst[e] * 4 + tt], 1);
    src_sorted[p] = s;
    et_sorted[p] = efeat[e];
  }
  int r_mine = (e < N_PAIRS) ? mid[e] : -1;
#pragma unroll
  for (int r = 0; r < 5; r++){
    unsigned long long mask = __ballot(r_mine == r);
    if (mask){
      int cnt = __popcll(mask);
      int leader = __ffsll((long long)mask) - 1;
      int base = 0;
      if (lane == leader) base = atomicAdd(&pos5[r * 16], cnt);
      base = __shfl(base, leader);
      if (r_mine == r){
        int rank = __popcll(mask & ((1ull << lane) - 1ull));
        pairs[off5[r] + base + rank] = e;
      }
    }
  }
}

// ---------------- MFMA slot projection -> bf16 feat + fused el/er partials ----------------
// One ct per block (36 VGPR, high occupancy). The (tile, ct) encoding in blockIdx.x puts all
// 4 ct-instances of a tile at the SAME residue mod 8 -> same XCD -> A tile hits L2 3 of 4 times.
// LDS rows padded to 40 shorts (80 B) to spread banks on b128 reads/writes.
#define LDA 40
template<int C, int NO, int TYPED>
__global__ void mfma_proj(const short* __restrict__ Xb, const short* __restrict__ Wt,
                          short* __restrict__ featb, const float* __restrict__ al,
                          const float* __restrict__ ar, float* __restrict__ elf,
                          float* __restrict__ erf){
  constexpr int H = NO / 64;
  const int t = blockIdx.z;
  int tile, ct;
  if constexpr (H == 4){
    const int x = blockIdx.x;            // grp*32 + ct*8 + slot
    const int grp = x >> 5, sub = x & 31;
    ct = sub >> 3;
    tile = grp * 8 + (sub & 7);
  } else { tile = blockIdx.x; ct = 0; }
  if constexpr (TYPED){
    const int lo[3] = {0, 62, 109};
    const int hi[3] = {63, 110, 157};
    if (tile >= hi[t] - lo[t]) return;
    tile += lo[t];
  } else {
    if (tile >= NPAD / 128) return;
  }
  const int n0 = tile * 128;
  const int tid = threadIdx.x;
  const int w = tid >> 6, lane = tid & 63;
  const int quad = lane >> 4, ln = lane & 15;
  __shared__ __attribute__((aligned(16))) short A_s[128 * LDA];
  __shared__ __attribute__((aligned(16))) short B_s[64 * LDA];
  const short* Xt  = Xb + (size_t)t * NPAD * C;
  const short* Wtt = Wt + ((size_t)t * NO + ct * 64) * C;
  f32x4 acc[2][4] = {};
  for (int kk = 0; kk < C; kk += 32){
    {
      int row = tid >> 1, hk = tid & 1;
      const s16x8* g = (const s16x8*)(Xt + (size_t)(n0 + row) * C + kk + hk * 16);
      s16x8 v0 = g[0], v1 = g[1];
      *(s16x8*)(A_s + row * LDA + hk * 16) = v0;
      *(s16x8*)(A_s + row * LDA + hk * 16 + 8) = v1;
    }
    {
      int row = tid >> 2, chunk = tid & 3;
      s16x8 v = *(const s16x8*)(Wtt + (size_t)row * C + kk + chunk * 8);
      *(s16x8*)(B_s + row * LDA + chunk * 8) = v;
    }
    __syncthreads();
    s16x8 af0 = *(s16x8*)(A_s + (w * 32 + ln) * LDA + quad * 8);
    s16x8 af1 = *(s16x8*)(A_s + (w * 32 + 16 + ln) * LDA + quad * 8);
    s16x8 bf[4];
#pragma unroll
    for (int b = 0; b < 4; b++) bf[b] = *(s16x8*)(B_s + (b * 16 + ln) * LDA + quad * 8);
#pragma unroll
    for (int b = 0; b < 4; b++){
      acc[0][b] = __builtin_amdgcn_mfma_f32_16x16x32_bf16(af0, bf[b], acc[0][b], 0, 0, 0);
      acc[1][b] = __builtin_amdgcn_mfma_f32_16x16x32_bf16(af1, bf[b], acc[1][b], 0, 0, 0);
    }
    __syncthreads();
  }
#pragma unroll
  for (int ar_ = 0; ar_ < 2; ar_++){
#pragma unroll
    for (int i = 0; i < 4; i++){
      int n = n0 + w * 32 + ar_ * 16 + quad * 4 + i;
      if (n >= N_NODES) continue;
#pragma unroll
      for (int b = 0; b < 4; b++){
        int jj = b * 16 + ln;
        featb[((size_t)n * H + ct) * 192 + t * 64 + jj] = f2bf(acc[ar_][b][i]);
      }
    }
  }
  float alv[4], arv[4];
#pragma unroll
  for (int b = 0; b < 4; b++){
    alv[b] = al[ct * 192 + t * 64 + b * 16 + ln];
    arv[b] = ar[ct * 192 + t * 64 + b * 16 + ln];
  }
#pragma unroll
  for (int ar_ = 0; ar_ < 2; ar_++){
#pragma unroll
    for (int i = 0; i < 4; i++){
      float pe = 0.f, pr = 0.f;
#pragma unroll
      for (int b = 0; b < 4; b++){
        pe += acc[ar_][b][i] * alv[b];
        pr += acc[ar_][b][i] * arv[b];
      }
#pragma unroll
      for (int o = 1; o < 16; o <<= 1){
        pe += __shfl_xor(pe, o);
        pr += __shfl_xor(pr, o);
      }
      int n = n0 + w * 32 + ar_ * 16 + quad * 4 + i;
      if (ln == 0 && n < N_NODES){
        atomicAdd(&elf[n * H + ct], pe);
        atomicAdd(&erf[n * H + ct], pr);
      }
    }
  }
}

// ---------------- fused softmax + gather aggregation + emb: 2 nodes per wave ----------------
// No out_s staging: outb stored directly from registers; per-slot l2-norm goes through a
// tiny mean buffer mb (24 chunk-positions x 9-stride) filled via wave-ordered h-rounds.
template<int H, int MODE, int ACT, int TYPED>
__global__ __launch_bounds__(256) void gat_fused(
    const int* __restrict__ csr_off, const int* __restrict__ src_sorted,
    const int* __restrict__ et_sorted,
    const float* __restrict__ el, const float* __restrict__ er, const float* __restrict__ ee5,
    const float* __restrict__ aprev, float* __restrict__ aout,
    const short* __restrict__ featb, short* __restrict__ outb,
    short* __restrict__ o_b, const int* __restrict__ cnt3, int kslice){
  const int wid = threadIdx.x >> 6, lane = threadIdx.x & 63;
  const int half = lane >> 5, hl = lane & 31;
  const int l32 = half << 5;
  const int n0 = blockIdx.x * 8 + wid * 2;        // wave owns nodes n0, n0+1; grid exact
  const int nme = n0 + half;                      // this half-wave's node
  __shared__ float a_s[4][64][H];
  __shared__ int   src_s[4][64];                  // pre-multiplied BYTE offsets into featb
  __shared__ float mb[4][2][216];                 // head-sum buffer, MB(c24,i) layout
  const char* fb = (const char*)featb;

  const int offm = csr_off[nme];
  const int cntm = csr_off[nme + 1] - offm;
  const int cnto = __shfl_xor(cntm, 32);
  const bool paired = (cntm <= 32) && (cnto <= 32);

  if (paired){
    // ---- softmax: edge e of node nme at lane l32+e ----
    float ern[H];
    if constexpr (H == 4){
      f32x4 ev = *(const f32x4*)(er + nme * 4);
#pragma unroll
      for (int h = 0; h < 4; h++) ern[h] = ev[h];
    } else ern[0] = er[nme];
    const int p = offm + hl;
    const bool valid = hl < cntm;
    int sidx = 0, r = 0;
    if (valid){ sidx = src_sorted[p]; r = et_sorted[p]; }
    int s0 = __shfl(sidx, l32);
    src_s[wid][lane] = (valid ? sidx : s0) * (H * 384);
    float lg[H];
#pragma unroll
    for (int h = 0; h < H; h++) lg[h] = -1e30f;
    if (valid){
      if constexpr (H == 4){
        f32x4 elv = *(const f32x4*)(el + sidx * 4);
        f32x4 eev = *(const f32x4*)(ee5 + r * 4);
#pragma unroll
        for (int h = 0; h < 4; h++){
          float v = elv[h] + ern[h] + eev[h];
          lg[h] = (v >= 0.f) ? v : 0.2f * v;
        }
      } else {
        float v = el[sidx] + ern[0] + ee5[r];
        lg[0] = (v >= 0.f) ? v : 0.2f * v;
      }
    }
    float ap[4] = {};
    if (MODE > 0 && valid){
      f32x4 av4 = *(const f32x4*)(aprev + (size_t)p * 4);
#pragma unroll
      for (int q = 0; q < 4; q++) ap[q] = av4[q];
    }
    float av[H];
#pragma unroll
    for (int h = 0; h < H; h++){
      float mh = half_max(lg[h]);
      float ex = valid ? __expf(lg[h] - mh) : 0.f;
      float sh = half_sum(ex);
      float a = ex / sh;
      if (MODE == 1) a = 0.95f * a + 0.05f * ap[h];
      if (MODE == 2) a = 0.95f * a + 0.0125f * (ap[0] + ap[1] + ap[2] + ap[3]);
      av[h] = a;
      a_s[wid][lane][h] = valid ? a : 0.f;
    }
    if constexpr (MODE != 2){
      if (valid){
        f32x4 o = {av[0], av[1], av[2], av[3]};
        *(f32x4*)(aout + (size_t)p * 4) = o;
      }
    }

    if constexpr (TYPED && H == 4){
      // ---- layer 0: slot-sparse rows; 32 live chunks = 1/lane, 2 edges/iter ----
      const int hh = hl >> 3, j8 = hl & 7;
      float acc[3][8] = {};
      const int b1 = cnt3[nme * 4], b2 = b1 + cnt3[nme * 4 + 1];
      const int rb[4] = {0, b1, b2, cntm};
#pragma unroll
      for (int t = 0; t < 3; t++){
        const int sub = hh * 384 + t * 128 + j8 * 16;
        for (int b = rb[t]; b < rb[t + 1]; b += 2){
          int e0 = l32 + b;
          bool v1 = (b + 1) < rb[t + 1];
          int e1 = v1 ? e0 + 1 : e0;
          float a0 = a_s[wid][e0][hh];
          float a1 = v1 ? a_s[wid][e1][hh] : 0.f;
          int so0 = src_s[wid][e0], so1 = src_s[wid][e1];
          s16x8 f0 = *(const s16x8*)(fb + so0 + sub);
          s16x8 f1 = *(const s16x8*)(fb + so1 + sub);
#pragma unroll
          for (int i = 0; i < 8; i++) acc[t][i] += a0 * bf2f(f0[i]) + a1 * bf2f(f1[i]);
        }
      }
#pragma unroll
      for (int t = 0; t < 3; t++){
        if (ACT){
#pragma unroll
          for (int i = 0; i < 8; i++) acc[t][i] = elu1(acc[t][i]);
        }
        if (outb){
          s16x8 o;
#pragma unroll
          for (int i = 0; i < 8; i++) o[i] = f2bf(acc[t][i]);
          *(s16x8*)(outb + ((size_t)(t * NPAD) + nme) * 256 + hh * 64 + j8 * 8) = o;
        }
      }
      // mean rounds by head (chunk c = hh*24 + t*8 + j8 -> c24 = t*8 + j8)
#pragma unroll
      for (int rr = 0; rr < 4; rr++){
        if (hh == rr){
#pragma unroll
          for (int t = 0; t < 3; t++)
#pragma unroll
            for (int i = 0; i < 8; i++){
              if (rr == 0) mb[wid][half][MB(t * 8 + j8, i)] = acc[t][i];
              else         mb[wid][half][MB(t * 8 + j8, i)] += acc[t][i];
            }
        }
      }
    } else if constexpr (H == 4){
      // ---- dense rows: 96 chunks / 32 lanes = 3/lane, 2 edges/iter ----
      const int p0 = hl, p1 = hl + 32, p2 = hl + 64;
      const int h0 = p0 / 24, h1 = p1 / 24, h2 = p2 / 24;
      float acc0[8] = {}, acc1[8] = {}, acc2[8] = {};
      const int cnt2 = (cntm + 1) & ~1;
      for (int b = 0; b < cnt2; b += 2){
        int e0 = l32 + b, e1 = l32 + b + 1;      // pads: a_s==0, src_s valid
        int so0 = src_s[wid][e0], so1 = src_s[wid][e1];
        float a00 = a_s[wid][e0][h0], a01 = a_s[wid][e0][h1], a02 = a_s[wid][e0][h2];
        float a10 = a_s[wid][e1][h0], a11 = a_s[wid][e1][h1], a12 = a_s[wid][e1][h2];
        s16x8 f00 = *(const s16x8*)(fb + so0 + p0 * 16);
        s16x8 f01 = *(const s16x8*)(fb + so0 + p1 * 16);
        s16x8 f02 = *(const s16x8*)(fb + so0 + p2 * 16);
        s16x8 f10 = *(const s16x8*)(fb + so1 + p0 * 16);
        s16x8 f11 = *(const s16x8*)(fb + so1 + p1 * 16);
        s16x8 f12 = *(const s16x8*)(fb + so1 + p2 * 16);
#pragma unroll
        for (int i = 0; i < 8; i++){
          acc0[i] += a00 * bf2f(f00[i]) + a10 * bf2f(f10[i]);
          acc1[i] += a01 * bf2f(f01[i]) + a11 * bf2f(f11[i]);
          acc2[i] += a02 * bf2f(f02[i]) + a12 * bf2f(f12[i]);
        }
      }
      if (ACT){
#pragma unroll
        for (int i = 0; i < 8; i++){
          acc0[i] = elu1(acc0[i]); acc1[i] = elu1(acc1[i]); acc2[i] = elu1(acc2[i]);
        }
      }
      if (outb){
#pragma unroll
        for (int cc = 0; cc < 3; cc++){
          int c = hl + cc * 32;
          const float* vv = (cc == 0) ? acc0 : ((cc == 1) ? acc1 : acc2);
          int h = c / 24, rm = c % 24, t = rm >> 3, j = (rm & 7) * 8;
          s16x8 o;
#pragma unroll
          for (int i = 0; i < 8; i++) o[i] = f2bf(vv[i]);
          *(s16x8*)(outb + ((size_t)(t * NPAD) + nme) * 256 + h * 64 + j) = o;
        }
      }
      // mean rounds by head
      float* mbh = mb[wid][half];
      if (hl < 24){
#pragma unroll
        for (int i = 0; i < 8; i++) mbh[MB(hl, i)] = acc0[i];
      }
      if (hl >= 24){
#pragma unroll
        for (int i = 0; i < 8; i++) mbh[MB(hl - 24, i)] += acc0[i];
      } else if (hl < 16){
#pragma unroll
        for (int i = 0; i < 8; i++) mbh[MB(hl + 8, i)] += acc1[i];
      }
      if (hl >= 16){
#pragma unroll
        for (int i = 0; i < 8; i++) mbh[MB(hl - 16, i)] += acc1[i];
      } else if (hl < 8){
#pragma unroll
        for (int i = 0; i < 8; i++) mbh[MB(hl + 16, i)] += acc2[i];
      }
      if (hl >= 8){
#pragma unroll
        for (int i = 0; i < 8; i++) mbh[MB(hl - 8, i)] += acc2[i];
      }
    } else {
      // ---- H == 1: 4 edges/iter x 3 chunks/lane, 2-step combine ----
      const int e4 = hl >> 3, cb = hl & 7;
      float acc[3][8] = {};
      for (int b = 0; b < cntm; b += 4){
        int e = l32 + b + e4;                    // b+e4 <= 31; pads a_s==0
        float a = a_s[wid][e][0];
        int so = src_s[wid][e];
#pragma unroll
        for (int c = 0; c < 3; c++){
          s16x8 fv = *(const s16x8*)(fb + so + (cb * 3 + c) * 16);
#pragma unroll
          for (int i = 0; i < 8; i++) acc[c][i] += a * bf2f(fv[i]);
        }
      }
#pragma unroll
      for (int c = 0; c < 3; c++){
#pragma unroll
        for (int i = 0; i < 8; i++){
          float v = acc[c][i];
          v += __shfl_xor(v, 8); v += __shfl_xor(v, 16);
          if (ACT) v = elu1(v);
          if (e4 == 0) mb[wid][half][MB(cb * 3 + c, i)] = v;
        }
      }
    }
  } else {
    // ---- rare fallback: process both nodes sequentially with the full wave ----
    for (int k = 0; k < 2; k++){
      const int n = n0 + k;
      const int off = csr_off[n];
      const int cnt = csr_off[n + 1] - off;
      float* mbk = mb[wid][k];
      float v0[8], v1[8];
      float ern[H];
#pragma unroll
      for (int h = 0; h < H; h++) ern[h] = er[n * H + h];
      if (cnt <= 64){
        int p = off + lane;
        int sidx = 0, r = 0;
        if (lane < cnt){ sidx = src_sorted[p]; r = et_sorted[p]; }
        int src0 = __shfl(sidx, 0);
        src_s[wid][lane] = ((lane < cnt) ? sidx : src0) * (H * 384);
        float lg[H];
#pragma unroll
        for (int h = 0; h < H; h++) lg[h] = -1e30f;
        if (lane < cnt){
#pragma unroll
          for (int h = 0; h < H; h++){
            float v = el[sidx * H + h] + ern[h] + ee5[r * H + h];
            lg[h] = (v >= 0.f) ? v : 0.2f * v;
          }
        }
        float ap[4] = {};
        if (MODE > 0 && lane < cnt){
#pragma unroll
          for (int q = 0; q < 4; q++) ap[q] = aprev[(size_t)p * 4 + q];
        }
        float av[H];
#pragma unroll
        for (int h = 0; h < H; h++){
          float mh = wave_max(lg[h]);
          float ex = (lane < cnt) ? __expf(lg[h] - mh) : 0.f;
          float sh = wave_sum(ex);
          float a = ex / sh;
          if (MODE == 1) a = 0.95f * a + 0.05f * ap[h];
          if (MODE == 2) a = 0.95f * a + 0.0125f * (ap[0] + ap[1] + ap[2] + ap[3]);
          av[h] = a;
          a_s[wid][lane][h] = (lane < cnt) ? a : 0.f;
        }
        if constexpr (MODE != 2){
          if (lane < cnt){
            f32x4 o = {av[0], av[1], av[2], av[3]};
            *(f32x4*)(aout + (size_t)p * 4) = o;
          }
        }
        if constexpr (H == 4){
          const int p0 = lane;
          const int p1 = (lane < 32) ? lane + 64 : lane - 32;
          const int p2 = lane + 32;
          const int hA = p0 / 24, hB = p1 / 24, hC = p2 / 24;
          const int eo2 = lane >> 5;
          float acc0[8] = {}, acc1[8] = {}, acc2[8] = {};
          const int cnt4 = (cnt + 3) & ~3;
          for (int b = 0; b < cnt4; b += 4){
            int eB0 = b + eo2, eB1 = b + 2 + eo2;
            int oA0 = src_s[wid][b],     oB0 = src_s[wid][eB0], oC0 = src_s[wid][b + 1];
            int oA1 = src_s[wid][b + 2], oB1 = src_s[wid][eB1], oC1 = src_s[wid][b + 3];
            float aA0 = a_s[wid][b][hA],     aB0 = a_s[wid][eB0][hB], aC0 = a_s[wid][b + 1][hC];
            float aA1 = a_s[wid][b + 2][hA], aB1 = a_s[wid][eB1][hB], aC1 = a_s[wid][b + 3][hC];
            s16x8 fA0 = *(const s16x8*)(fb + oA0 + p0 * 16);
            s16x8 fB0 = *(const s16x8*)(fb + oB0 + p1 * 16);
            s16x8 fC0 = *(const s16x8*)(fb + oC0 + p2 * 16);
            s16x8 fA1 = *(const s16x8*)(fb + oA1 + p0 * 16);
            s16x8 fB1 = *(const s16x8*)(fb + oB1 + p1 * 16);
            s16x8 fC1 = *(const s16x8*)(fb + oC1 + p2 * 16);
#pragma unroll
            for (int i = 0; i < 8; i++){
              acc0[i] += aA0 * bf2f(fA0[i]) + aA1 * bf2f(fA1[i]);
              acc1[i] += aB0 * bf2f(fB0[i]) + aB1 * bf2f(fB1[i]);
              acc2[i] += aC0 * bf2f(fC0[i]) + aC1 * bf2f(fC1[i]);
            }
          }
#pragma unroll
          for (int i = 0; i < 8; i++){
            float x1 = (lane < 32) ? acc2[i] : acc1[i];
            float r1 = __shfl_xor(x1, 32);
            float t0 = acc0[i] + r1;
            v0[i] = ACT ? elu1(t0) : t0;
            float r2 = __shfl_xor(acc2[i], 32);
            if (lane < 32){
              float t1 = acc1[i] + r2;
              v1[i] = ACT ? elu1(t1) : t1;
            }
          }
        } else {
          const int eo = lane & 7, cb = lane >> 3;
          float acc[3][8] = {};
          for (int b = 0; b < cnt; b += 8){
            int e = b + eo;
            float a = a_s[wid][e][0];
            int so = src_s[wid][e];
#pragma unroll
            for (int c = 0; c < 3; c++){
              s16x8 fv = *(const s16x8*)(fb + so + (cb * 3 + c) * 16);
#pragma unroll
              for (int i = 0; i < 8; i++) acc[c][i] += a * bf2f(fv[i]);
            }
          }
#pragma unroll
          for (int c = 0; c < 3; c++){
#pragma unroll
            for (int i = 0; i < 8; i++){
              float v = acc[c][i];
              v += __shfl_xor(v, 1); v += __shfl_xor(v, 2); v += __shfl_xor(v, 4);
              if (ACT) v = elu1(v);
              if (eo == 0) mbk[MB(cb * 3 + c, i)] = v;
            }
          }
        }
      } else {
        // cnt > 64 serial path
        constexpr int NC = H * 192 / 8;
        const int c0 = lane, h0 = (c0 / 24) % H;
        const int c1 = lane + 64, h1 = (c1 / 24) % H;
        const bool act0 = (c0 < NC);
        const bool act1 = (H == 4) && (lane < 32);
        float acc0[8] = {}, acc1[8] = {};
        float mh[H], sh[H];
#pragma unroll
        for (int h = 0; h < H; h++){ mh[h] = -1e30f; sh[h] = 0.f; }
        for (int b = lane; b < cnt; b += 64){
          int pp = off + b; int s = src_sorted[pp]; int r = et_sorted[pp];
#pragma unroll
          for (int h = 0; h < H; h++){
            float v = el[s * H + h] + ern[h] + ee5[r * H + h];
            v = (v >= 0.f) ? v : 0.2f * v;
            mh[h] = fmaxf(mh[h], v);
          }
        }
#pragma unroll
        for (int h = 0; h < H; h++) mh[h] = wave_max(mh[h]);
        for (int b = lane; b < cnt; b += 64){
          int pp = off + b; int s = src_sorted[pp]; int r = et_sorted[pp];
#pragma unroll
          for (int h = 0; h < H; h++){
            float v = el[s * H + h] + ern[h] + ee5[r * H + h];
            v = (v >= 0.f) ? v : 0.2f * v;
            sh[h] += __expf(v - mh[h]);
          }
        }
#pragma unroll
        for (int h = 0; h < H; h++) sh[h] = wave_sum(sh[h]);
        if (MODE != 2){
          for (int b = lane; b < cnt; b += 64){
            int pp = off + b; int s = src_sorted[pp]; int r = et_sorted[pp];
            float ap[4] = {};
            if (MODE > 0){
#pragma unroll
              for (int q = 0; q < 4; q++) ap[q] = aprev[(size_t)pp * 4 + q];
            }
            float av[4] = {};
#pragma unroll
            for (int h = 0; h < H; h++){
              float v = el[s * H + h] + ern[h] + ee5[r * H + h];
              v = (v >= 0.f) ? v : 0.2f * v;
              float a = __expf(v - mh[h]) / sh[h];
              if (MODE == 1) a = 0.95f * a + 0.05f * ap[h];
              av[h] = a;
            }
            f32x4 o = {av[0], av[1], av[2], av[3]};
            *(f32x4*)(aout + (size_t)pp * 4) = o;
          }
        }
        for (int b = 0; b < cnt; b++){
          int pp = off + b; int s = src_sorted[pp]; int r = et_sorted[pp];
          const short* row = featb + (size_t)s * (H * 192);
          float apm[4] = {};
          if (MODE > 0){
#pragma unroll
            for (int q = 0; q < 4; q++) apm[q] = aprev[(size_t)pp * 4 + q];
          }
          if (act0){
            float v = el[s * H + h0] + ern[h0] + ee5[r * H + h0];
            v = (v >= 0.f) ? v : 0.2f * v;
            float a = __expf(v - mh[h0]) / sh[h0];
            if (MODE == 1) a = 0.95f * a + 0.05f * apm[h0];
            if (MODE == 2) a = 0.95f * a + 0.0125f * (apm[0] + apm[1] + apm[2] + apm[3]);
            s16x8 vv = *(const s16x8*)(row + c0 * 8);
#pragma unroll
            for (int i = 0; i < 8; i++) acc0[i] += a * bf2f(vv[i]);
          }
          if (act1){
            float v = el[s * H + h1] + ern[h1] + ee5[r * H + h1];
            v = (v >= 0.f) ? v : 0.2f * v;
            float a = __expf(v - mh[h1]) / sh[h1];
            if (MODE == 1) a = 0.95f * a + 0.05f * apm[h1];
            s16x8 vv = *(const s16x8*)(row + c1 * 8);
#pragma unroll
            for (int i = 0; i < 8; i++) acc1[i] += a * bf2f(vv[i]);
          }
        }
        if constexpr (H == 4){
#pragma unroll
          for (int i = 0; i < 8; i++){
            v0[i] = ACT ? elu1(acc0[i]) : acc0[i];
            if (lane < 32) v1[i] = ACT ? elu1(acc1[i]) : acc1[i];
          }
        } else {
          if (lane < 24){
#pragma unroll
            for (int i = 0; i < 8; i++) mbk[MB(lane, i)] = ACT ? elu1(acc0[i]) : acc0[i];
          }
        }
      }
      // ---- shared H==4 fallback epilogue: outb from regs + mean rounds ----
      if constexpr (H == 4){
        if (outb){
          {
            int c = lane, h = c / 24, rm = c % 24, t = rm >> 3, j = (rm & 7) * 8;
            s16x8 o;
#pragma unroll
            for (int i = 0; i < 8; i++) o[i] = f2bf(v0[i]);
            *(s16x8*)(outb + ((size_t)(t * NPAD) + n) * 256 + h * 64 + j) = o;
          }
          if (lane < 32){
            int c = lane + 64, h = c / 24, rm = c % 24, t = rm >> 3, j = (rm & 7) * 8;
            s16x8 o;
#pragma unroll
            for (int i = 0; i < 8; i++) o[i] = f2bf(v1[i]);
            *(s16x8*)(outb + ((size_t)(t * NPAD) + n) * 256 + h * 64 + j) = o;
          }
        }
        if (lane < 24){
#pragma unroll
          for (int i = 0; i < 8; i++) mbk[MB(lane, i)] = v0[i];
        }
        if (lane >= 24 && lane < 48){
#pragma unroll
          for (int i = 0; i < 8; i++) mbk[MB(lane - 24, i)] += v0[i];
        }
        if (lane >= 48){
#pragma unroll
          for (int i = 0; i < 8; i++) mbk[MB(lane - 48, i)] += v0[i];
        } else if (lane < 8){
#pragma unroll
          for (int i = 0; i < 8; i++) mbk[MB(lane + 16, i)] += v1[i];
        }
        if (lane >= 8 && lane < 32){
#pragma unroll
          for (int i = 0; i < 8; i++) mbk[MB(lane - 8, i)] += v1[i];
        }
      }
    }
  }

  // ---- final per-slot l2 norm from mb (per half-wave, node nme) ----
  const int cb8 = hl >> 3, ib = hl & 7;
  const float* mbh = mb[wid][half];
  for (int t = 0; t < 3; t++){
    float va = mbh[MB(t * 8 + cb8, ib)];
    float vb = mbh[MB(t * 8 + cb8 + 4, ib)];
    if constexpr (H == 4){ va *= 0.25f; vb *= 0.25f; }
    float ss = half_sum(va * va + vb * vb);
    float sc = 1.f / fmaxf(sqrtf(ss), 1e-12f);
    short* ob = o_b + (size_t)nme * 768 + t * 256 + kslice * 64;
    ob[hl] = f2bf(va * sc);
    ob[hl + 32] = f2bf(vb * sc);
  }
}

// ---------------- DistMult via MFMA ----------------
__global__ void distmult_mfma(const short* __restrict__ o_b, const short* __restrict__ Mt,
                              const int* __restrict__ pairs, const int* __restrict__ left,
                              const int* __restrict__ right, const int* __restrict__ mid,
                              float* __restrict__ score){
  const int pt = blockIdx.x, ct = blockIdx.y;
  const int tid = threadIdx.x;
  const int w = tid >> 6, lane = tid & 63;
  const int quad = lane >> 4, ln = lane & 15;
  __shared__ __attribute__((aligned(16))) short smem[8192];
  short* A_s = smem;
  short* B_s = smem + 2048;
  __shared__ int pid_s[64];
  __shared__ int lbase[64];
  if (tid < 64){
    int p = pairs[pt * 64 + tid];
    pid_s[tid] = p;
    lbase[tid] = (p >= 0) ? left[p] * 768 : 0;
  }
  __syncthreads();
  int p0 = pid_s[0];
  if (p0 < 0) return;
  const int r = mid[p0];
  const short* Mr = Mt + (size_t)r * 768 * 768;
  f32x4 acc[8] = {};
  for (int kk = 0; kk < 768; kk += 32){
    {
      int row = tid >> 2, chunk = tid & 3;
      s16x8 v = *(const s16x8*)(o_b + (size_t)lbase[row] + kk + chunk * 8);
      *(s16x8*)(A_s + row * 32 + chunk * 8) = v;
    }
    {
      int row = tid >> 1, half = tid & 1;
      const s16x8* g = (const s16x8*)(Mr + (size_t)(ct * 128 + row) * 768 + kk + half * 16);
      s16x8 v0 = g[0], v1 = g[1];
      *(s16x8*)(B_s + row * 32 + half * 16) = v0;
      *(s16x8*)(B_s + row * 32 + half * 16 + 8) = v1;
    }
    __syncthreads();
    s16x8 af = *(s16x8*)(A_s + (w * 16 + ln) * 32 + quad * 8);
#pragma unroll
    for (int b = 0; b < 8; b++){
      s16x8 bf = *(s16x8*)(B_s + (b * 16 + ln) * 32 + quad * 8);
      acc[b] = __builtin_amdgcn_mfma_f32_16x16x32_bf16(af, bf, acc[b], 0, 0, 0);
    }
    __syncthreads();
  }
  short* RE_s = smem;
  {
    int row = tid >> 2, quarter = tid & 3;
    int p = pid_s[row];
    s16x8 v0 = {}, v1 = {}, v2 = {}, v3 = {};
    if (p >= 0){
      const s16x8* g = (const s16x8*)(o_b + (size_t)right[p] * 768 + ct * 128 + quarter * 32);
      v0 = g[0]; v1 = g[1]; v2 = g[2]; v3 = g[3];
    }
    __syncthreads();
    short* dst = RE_s + row * 128 + quarter * 32;
    *(s16x8*)(dst)      = v0;
    *(s16x8*)(dst + 8)  = v1;
    *(s16x8*)(dst + 16) = v2;
    *(s16x8*)(dst + 24) = v3;
  }
  __syncthreads();
#pragma unroll
  for (int i = 0; i < 4; i++){
    int row = w * 16 + quad * 4 + i;
    float s = 0.f;
#pragma unroll
    for (int b = 0; b < 8; b++)
      s += acc[b][i] * bf2f(RE_s[row * 128 + b * 16 + ln]);
    s += __shfl_xor(s, 1); s += __shfl_xor(s, 2);
    s += __shfl_xor(s, 4); s += __shfl_xor(s, 8);
    if (ln == 0){
      int p = pid_s[row];
      if (p >= 0) atomicAdd(&score[p], s);
    }
  }
}

__global__ void sigmoid_k(const float* __restrict__ score, float* __restrict__ out){
  int i = blockIdx.x * 256 + threadIdx.x;
  if (i < N_PAIRS) out[i] = 1.f / (1.f + __expf(-score[i]));
}

// ---------------- launcher ----------------
extern "C" void kernel_launch(void* const* d_in, const int* in_sizes, int n_in,
                              void* d_out, int out_size, void* d_ws, size_t ws_size,
                              hipStream_t stream){
  const float* f0 = (const float*)d_in[0];
  const float* w0 = (const float*)d_in[1];
  const float* b0 = (const float*)d_in[2];
  const float* f1 = (const float*)d_in[3];
  const float* w1 = (const float*)d_in[4];
  const float* b1 = (const float*)d_in[5];
  const float* f2 = (const float*)d_in[6];
  const float* w2_ = (const float*)d_in[7];
  const float* b2 = (const float*)d_in[8];
  const float* lW[3]  = {(const float*)d_in[9],  (const float*)d_in[15], (const float*)d_in[21]};
  const float* lal[3] = {(const float*)d_in[10], (const float*)d_in[16], (const float*)d_in[22]};
  const float* lar[3] = {(const float*)d_in[11], (const float*)d_in[17], (const float*)d_in[23]};
  const float* lee[3] = {(const float*)d_in[12], (const float*)d_in[18], (const float*)d_in[24]};
  const float* lwe[3] = {(const float*)d_in[13], (const float*)d_in[19], (const float*)d_in[25]};
  const float* lae[3] = {(const float*)d_in[14], (const float*)d_in[20], (const float*)d_in[26]};
  const float* dmW = (const float*)d_in[27];
  const int* efeat = (const int*)d_in[28];
  const int* srcv  = (const int*)d_in[29];
  const int* dstv  = (const int*)d_in[30];
  const int* left  = (const int*)d_in[31];
  const int* right = (const int*)d_in[32];
  const int* midv  = (const int*)d_in[33];
  float* out = (float*)d_out;

  // ---- workspace layout ----
  short* feat_b = (short*)d_ws;               // 15,360,000 shorts
  float* aA     = (float*)(feat_b + 15360000);// 800,000
  float* aB     = aA + 800000;                // 800,000
  float* eall   = aB + 800000;                // 480,000
  float* ee5f   = eall + 480000;              // 96
  float* score  = ee5f + 96;                  // 10,016
  int* cnt3     = (int*)(score + 10016);      // 80,000  (per dst x 4: typed counts)
  int* csr_off  = cnt3 + 80000;               // 20,004
  int* csr_pos  = csr_off + 20004;            // 80,000  (per dst x 4: typed scatter cursors)
  int* loc      = csr_pos + 80000;            // 20,000
  int* bsum     = loc + 20000;                // 128
  int* bofs     = bsum + 128;                 // 128
  int* src_sorted = bofs + 128;               // 200,000
  int* et_sorted  = src_sorted + 200000;      // 200,000
  int* cnt5     = et_sorted + 200000;         // 80
  int* off5     = cnt5 + 80;                  // 8
  int* pos5     = off5 + 8;                   // 80
  int* pairs    = pos5 + 80;                  // 10,368
  short* o_b    = (short*)(pairs + PAIR_PAD); // 15,360,000
  short* Xb0    = o_b + 15360000;             // 3,858,432
  short* Xb12   = Xb0 + 3858432;              // 15,433,728
  short* Wt0    = Xb12 + 15433728;            // 49,152
  short* Wt1    = Wt0 + 49152;                // 196,608
  short* Wt2    = Wt1 + 196608;               // 49,152
  short* Mt     = Wt2 + 49152;                // 2,949,120
  float* elf0 = eall, *erf0 = eall + 80000;
  float* elf1 = eall + 160000, *erf1 = eall + 240000;
  float* elf2 = eall + 320000, *erf2 = eall + 400000;

  build_h<<<2500, 64, 0, stream>>>(f0, w0, b0, f1, w1, b1, f2, w2_, b2, Xb0, o_b,
                                   cnt3, cnt5, pos5, score, pairs, eall, Xb12, feat_b);
  count_prep_k<<<782 + 6336, 256, 0, stream>>>(dstv, srcv, cnt3, midv, cnt5,
                                               lW[0], lW[1], lW[2], dmW, Wt0, Wt1, Wt2, Mt,
                                               lee[0], lwe[0], lae[0], lee[1], lwe[1], lae[1],
                                               lee[2], lwe[2], lae[2], ee5f);
  scan1_k<<<NBLK, 256, 0, stream>>>(cnt3, loc, bsum);
  scan2_k<<<1, 128, 0, stream>>>(bsum, bofs, cnt5, off5);
  scan3_k<<<NBLK, 256, 0, stream>>>(loc, bofs, csr_off, csr_pos, cnt3);
  scatter_k<<<782, 256, 0, stream>>>(dstv, srcv, efeat, csr_pos, src_sorted, et_sorted,
                                     midv, off5, pos5, pairs);

  // layer 0 (H=4, typed proj tiles, typed slot-gather, ELU) -> emb slice 1
  // grid.x = 4 ct * 64-slot groups (per-t tile counts 63/48/48, guarded in-kernel)
  { dim3 g(256, 1, 3);
    mfma_proj<64, 256, 1><<<g, 256, 0, stream>>>(Xb0, Wt0, feat_b, lal[0], lar[0], elf0, erf0); }
  gat_fused<4, 0, 1, 1><<<2500, 256, 0, stream>>>(csr_off, src_sorted, et_sorted, elf0, erf0, ee5f,
                                                  nullptr, aA, feat_b, Xb12, o_b, cnt3, 1);

  // layer 1 (H=4, residual aA, ELU) -> emb slice 2
  // grid.x = 4 ct * 160 (157 tiles padded to 160; XCD-affine swizzle in-kernel)
  { dim3 g(640, 1, 3);
    mfma_proj<256, 256, 0><<<g, 256, 0, stream>>>(Xb12, Wt1, feat_b, lal[1], lar[1], elf1, erf1); }
  gat_fused<4, 1, 1, 0><<<2500, 256, 0, stream>>>(csr_off, src_sorted, et_sorted, elf1, erf1, ee5f + 32,
                                                  aA, aB, feat_b, Xb12, o_b, cnt3, 2);

  // layer 2 (H=1, blend vs mean of a1, no activation) -> emb slice 3
  { dim3 g(157, 1, 3);
    mfma_proj<256, 64, 0><<<g, 256, 0, stream>>>(Xb12, Wt2, feat_b, lal[2], lar[2], elf2, erf2); }
  gat_fused<1, 2, 0, 0><<<2500, 256, 0, stream>>>(csr_off, src_sorted, et_sorted, elf2, erf2, ee5f + 64,
                                                  aB, nullptr, feat_b, nullptr, o_b, cnt3, 3);

  // DistMult + sigmoid
  { dim3 g(DM_TILES, 6); distmult_mfma<<<g, 256, 0, stream>>>(o_b, Mt, pairs, left, right, midv, score); }
  sigmoid_k<<<40, 256, 0, stream>>>(score, out);
}

// Round 7
// 444.245 us; speedup vs baseline: 1.0202x; 1.0202x over previous
//
#include <hip/hip_runtime.h>
#include <math.h>

// ---------------- constants ----------------
#define N_NODES 20000
#define NPAD    20096          // 157*128
#define N_EDGES 200000
#define N_PAIRS 10000
#define PAIR_PAD 10368         // 162*64
#define DM_TILES 162
#define NBLK    79             // 79*256 = 20224 >= N_NODES

typedef __attribute__((ext_vector_type(8))) short s16x8;
typedef __attribute__((ext_vector_type(4))) float f32x4;

__device__ inline float wave_max(float v){
  for (int o = 32; o > 0; o >>= 1) v = fmaxf(v, __shfl_xor(v, o));
  return v;
}
__device__ inline float wave_sum(float v){
  for (int o = 32; o > 0; o >>= 1) v += __shfl_xor(v, o);
  return v;
}
__device__ inline float half_max(float v){
  for (int o = 16; o > 0; o >>= 1) v = fmaxf(v, __shfl_xor(v, o));
  return v;
}
__device__ inline float half_sum(float v){
  for (int o = 16; o > 0; o >>= 1) v += __shfl_xor(v, o);
  return v;
}
__device__ inline short f2bf(float x){
  union { float f; unsigned u; } v; v.f = x;
  unsigned r = (v.u + 0x7FFFu + ((v.u >> 16) & 1u)) >> 16;
  return (short)r;
}
__device__ inline float bf2f(short s){
  union { unsigned u; float f; } v; v.u = ((unsigned)(unsigned short)s) << 16;
  return v.f;
}
__device__ inline int ntype(int s){ return (s < 8000) ? 0 : ((s < 14000) ? 1 : 2); }
__device__ inline float elu1(float x){ return (x > 0.f) ? x : expm1f(x); }

// mean/norm buffer slot: chunk-in-head c24 (0..23), elem i (0..7); stride 9 -> conflict-free
#define MB(c24, i) ((c24) * 9 + (i))

// ---------------- input linears (8 nodes/block) + ALL workspace zeroing + o_b slice 0 ----------------
__global__ void build_h(const float* __restrict__ f0, const float* __restrict__ w0, const float* __restrict__ b0,
                        const float* __restrict__ f1, const float* __restrict__ w1, const float* __restrict__ b1,
                        const float* __restrict__ f2, const float* __restrict__ w2, const float* __restrict__ b2,
                        short* __restrict__ Xb0, short* __restrict__ o_b,
                        int* __restrict__ cnt3, int* __restrict__ cnt5, int* __restrict__ pos5,
                        float* __restrict__ score, int* __restrict__ pairs,
                        float* __restrict__ eall, short* __restrict__ Xb12,
                        short* __restrict__ featb){
  const int blk = blockIdx.x, lane = threadIdx.x;
  const int gid = blk * 64 + lane;             // 0..159999
  // ---- zeroing (spread across grid) ----
  if (gid < 80000) cnt3[gid] = 0;
  if (gid < 5){ cnt5[gid * 16] = 0; pos5[gid * 16] = 0; }
  if (gid < 10016) score[gid] = 0.f;
  if (gid < PAIR_PAD) pairs[gid] = -1;
  for (int i = gid; i < 480000; i += 160000) eall[i] = 0.f;
  s16x8 z = {};
  if (gid < 4608){  // Xb12 pad rows: 3 * 96 * 256 shorts
    int t = (gid * 16) / 24576, off = (gid * 16) % 24576;
    short* p = Xb12 + ((size_t)(t * NPAD + N_NODES)) * 256 + off;
    *(s16x8*)p = z; *(s16x8*)(p + 8) = z;
  }
  if (gid < 1152){  // Xb0 pad rows
    int t = (gid * 16) / 6144, off = (gid * 16) % 6144;
    short* p = Xb0 + ((size_t)(t * NPAD + N_NODES)) * 64 + off;
    *(s16x8*)p = z; *(s16x8*)(p + 8) = z;
  }
  // ---- per-block type ----
  int t, C, nbase; const float *f, *w, *b;
  if (blk < 1000)       { t = 0; nbase = 0;     C = 256; f = f0; w = w0; b = b0; }
  else if (blk < 1750)  { t = 1; nbase = 8000;  C = 128; f = f1; w = w1; b = b1; }
  else                  { t = 2; nbase = 14000; C = 64;  f = f2; w = w2; b = b2; }
  const int n0 = blk * 8;
  const int n0l = n0 - nbase;
  __shared__ float xs[8 * 256];
  const float* fr = f + (size_t)n0l * C;
  for (int i = lane; i < 8 * C; i += 64) xs[i] = fr[i];
  __syncthreads();
  float acc[8];
#pragma unroll
  for (int j = 0; j < 8; j++) acc[j] = b[lane];
  for (int c = 0; c < C; c++){
    float wv = w[c * 64 + lane];
#pragma unroll
    for (int j = 0; j < 8; j++) acc[j] += xs[j * C + c] * wv;
  }
  for (int j = 0; j < 8; j++){
    int n = n0 + j;
    // off-slot feat_b zero (layer-0 typed proj skips those tiles; cnt>64 fallback reads full rows)
    {
      int h = lane >> 4, si = (lane >> 3) & 1, j8 = lane & 7;
      int s0 = (t == 0) ? 1 : 0;
      int s1 = (t == 2) ? 1 : 2;
      int toff = si ? s1 : s0;
      *(s16x8*)(featb + ((size_t)n * 4 + h) * 192 + toff * 64 + j8 * 8) = z;
    }
    for (int tt = 0; tt < 3; tt++)
      Xb0[((size_t)(tt * NPAD) + n) * 64 + lane] = f2bf((tt == t) ? acc[j] : 0.f);
    float ss = wave_sum(acc[j] * acc[j]);
    float sc = 1.f / fmaxf(sqrtf(ss), 1e-12f);
    for (int tt = 0; tt < 3; tt++)
      o_b[(size_t)n * 768 + tt * 256 + lane] = f2bf((tt == t) ? acc[j] * sc : 0.f);
  }
}

// ---------------- merged: typed edge/pair counting (blocks 0..781) + weight prep ----------------
__global__ void count_prep_k(const int* __restrict__ dst, const int* __restrict__ srcv,
                             int* __restrict__ cnt3,
                             const int* __restrict__ mid, int* __restrict__ cnt5,
                             const float* __restrict__ lW0, const float* __restrict__ lW1,
                             const float* __restrict__ lW2, const float* __restrict__ dmW,
                             short* __restrict__ Wt0, short* __restrict__ Wt1,
                             short* __restrict__ Wt2, short* __restrict__ Mt,
                             const float* __restrict__ ee0, const float* __restrict__ we0, const float* __restrict__ ae0,
                             const float* __restrict__ ee1, const float* __restrict__ we1, const float* __restrict__ ae1,
                             const float* __restrict__ ee2, const float* __restrict__ we2, const float* __restrict__ ae2,
                             float* __restrict__ ee5f){
  if (blockIdx.x < 782){
    int e = blockIdx.x * 256 + threadIdx.x;
    int lane = threadIdx.x & 63;
    if (e < N_EDGES){
      int tt = ntype(srcv[e]);
      atomicAdd(&cnt3[dst[e] * 4 + tt], 1);
    }
    int r_mine = (e < N_PAIRS) ? mid[e] : -1;
#pragma unroll
    for (int r = 0; r < 5; r++){
      unsigned long long mask = __ballot(r_mine == r);
      if (mask){
        int leader = __ffsll((long long)mask) - 1;
        if (lane == leader) atomicAdd(&cnt5[r * 16], __popcll(mask));
      }
    }
    return;
  }
  int lin = blockIdx.x - 782;
  int z = lin / 576;
  int rem = lin % 576;
  int by = rem / 24, bx = rem % 24;
  if (z == 10){
    int r = bx, L = by;
    if (r >= 5 || L >= 3) return;
    int H = (L == 2) ? 1 : 4;
    const float* eetab = (L == 0) ? ee0 : ((L == 1) ? ee1 : ee2);
    const float* We    = (L == 0) ? we0 : ((L == 1) ? we1 : we2);
    const float* ae    = (L == 0) ? ae0 : ((L == 1) ? ae1 : ae2);
    int h = threadIdx.x >> 6, lane = threadIdx.x & 63;
    if (h >= H) return;
    float v = 0.f;
    for (int k = 0; k < 64; k++) v += eetab[r * 64 + k] * We[k * H * 64 + h * 64 + lane];
    v *= ae[h * 64 + lane];
    v = wave_sum(v);
    if (lane == 0) ee5f[L * 32 + r * H + h] = v;
    return;
  }
  const float* s; short* d; int R, Cc, r0, c0;
  if (z < 5){
    s = dmW + (size_t)z * 589824; d = Mt + (size_t)z * 589824;
    R = 768; Cc = 768; r0 = bx * 32; c0 = by * 32;
  } else if (z < 8){
    if (bx >= 8 || by >= 8) return;
    int t = z - 5;
    s = lW1 + (size_t)t * 65536; d = Wt1 + (size_t)t * 65536;
    R = 256; Cc = 256; r0 = bx * 32; c0 = by * 32;
  } else if (z == 8){
    if (bx >= 6 || by >= 8) return;
    int t = bx >> 1;
    s = lW0 + (size_t)t * 16384; d = Wt0 + (size_t)t * 16384;
    R = 64; Cc = 256; r0 = (bx & 1) * 32; c0 = by * 32;
  } else {
    if (bx >= 8 || by >= 6) return;
    int t = by >> 1;
    s = lW2 + (size_t)t * 16384; d = Wt2 + (size_t)t * 16384;
    R = 256; Cc = 64; r0 = bx * 32; c0 = (by & 1) * 32;
  }
  __shared__ float tile[32][33];
  int tx = threadIdx.x & 31, ty = threadIdx.x >> 5;
  for (int i = 0; i < 32; i += 8){
    int r = r0 + ty + i;
    tile[ty + i][tx] = (r < R && c0 + tx < Cc) ? s[(size_t)r * Cc + c0 + tx] : 0.f;
  }
  __syncthreads();
  for (int i = 0; i < 32; i += 8){
    int c = c0 + ty + i;
    if (c < Cc && r0 + tx < R)
      d[(size_t)c * R + r0 + tx] = f2bf(tile[tx][ty + i]);
  }
}

// ---------------- hierarchical scan ----------------
__global__ void scan1_k(const int* __restrict__ cnt3, int* __restrict__ loc, int* __restrict__ bsum){
  __shared__ int s[256];
  int tid = threadIdx.x;
  int idx = blockIdx.x * 256 + tid;
  int v = (idx < N_NODES) ? (cnt3[idx * 4] + cnt3[idx * 4 + 1] + cnt3[idx * 4 + 2]) : 0;
  s[tid] = v;
  __syncthreads();
  for (int o = 1; o < 256; o <<= 1){
    int u = (tid >= o) ? s[tid - o] : 0;
    __syncthreads();
    s[tid] += u;
    __syncthreads();
  }
  if (idx < N_NODES) loc[idx] = s[tid] - v;
  if (tid == 255) bsum[blockIdx.x] = s[255];
}

__global__ void scan2_k(const int* __restrict__ bsum, int* __restrict__ bofs,
                        const int* __restrict__ cnt5, int* __restrict__ off5){
  __shared__ int s[128];
  int tid = threadIdx.x;
  int v = (tid < NBLK) ? bsum[tid] : 0;
  s[tid] = v;
  __syncthreads();
  for (int o = 1; o < 128; o <<= 1){
    int u = (tid >= o) ? s[tid - o] : 0;
    __syncthreads();
    s[tid] += u;
    __syncthreads();
  }
  if (tid < NBLK) bofs[tid] = s[tid] - v;
  if (tid == 0){
    int r0 = 0;
    for (int r = 0; r < 5; r++){ off5[r] = r0; r0 += ((cnt5[r * 16] + 63) >> 6) << 6; }
  }
}

__global__ void scan3_k(const int* __restrict__ loc, const int* __restrict__ bofs,
                        int* __restrict__ coff, int* __restrict__ cpos,
                        const int* __restrict__ cnt3){
  int idx = blockIdx.x * 256 + threadIdx.x;
  if (idx < N_NODES){
    int v = loc[idx] + bofs[blockIdx.x];
    coff[idx] = v;
    int c0 = cnt3[idx * 4], c1 = cnt3[idx * 4 + 1];
    cpos[idx * 4]     = v;
    cpos[idx * 4 + 1] = v + c0;
    cpos[idx * 4 + 2] = v + c0 + c1;
  }
  if (idx == 0) coff[N_NODES] = N_EDGES;
}

__global__ void scatter_k(const int* __restrict__ dst, const int* __restrict__ srcv,
                          const int* __restrict__ efeat, int* __restrict__ cpos,
                          int* __restrict__ src_sorted, int* __restrict__ et_sorted,
                          const int* __restrict__ mid, const int* __restrict__ off5,
                          int* __restrict__ pos5, int* __restrict__ pairs){
  int e = blockIdx.x * 256 + threadIdx.x;
  int lane = threadIdx.x & 63;
  if (e < N_EDGES){
    int s = srcv[e];
    int tt = ntype(s);
    int p = atomicAdd(&cpos[dst[e] * 4 + tt], 1);
    src_sorted[p] = s;
    et_sorted[p] = efeat[e];
  }
  int r_mine = (e < N_PAIRS) ? mid[e] : -1;
#pragma unroll
  for (int r = 0; r < 5; r++){
    unsigned long long mask = __ballot(r_mine == r);
    if (mask){
      int cnt = __popcll(mask);
      int leader = __ffsll((long long)mask) - 1;
      int base = 0;
      if (lane == leader) base = atomicAdd(&pos5[r * 16], cnt);
      base = __shfl(base, leader);
      if (r_mine == r){
        int rank = __popcll(mask & ((1ull << lane) - 1ull));
        pairs[off5[r] + base + rank] = e;
      }
    }
  }
}

// ---------------- MFMA slot projection -> bf16 feat + fused el/er partials ----------------
// One ct per block (36 VGPR, high occupancy). The (tile, ct) encoding in blockIdx.x puts all
// 4 ct-instances of a tile at the SAME residue mod 8 -> same XCD -> A tile hits L2 3 of 4 times.
// LDS rows padded to 40 shorts (80 B) to spread banks on b128 reads/writes.
#define LDA 40
template<int C, int NO, int TYPED>
__global__ void mfma_proj(const short* __restrict__ Xb, const short* __restrict__ Wt,
                          short* __restrict__ featb, const float* __restrict__ al,
                          const float* __restrict__ ar, float* __restrict__ elf,
                          float* __restrict__ erf){
  constexpr int H = NO / 64;
  const int t = blockIdx.z;
  int tile, ct;
  if constexpr (H == 4){
    const int x = blockIdx.x;            // grp*32 + ct*8 + slot
    const int grp = x >> 5, sub = x & 31;
    ct = sub >> 3;
    tile = grp * 8 + (sub & 7);
  } else { tile = blockIdx.x; ct = 0; }
  if constexpr (TYPED){
    const int lo[3] = {0, 62, 109};
    const int hi[3] = {63, 110, 157};
    if (tile >= hi[t] - lo[t]) return;
    tile += lo[t];
  } else {
    if (tile >= NPAD / 128) return;
  }
  const int n0 = tile * 128;
  const int tid = threadIdx.x;
  const int w = tid >> 6, lane = tid & 63;
  const int quad = lane >> 4, ln = lane & 15;
  __shared__ __attribute__((aligned(16))) short A_s[128 * LDA];
  __shared__ __attribute__((aligned(16))) short B_s[64 * LDA];
  const short* Xt  = Xb + (size_t)t * NPAD * C;
  const short* Wtt = Wt + ((size_t)t * NO + ct * 64) * C;
  f32x4 acc[2][4] = {};
  for (int kk = 0; kk < C; kk += 32){
    {
      int row = tid >> 1, hk = tid & 1;
      const s16x8* g = (const s16x8*)(Xt + (size_t)(n0 + row) * C + kk + hk * 16);
      s16x8 v0 = g[0], v1 = g[1];
      *(s16x8*)(A_s + row * LDA + hk * 16) = v0;
      *(s16x8*)(A_s + row * LDA + hk * 16 + 8) = v1;
    }
    {
      int row = tid >> 2, chunk = tid & 3;
      s16x8 v = *(const s16x8*)(Wtt + (size_t)row * C + kk + chunk * 8);
      *(s16x8*)(B_s + row * LDA + chunk * 8) = v;
    }
    __syncthreads();
    s16x8 af0 = *(s16x8*)(A_s + (w * 32 + ln) * LDA + quad * 8);
    s16x8 af1 = *(s16x8*)(A_s + (w * 32 + 16 + ln) * LDA + quad * 8);
    s16x8 bf[4];
#pragma unroll
    for (int b = 0; b < 4; b++) bf[b] = *(s16x8*)(B_s + (b * 16 + ln) * LDA + quad * 8);
#pragma unroll
    for (int b = 0; b < 4; b++){
      acc[0][b] = __builtin_amdgcn_mfma_f32_16x16x32_bf16(af0, bf[b], acc[0][b], 0, 0, 0);
      acc[1][b] = __builtin_amdgcn_mfma_f32_16x16x32_bf16(af1, bf[b], acc[1][b], 0, 0, 0);
    }
    __syncthreads();
  }
#pragma unroll
  for (int ar_ = 0; ar_ < 2; ar_++){
#pragma unroll
    for (int i = 0; i < 4; i++){
      int n = n0 + w * 32 + ar_ * 16 + quad * 4 + i;
      if (n >= N_NODES) continue;
#pragma unroll
      for (int b = 0; b < 4; b++){
        int jj = b * 16 + ln;
        featb[((size_t)n * H + ct) * 192 + t * 64 + jj] = f2bf(acc[ar_][b][i]);
      }
    }
  }
  float alv[4], arv[4];
#pragma unroll
  for (int b = 0; b < 4; b++){
    alv[b] = al[ct * 192 + t * 64 + b * 16 + ln];
    arv[b] = ar[ct * 192 + t * 64 + b * 16 + ln];
  }
#pragma unroll
  for (int ar_ = 0; ar_ < 2; ar_++){
#pragma unroll
    for (int i = 0; i < 4; i++){
      float pe = 0.f, pr = 0.f;
#pragma unroll
      for (int b = 0; b < 4; b++){
        pe += acc[ar_][b][i] * alv[b];
        pr += acc[ar_][b][i] * arv[b];
      }
#pragma unroll
      for (int o = 1; o < 16; o <<= 1){
        pe += __shfl_xor(pe, o);
        pr += __shfl_xor(pr, o);
      }
      int n = n0 + w * 32 + ar_ * 16 + quad * 4 + i;
      if (ln == 0 && n < N_NODES){
        atomicAdd(&elf[n * H + ct], pe);
        atomicAdd(&erf[n * H + ct], pr);
      }
    }
  }
}

// ---------------- fused softmax + gather aggregation + emb: 2 nodes per wave ----------------
// outb stored directly from registers; per-slot l2-norm via small mb buffer (wave-ordered rounds).
// Gather loops unrolled for memory-level parallelism (12 / 6 / 6 loads in flight).
template<int H, int MODE, int ACT, int TYPED>
__global__ __launch_bounds__(256) void gat_fused(
    const int* __restrict__ csr_off, const int* __restrict__ src_sorted,
    const int* __restrict__ et_sorted,
    const float* __restrict__ el, const float* __restrict__ er, const float* __restrict__ ee5,
    const float* __restrict__ aprev, float* __restrict__ aout,
    const short* __restrict__ featb, short* __restrict__ outb,
    short* __restrict__ o_b, const int* __restrict__ cnt3, int kslice){
  const int wid = threadIdx.x >> 6, lane = threadIdx.x & 63;
  const int half = lane >> 5, hl = lane & 31;
  const int l32 = half << 5;
  const int n0 = blockIdx.x * 8 + wid * 2;        // wave owns nodes n0, n0+1; grid exact
  const int nme = n0 + half;                      // this half-wave's node
  __shared__ float a_s[4][64][H];
  __shared__ int   src_s[4][64];                  // pre-multiplied BYTE offsets into featb
  __shared__ float mb[4][2][216];                 // head-sum buffer, MB(c24,i) layout
  const char* fb = (const char*)featb;

  const int offm = csr_off[nme];
  const int cntm = csr_off[nme + 1] - offm;
  const int cnto = __shfl_xor(cntm, 32);
  const bool paired = (cntm <= 32) && (cnto <= 32);

  if (paired){
    // ---- softmax: edge e of node nme at lane l32+e ----
    float ern[H];
    if constexpr (H == 4){
      f32x4 ev = *(const f32x4*)(er + nme * 4);
#pragma unroll
      for (int h = 0; h < 4; h++) ern[h] = ev[h];
    } else ern[0] = er[nme];
    const int p = offm + hl;
    const bool valid = hl < cntm;
    int sidx = 0, r = 0;
    if (valid){ sidx = src_sorted[p]; r = et_sorted[p]; }
    int s0 = __shfl(sidx, l32);
    src_s[wid][lane] = (valid ? sidx : s0) * (H * 384);
    float lg[H];
#pragma unroll
    for (int h = 0; h < H; h++) lg[h] = -1e30f;
    if (valid){
      if constexpr (H == 4){
        f32x4 elv = *(const f32x4*)(el + sidx * 4);
        f32x4 eev = *(const f32x4*)(ee5 + r * 4);
#pragma unroll
        for (int h = 0; h < 4; h++){
          float v = elv[h] + ern[h] + eev[h];
          lg[h] = (v >= 0.f) ? v : 0.2f * v;
        }
      } else {
        float v = el[sidx] + ern[0] + ee5[r];
        lg[0] = (v >= 0.f) ? v : 0.2f * v;
      }
    }
    float ap[4] = {};
    if (MODE > 0 && valid){
      f32x4 av4 = *(const f32x4*)(aprev + (size_t)p * 4);
#pragma unroll
      for (int q = 0; q < 4; q++) ap[q] = av4[q];
    }
    float av[H];
#pragma unroll
    for (int h = 0; h < H; h++){
      float mh = half_max(lg[h]);
      float ex = valid ? __expf(lg[h] - mh) : 0.f;
      float sh = half_sum(ex);
      float a = ex / sh;
      if (MODE == 1) a = 0.95f * a + 0.05f * ap[h];
      if (MODE == 2) a = 0.95f * a + 0.0125f * (ap[0] + ap[1] + ap[2] + ap[3]);
      av[h] = a;
      a_s[wid][lane][h] = valid ? a : 0.f;
    }
    if constexpr (MODE != 2){
      if (valid){
        f32x4 o = {av[0], av[1], av[2], av[3]};
        *(f32x4*)(aout + (size_t)p * 4) = o;
      }
    }

    if constexpr (TYPED && H == 4){
      // ---- layer 0: slot-sparse rows; one 2-edge segment per type per iter (6 loads in flight) ----
      const int hh = hl >> 3, j8 = hl & 7;
      const int sub = hh * 384 + j8 * 16;
      float acc[3][8] = {};
      const int b1 = cnt3[nme * 4], b2 = b1 + cnt3[nme * 4 + 1];
      const int base_[3] = {0, b1, b2};
      const int lim_[3]  = {b1, b2, cntm};
      int maxrun = lim_[0] - base_[0];
      maxrun = max(maxrun, lim_[1] - base_[1]);
      maxrun = max(maxrun, lim_[2] - base_[2]);
      for (int b = 0; b < maxrun; b += 2){
        int i0[3], i1[3]; float a0[3], a1[3];
#pragma unroll
        for (int t = 0; t < 3; t++){
          int e0 = base_[t] + b, e1 = e0 + 1;
          bool v0 = e0 < lim_[t], v1 = e1 < lim_[t];
          i0[t] = v0 ? e0 : 0; i1[t] = v1 ? e1 : 0;
          a0[t] = v0 ? a_s[wid][l32 + i0[t]][hh] : 0.f;
          a1[t] = v1 ? a_s[wid][l32 + i1[t]][hh] : 0.f;
        }
        s16x8 f0[3], f1[3];
#pragma unroll
        for (int t = 0; t < 3; t++){
          f0[t] = *(const s16x8*)(fb + src_s[wid][l32 + i0[t]] + sub + t * 128);
          f1[t] = *(const s16x8*)(fb + src_s[wid][l32 + i1[t]] + sub + t * 128);
        }
#pragma unroll
        for (int t = 0; t < 3; t++)
#pragma unroll
          for (int i = 0; i < 8; i++)
            acc[t][i] += a0[t] * bf2f(f0[t][i]) + a1[t] * bf2f(f1[t][i]);
      }
#pragma unroll
      for (int t = 0; t < 3; t++){
        if (ACT){
#pragma unroll
          for (int i = 0; i < 8; i++) acc[t][i] = elu1(acc[t][i]);
        }
        if (outb){
          s16x8 o;
#pragma unroll
          for (int i = 0; i < 8; i++) o[i] = f2bf(acc[t][i]);
          *(s16x8*)(outb + ((size_t)(t * NPAD) + nme) * 256 + hh * 64 + j8 * 8) = o;
        }
      }
      // mean rounds by head (chunk c = hh*24 + t*8 + j8 -> c24 = t*8 + j8)
#pragma unroll
      for (int rr = 0; rr < 4; rr++){
        if (hh == rr){
#pragma unroll
          for (int t = 0; t < 3; t++)
#pragma unroll
            for (int i = 0; i < 8; i++){
              if (rr == 0) mb[wid][half][MB(t * 8 + j8, i)] = acc[t][i];
              else         mb[wid][half][MB(t * 8 + j8, i)] += acc[t][i];
            }
        }
      }
    } else if constexpr (H == 4){
      // ---- dense rows: 96 chunks / 32 lanes = 3/lane, 4 edges/iter (12 loads in flight) ----
      const int p0 = hl, p1 = hl + 32, p2 = hl + 64;
      const int h0 = p0 / 24, h1 = p1 / 24, h2 = p2 / 24;
      float acc0[8] = {}, acc1[8] = {}, acc2[8] = {};
      const int cnt4m = (cntm + 3) & ~3;
      for (int b = 0; b < cnt4m; b += 4){
        int e0 = l32 + b;
        int so0 = src_s[wid][e0],     so1 = src_s[wid][e0 + 1];
        int so2 = src_s[wid][e0 + 2], so3 = src_s[wid][e0 + 3];
        float a00 = a_s[wid][e0][h0],     a01 = a_s[wid][e0][h1],     a02 = a_s[wid][e0][h2];
        float a10 = a_s[wid][e0 + 1][h0], a11 = a_s[wid][e0 + 1][h1], a12 = a_s[wid][e0 + 1][h2];
        float a20 = a_s[wid][e0 + 2][h0], a21 = a_s[wid][e0 + 2][h1], a22 = a_s[wid][e0 + 2][h2];
        float a30 = a_s[wid][e0 + 3][h0], a31 = a_s[wid][e0 + 3][h1], a32 = a_s[wid][e0 + 3][h2];
        s16x8 f00 = *(const s16x8*)(fb + so0 + p0 * 16);
        s16x8 f01 = *(const s16x8*)(fb + so0 + p1 * 16);
        s16x8 f02 = *(const s16x8*)(fb + so0 + p2 * 16);
        s16x8 f10 = *(const s16x8*)(fb + so1 + p0 * 16);
        s16x8 f11 = *(const s16x8*)(fb + so1 + p1 * 16);
        s16x8 f12 = *(const s16x8*)(fb + so1 + p2 * 16);
        s16x8 f20 = *(const s16x8*)(fb + so2 + p0 * 16);
        s16x8 f21 = *(const s16x8*)(fb + so2 + p1 * 16);
        s16x8 f22 = *(const s16x8*)(fb + so2 + p2 * 16);
        s16x8 f30 = *(const s16x8*)(fb + so3 + p0 * 16);
        s16x8 f31 = *(const s16x8*)(fb + so3 + p1 * 16);
        s16x8 f32_ = *(const s16x8*)(fb + so3 + p2 * 16);
#pragma unroll
        for (int i = 0; i < 8; i++){
          acc0[i] += a00 * bf2f(f00[i]) + a10 * bf2f(f10[i]) + a20 * bf2f(f20[i]) + a30 * bf2f(f30[i]);
          acc1[i] += a01 * bf2f(f01[i]) + a11 * bf2f(f11[i]) + a21 * bf2f(f21[i]) + a31 * bf2f(f31[i]);
          acc2[i] += a02 * bf2f(f02[i]) + a12 * bf2f(f12[i]) + a22 * bf2f(f22[i]) + a32 * bf2f(f32_[i]);
        }
      }
      if (ACT){
#pragma unroll
        for (int i = 0; i < 8; i++){
          acc0[i] = elu1(acc0[i]); acc1[i] = elu1(acc1[i]); acc2[i] = elu1(acc2[i]);
        }
      }
      if (outb){
#pragma unroll
        for (int cc = 0; cc < 3; cc++){
          int c = hl + cc * 32;
          const float* vv = (cc == 0) ? acc0 : ((cc == 1) ? acc1 : acc2);
          int h = c / 24, rm = c % 24, t = rm >> 3, j = (rm & 7) * 8;
          s16x8 o;
#pragma unroll
          for (int i = 0; i < 8; i++) o[i] = f2bf(vv[i]);
          *(s16x8*)(outb + ((size_t)(t * NPAD) + nme) * 256 + h * 64 + j) = o;
        }
      }
      // mean rounds by head
      float* mbh = mb[wid][half];
      if (hl < 24){
#pragma unroll
        for (int i = 0; i < 8; i++) mbh[MB(hl, i)] = acc0[i];
      }
      if (hl >= 24){
#pragma unroll
        for (int i = 0; i < 8; i++) mbh[MB(hl - 24, i)] += acc0[i];
      } else if (hl < 16){
#pragma unroll
        for (int i = 0; i < 8; i++) mbh[MB(hl + 8, i)] += acc1[i];
      }
      if (hl >= 16){
#pragma unroll
        for (int i = 0; i < 8; i++) mbh[MB(hl - 16, i)] += acc1[i];
      } else if (hl < 8){
#pragma unroll
        for (int i = 0; i < 8; i++) mbh[MB(hl + 16, i)] += acc2[i];
      }
      if (hl >= 8){
#pragma unroll
        for (int i = 0; i < 8; i++) mbh[MB(hl - 8, i)] += acc2[i];
      }
    } else {
      // ---- H == 1: 8 edges/iter x 3 chunks/lane over 8-lane groups (6 loads in flight) ----
      const int e4 = hl >> 3, cb = hl & 7;
      float acc[3][8] = {};
      for (int b = 0; b < cntm; b += 8){
        int i0 = b + e4, i1 = b + 4 + e4;        // <= 31 always; pads a_s==0
        float a0 = a_s[wid][l32 + i0][0];
        float a1 = a_s[wid][l32 + i1][0];
        int so0 = src_s[wid][l32 + i0], so1 = src_s[wid][l32 + i1];
        s16x8 f0[3], f1[3];
#pragma unroll
        for (int c = 0; c < 3; c++){
          f0[c] = *(const s16x8*)(fb + so0 + (cb * 3 + c) * 16);
          f1[c] = *(const s16x8*)(fb + so1 + (cb * 3 + c) * 16);
        }
#pragma unroll
        for (int c = 0; c < 3; c++)
#pragma unroll
          for (int i = 0; i < 8; i++)
            acc[c][i] += a0 * bf2f(f0[c][i]) + a1 * bf2f(f1[c][i]);
      }
#pragma unroll
      for (int c = 0; c < 3; c++){
#pragma unroll
        for (int i = 0; i < 8; i++){
          float v = acc[c][i];
          v += __shfl_xor(v, 8); v += __shfl_xor(v, 16);
          if (ACT) v = elu1(v);
          if (e4 == 0) mb[wid][half][MB(cb * 3 + c, i)] = v;
        }
      }
    }
  } else {
    // ---- rare fallback: process both nodes sequentially with the full wave ----
    for (int k = 0; k < 2; k++){
      const int n = n0 + k;
      const int off = csr_off[n];
      const int cnt = csr_off[n + 1] - off;
      float* mbk = mb[wid][k];
      float v0[8], v1[8];
      float ern[H];
#pragma unroll
      for (int h = 0; h < H; h++) ern[h] = er[n * H + h];
      if (cnt <= 64){
        int p = off + lane;
        int sidx = 0, r = 0;
        if (lane < cnt){ sidx = src_sorted[p]; r = et_sorted[p]; }
        int src0 = __shfl(sidx, 0);
        src_s[wid][lane] = ((lane < cnt) ? sidx : src0) * (H * 384);
        float lg[H];
#pragma unroll
        for (int h = 0; h < H; h++) lg[h] = -1e30f;
        if (lane < cnt){
#pragma unroll
          for (int h = 0; h < H; h++){
            float v = el[sidx * H + h] + ern[h] + ee5[r * H + h];
            lg[h] = (v >= 0.f) ? v : 0.2f * v;
          }
        }
        float ap[4] = {};
        if (MODE > 0 && lane < cnt){
#pragma unroll
          for (int q = 0; q < 4; q++) ap[q] = aprev[(size_t)p * 4 + q];
        }
        float av[H];
#pragma unroll
        for (int h = 0; h < H; h++){
          float mh = wave_max(lg[h]);
          float ex = (lane < cnt) ? __expf(lg[h] - mh) : 0.f;
          float sh = wave_sum(ex);
          float a = ex / sh;
          if (MODE == 1) a = 0.95f * a + 0.05f * ap[h];
          if (MODE == 2) a = 0.95f * a + 0.0125f * (ap[0] + ap[1] + ap[2] + ap[3]);
          av[h] = a;
          a_s[wid][lane][h] = (lane < cnt) ? a : 0.f;
        }
        if constexpr (MODE != 2){
          if (lane < cnt){
            f32x4 o = {av[0], av[1], av[2], av[3]};
            *(f32x4*)(aout + (size_t)p * 4) = o;
          }
        }
        if constexpr (H == 4){
          const int p0 = lane;
          const int p1 = (lane < 32) ? lane + 64 : lane - 32;
          const int p2 = lane + 32;
          const int hA = p0 / 24, hB = p1 / 24, hC = p2 / 24;
          const int eo2 = lane >> 5;
          float acc0[8] = {}, acc1[8] = {}, acc2[8] = {};
          const int cnt4 = (cnt + 3) & ~3;
          for (int b = 0; b < cnt4; b += 4){
            int eB0 = b + eo2, eB1 = b + 2 + eo2;
            int oA0 = src_s[wid][b],     oB0 = src_s[wid][eB0], oC0 = src_s[wid][b + 1];
            int oA1 = src_s[wid][b + 2], oB1 = src_s[wid][eB1], oC1 = src_s[wid][b + 3];
            float aA0 = a_s[wid][b][hA],     aB0 = a_s[wid][eB0][hB], aC0 = a_s[wid][b + 1][hC];
            float aA1 = a_s[wid][b + 2][hA], aB1 = a_s[wid][eB1][hB], aC1 = a_s[wid][b + 3][hC];
            s16x8 fA0 = *(const s16x8*)(fb + oA0 + p0 * 16);
            s16x8 fB0 = *(const s16x8*)(fb + oB0 + p1 * 16);
            s16x8 fC0 = *(const s16x8*)(fb + oC0 + p2 * 16);
            s16x8 fA1 = *(const s16x8*)(fb + oA1 + p0 * 16);
            s16x8 fB1 = *(const s16x8*)(fb + oB1 + p1 * 16);
            s16x8 fC1 = *(const s16x8*)(fb + oC1 + p2 * 16);
#pragma unroll
            for (int i = 0; i < 8; i++){
              acc0[i] += aA0 * bf2f(fA0[i]) + aA1 * bf2f(fA1[i]);
              acc1[i] += aB0 * bf2f(fB0[i]) + aB1 * bf2f(fB1[i]);
              acc2[i] += aC0 * bf2f(fC0[i]) + aC1 * bf2f(fC1[i]);
            }
          }
#pragma unroll
          for (int i = 0; i < 8; i++){
            float x1 = (lane < 32) ? acc2[i] : acc1[i];
            float r1 = __shfl_xor(x1, 32);
            float t0 = acc0[i] + r1;
            v0[i] = ACT ? elu1(t0) : t0;
            float r2 = __shfl_xor(acc2[i], 32);
            if (lane < 32){
              float t1 = acc1[i] + r2;
              v1[i] = ACT ? elu1(t1) : t1;
            }
          }
        } else {
          const int eo = lane & 7, cb = lane >> 3;
          float acc[3][8] = {};
          for (int b = 0; b < cnt; b += 8){
            int e = b + eo;
            float a = a_s[wid][e][0];
            int so = src_s[wid][e];
#pragma unroll
            for (int c = 0; c < 3; c++){
              s16x8 fv = *(const s16x8*)(fb + so + (cb * 3 + c) * 16);
#pragma unroll
              for (int i = 0; i < 8; i++) acc[c][i] += a * bf2f(fv[i]);
            }
          }
#pragma unroll
          for (int c = 0; c < 3; c++){
#pragma unroll
            for (int i = 0; i < 8; i++){
              float v = acc[c][i];
              v += __shfl_xor(v, 1); v += __shfl_xor(v, 2); v += __shfl_xor(v, 4);
              if (ACT) v = elu1(v);
              if (eo == 0) mbk[MB(cb * 3 + c, i)] = v;
            }
          }
        }
      } else {
        // cnt > 64 serial path
        constexpr int NC = H * 192 / 8;
        const int c0 = lane, h0 = (c0 / 24) % H;
        const int c1 = lane + 64, h1 = (c1 / 24) % H;
        const bool act0 = (c0 < NC);
        const bool act1 = (H == 4) && (lane < 32);
        float acc0[8] = {}, acc1[8] = {};
        float mh[H], sh[H];
#pragma unroll
        for (int h = 0; h < H; h++){ mh[h] = -1e30f; sh[h] = 0.f; }
        for (int b = lane; b < cnt; b += 64){
          int pp = off + b; int s = src_sorted[pp]; int r = et_sorted[pp];
#pragma unroll
          for (int h = 0; h < H; h++){
            float v = el[s * H + h] + ern[h] + ee5[r * H + h];
            v = (v >= 0.f) ? v : 0.2f * v;
            mh[h] = fmaxf(mh[h], v);
          }
        }
#pragma unroll
        for (int h = 0; h < H; h++) mh[h] = wave_max(mh[h]);
        for (int b = lane; b < cnt; b += 64){
          int pp = off + b; int s = src_sorted[pp]; int r = et_sorted[pp];
#pragma unroll
          for (int h = 0; h < H; h++){
            float v = el[s * H + h] + ern[h] + ee5[r * H + h];
            v = (v >= 0.f) ? v : 0.2f * v;
            sh[h] += __expf(v - mh[h]);
          }
        }
#pragma unroll
        for (int h = 0; h < H; h++) sh[h] = wave_sum(sh[h]);
        if (MODE != 2){
          for (int b = lane; b < cnt; b += 64){
            int pp = off + b; int s = src_sorted[pp]; int r = et_sorted[pp];
            float ap[4] = {};
            if (MODE > 0){
#pragma unroll
              for (int q = 0; q < 4; q++) ap[q] = aprev[(size_t)pp * 4 + q];
            }
            float av[4] = {};
#pragma unroll
            for (int h = 0; h < H; h++){
              float v = el[s * H + h] + ern[h] + ee5[r * H + h];
              v = (v >= 0.f) ? v : 0.2f * v;
              float a = __expf(v - mh[h]) / sh[h];
              if (MODE == 1) a = 0.95f * a + 0.05f * ap[h];
              av[h] = a;
            }
            f32x4 o = {av[0], av[1], av[2], av[3]};
            *(f32x4*)(aout + (size_t)pp * 4) = o;
          }
        }
        for (int b = 0; b < cnt; b++){
          int pp = off + b; int s = src_sorted[pp]; int r = et_sorted[pp];
          const short* row = featb + (size_t)s * (H * 192);
          float apm[4] = {};
          if (MODE > 0){
#pragma unroll
            for (int q = 0; q < 4; q++) apm[q] = aprev[(size_t)pp * 4 + q];
          }
          if (act0){
            float v = el[s * H + h0] + ern[h0] + ee5[r * H + h0];
            v = (v >= 0.f) ? v : 0.2f * v;
            float a = __expf(v - mh[h0]) / sh[h0];
            if (MODE == 1) a = 0.95f * a + 0.05f * apm[h0];
            if (MODE == 2) a = 0.95f * a + 0.0125f * (apm[0] + apm[1] + apm[2] + apm[3]);
            s16x8 vv = *(const s16x8*)(row + c0 * 8);
#pragma unroll
            for (int i = 0; i < 8; i++) acc0[i] += a * bf2f(vv[i]);
          }
          if (act1){
            float v = el[s * H + h1] + ern[h1] + ee5[r * H + h1];
            v = (v >= 0.f) ? v : 0.2f * v;
            float a = __expf(v - mh[h1]) / sh[h1];
            if (MODE == 1) a = 0.95f * a + 0.05f * apm[h1];
            s16x8 vv = *(const s16x8*)(row + c1 * 8);
#pragma unroll
            for (int i = 0; i < 8; i++) acc1[i] += a * bf2f(vv[i]);
          }
        }
        if constexpr (H == 4){
#pragma unroll
          for (int i = 0; i < 8; i++){
            v0[i] = ACT ? elu1(acc0[i]) : acc0[i];
            if (lane < 32) v1[i] = ACT ? elu1(acc1[i]) : acc1[i];
          }
        } else {
          if (lane < 24){
#pragma unroll
            for (int i = 0; i < 8; i++) mbk[MB(lane, i)] = ACT ? elu1(acc0[i]) : acc0[i];
          }
        }
      }
      // ---- shared H==4 fallback epilogue: outb from regs + mean rounds ----
      if constexpr (H == 4){
        if (outb){
          {
            int c = lane, h = c / 24, rm = c % 24, t = rm >> 3, j = (rm & 7) * 8;
            s16x8 o;
#pragma unroll
            for (int i = 0; i < 8; i++) o[i] = f2bf(v0[i]);
            *(s16x8*)(outb + ((size_t)(t * NPAD) + n) * 256 + h * 64 + j) = o;
          }
          if (lane < 32){
            int c = lane + 64, h = c / 24, rm = c % 24, t = rm >> 3, j = (rm & 7) * 8;
            s16x8 o;
#pragma unroll
            for (int i = 0; i < 8; i++) o[i] = f2bf(v1[i]);
            *(s16x8*)(outb + ((size_t)(t * NPAD) + n) * 256 + h * 64 + j) = o;
          }
        }
        if (lane < 24){
#pragma unroll
          for (int i = 0; i < 8; i++) mbk[MB(lane, i)] = v0[i];
        }
        if (lane >= 24 && lane < 48){
#pragma unroll
          for (int i = 0; i < 8; i++) mbk[MB(lane - 24, i)] += v0[i];
        }
        if (lane >= 48){
#pragma unroll
          for (int i = 0; i < 8; i++) mbk[MB(lane - 48, i)] += v0[i];
        } else if (lane < 8){
#pragma unroll
          for (int i = 0; i < 8; i++) mbk[MB(lane + 16, i)] += v1[i];
        }
        if (lane >= 8 && lane < 32){
#pragma unroll
          for (int i = 0; i < 8; i++) mbk[MB(lane - 8, i)] += v1[i];
        }
      }
    }
  }

  // ---- final per-slot l2 norm from mb (per half-wave, node nme) ----
  const int cb8 = hl >> 3, ib = hl & 7;
  const float* mbh = mb[wid][half];
  for (int t = 0; t < 3; t++){
    float va = mbh[MB(t * 8 + cb8, ib)];
    float vb = mbh[MB(t * 8 + cb8 + 4, ib)];
    if constexpr (H == 4){ va *= 0.25f; vb *= 0.25f; }
    float ss = half_sum(va * va + vb * vb);
    float sc = 1.f / fmaxf(sqrtf(ss), 1e-12f);
    short* ob = o_b + (size_t)nme * 768 + t * 256 + kslice * 64;
    ob[hl] = f2bf(va * sc);
    ob[hl + 32] = f2bf(vb * sc);
  }
}

// ---------------- DistMult via MFMA ----------------
__global__ void distmult_mfma(const short* __restrict__ o_b, const short* __restrict__ Mt,
                              const int* __restrict__ pairs, const int* __restrict__ left,
                              const int* __restrict__ right, const int* __restrict__ mid,
                              float* __restrict__ score){
  const int pt = blockIdx.x, ct = blockIdx.y;
  const int tid = threadIdx.x;
  const int w = tid >> 6, lane = tid & 63;
  const int quad = lane >> 4, ln = lane & 15;
  __shared__ __attribute__((aligned(16))) short smem[8192];
  short* A_s = smem;
  short* B_s = smem + 2048;
  __shared__ int pid_s[64];
  __shared__ int lbase[64];
  if (tid < 64){
    int p = pairs[pt * 64 + tid];
    pid_s[tid] = p;
    lbase[tid] = (p >= 0) ? left[p] * 768 : 0;
  }
  __syncthreads();
  int p0 = pid_s[0];
  if (p0 < 0) return;
  const int r = mid[p0];
  const short* Mr = Mt + (size_t)r * 768 * 768;
  f32x4 acc[8] = {};
  for (int kk = 0; kk < 768; kk += 32){
    {
      int row = tid >> 2, chunk = tid & 3;
      s16x8 v = *(const s16x8*)(o_b + (size_t)lbase[row] + kk + chunk * 8);
      *(s16x8*)(A_s + row * 32 + chunk * 8) = v;
    }
    {
      int row = tid >> 1, half = tid & 1;
      const s16x8* g = (const s16x8*)(Mr + (size_t)(ct * 128 + row) * 768 + kk + half * 16);
      s16x8 v0 = g[0], v1 = g[1];
      *(s16x8*)(B_s + row * 32 + half * 16) = v0;
      *(s16x8*)(B_s + row * 32 + half * 16 + 8) = v1;
    }
    __syncthreads();
    s16x8 af = *(s16x8*)(A_s + (w * 16 + ln) * 32 + quad * 8);
#pragma unroll
    for (int b = 0; b < 8; b++){
      s16x8 bf = *(s16x8*)(B_s + (b * 16 + ln) * 32 + quad * 8);
      acc[b] = __builtin_amdgcn_mfma_f32_16x16x32_bf16(af, bf, acc[b], 0, 0, 0);
    }
    __syncthreads();
  }
  short* RE_s = smem;
  {
    int row = tid >> 2, quarter = tid & 3;
    int p = pid_s[row];
    s16x8 v0 = {}, v1 = {}, v2 = {}, v3 = {};
    if (p >= 0){
      const s16x8* g = (const s16x8*)(o_b + (size_t)right[p] * 768 + ct * 128 + quarter * 32);
      v0 = g[0]; v1 = g[1]; v2 = g[2]; v3 = g[3];
    }
    __syncthreads();
    short* dst = RE_s + row * 128 + quarter * 32;
    *(s16x8*)(dst)      = v0;
    *(s16x8*)(dst + 8)  = v1;
    *(s16x8*)(dst + 16) = v2;
    *(s16x8*)(dst + 24) = v3;
  }
  __syncthreads();
#pragma unroll
  for (int i = 0; i < 4; i++){
    int row = w * 16 + quad * 4 + i;
    float s = 0.f;
#pragma unroll
    for (int b = 0; b < 8; b++)
      s += acc[b][i] * bf2f(RE_s[row * 128 + b * 16 + ln]);
    s += __shfl_xor(s, 1); s += __shfl_xor(s, 2);
    s += __shfl_xor(s, 4); s += __shfl_xor(s, 8);
    if (ln == 0){
      int p = pid_s[row];
      if (p >= 0) atomicAdd(&score[p], s);
    }
  }
}

__global__ void sigmoid_k(const float* __restrict__ score, float* __restrict__ out){
  int i = blockIdx.x * 256 + threadIdx.x;
  if (i < N_PAIRS) out[i] = 1.f / (1.f + __expf(-score[i]));
}

// ---------------- launcher ----------------
extern "C" void kernel_launch(void* const* d_in, const int* in_sizes, int n_in,
                              void* d_out, int out_size, void* d_ws, size_t ws_size,
                              hipStream_t stream){
  const float* f0 = (const float*)d_in[0];
  const float* w0 = (const float*)d_in[1];
  const float* b0 = (const float*)d_in[2];
  const float* f1 = (const float*)d_in[3];
  const float* w1 = (const float*)d_in[4];
  const float* b1 = (const float*)d_in[5];
  const float* f2 = (const float*)d_in[6];
  const float* w2_ = (const float*)d_in[7];
  const float* b2 = (const float*)d_in[8];
  const float* lW[3]  = {(const float*)d_in[9],  (const float*)d_in[15], (const float*)d_in[21]};
  const float* lal[3] = {(const float*)d_in[10], (const float*)d_in[16], (const float*)d_in[22]};
  const float* lar[3] = {(const float*)d_in[11], (const float*)d_in[17], (const float*)d_in[23]};
  const float* lee[3] = {(const float*)d_in[12], (const float*)d_in[18], (const float*)d_in[24]};
  const float* lwe[3] = {(const float*)d_in[13], (const float*)d_in[19], (const float*)d_in[25]};
  const float* lae[3] = {(const float*)d_in[14], (const float*)d_in[20], (const float*)d_in[26]};
  const float* dmW = (const float*)d_in[27];
  const int* efeat = (const int*)d_in[28];
  const int* srcv  = (const int*)d_in[29];
  const int* dstv  = (const int*)d_in[30];
  const int* left  = (const int*)d_in[31];
  const int* right = (const int*)d_in[32];
  const int* midv  = (const int*)d_in[33];
  float* out = (float*)d_out;

  // ---- workspace layout ----
  short* feat_b = (short*)d_ws;               // 15,360,000 shorts
  float* aA     = (float*)(feat_b + 15360000);// 800,000
  float* aB     = aA + 800000;                // 800,000
  float* eall   = aB + 800000;                // 480,000
  float* ee5f   = eall + 480000;              // 96
  float* score  = ee5f + 96;                  // 10,016
  int* cnt3     = (int*)(score + 10016);      // 80,000  (per dst x 4: typed counts)
  int* csr_off  = cnt3 + 80000;               // 20,004
  int* csr_pos  = csr_off + 20004;            // 80,000  (per dst x 4: typed scatter cursors)
  int* loc      = csr_pos + 80000;            // 20,000
  int* bsum     = loc + 20000;                // 128
  int* bofs     = bsum + 128;                 // 128
  int* src_sorted = bofs + 128;               // 200,000
  int* et_sorted  = src_sorted + 200000;      // 200,000
  int* cnt5     = et_sorted + 200000;         // 80
  int* off5     = cnt5 + 80;                  // 8
  int* pos5     = off5 + 8;                   // 80
  int* pairs    = pos5 + 80;                  // 10,368
  short* o_b    = (short*)(pairs + PAIR_PAD); // 15,360,000
  short* Xb0    = o_b + 15360000;             // 3,858,432
  short* Xb12   = Xb0 + 3858432;              // 15,433,728
  short* Wt0    = Xb12 + 15433728;            // 49,152
  short* Wt1    = Wt0 + 49152;                // 196,608
  short* Wt2    = Wt1 + 196608;               // 49,152
  short* Mt     = Wt2 + 49152;                // 2,949,120
  float* elf0 = eall, *erf0 = eall + 80000;
  float* elf1 = eall + 160000, *erf1 = eall + 240000;
  float* elf2 = eall + 320000, *erf2 = eall + 400000;

  build_h<<<2500, 64, 0, stream>>>(f0, w0, b0, f1, w1, b1, f2, w2_, b2, Xb0, o_b,
                                   cnt3, cnt5, pos5, score, pairs, eall, Xb12, feat_b);
  count_prep_k<<<782 + 6336, 256, 0, stream>>>(dstv, srcv, cnt3, midv, cnt5,
                                               lW[0], lW[1], lW[2], dmW, Wt0, Wt1, Wt2, Mt,
                                               lee[0], lwe[0], lae[0], lee[1], lwe[1], lae[1],
                                               lee[2], lwe[2], lae[2], ee5f);
  scan1_k<<<NBLK, 256, 0, stream>>>(cnt3, loc, bsum);
  scan2_k<<<1, 128, 0, stream>>>(bsum, bofs, cnt5, off5);
  scan3_k<<<NBLK, 256, 0, stream>>>(loc, bofs, csr_off, csr_pos, cnt3);
  scatter_k<<<782, 256, 0, stream>>>(dstv, srcv, efeat, csr_pos, src_sorted, et_sorted,
                                     midv, off5, pos5, pairs);

  // layer 0 (H=4, typed proj tiles, typed slot-gather, ELU) -> emb slice 1
  // grid.x = 4 ct * 64-slot groups (per-t tile counts 63/48/48, guarded in-kernel)
  { dim3 g(256, 1, 3);
    mfma_proj<64, 256, 1><<<g, 256, 0, stream>>>(Xb0, Wt0, feat_b, lal[0], lar[0], elf0, erf0); }
  gat_fused<4, 0, 1, 1><<<2500, 256, 0, stream>>>(csr_off, src_sorted, et_sorted, elf0, erf0, ee5f,
                                                  nullptr, aA, feat_b, Xb12, o_b, cnt3, 1);

  // layer 1 (H=4, residual aA, ELU) -> emb slice 2
  // grid.x = 4 ct * 160 (157 tiles padded to 160; XCD-affine swizzle in-kernel)
  { dim3 g(640, 1, 3);
    mfma_proj<256, 256, 0><<<g, 256, 0, stream>>>(Xb12, Wt1, feat_b, lal[1], lar[1], elf1, erf1); }
  gat_fused<4, 1, 1, 0><<<2500, 256, 0, stream>>>(csr_off, src_sorted, et_sorted, elf1, erf1, ee5f + 32,
                                                  aA, aB, feat_b, Xb12, o_b, cnt3, 2);

  // layer 2 (H=1, blend vs mean of a1, no activation) -> emb slice 3
  { dim3 g(157, 1, 3);
    mfma_proj<256, 64, 0><<<g, 256, 0, stream>>>(Xb12, Wt2, feat_b, lal[2], lar[2], elf2, erf2); }
  gat_fused<1, 2, 0, 0><<<2500, 256, 0, stream>>>(csr_off, src_sorted, et_sorted, elf2, erf2, ee5f + 64,
                                                  aB, nullptr, feat_b, nullptr, o_b, cnt3, 3);

  // DistMult + sigmoid
  { dim3 g(DM_TILES, 6); distmult_mfma<<<g, 256, 0, stream>>>(o_b, Mt, pairs, left, right, midv, score); }
  sigmoid_k<<<40, 256, 0, stream>>>(score, out);
}

// Round 8
// 438.450 us; speedup vs baseline: 1.0336x; 1.0132x over previous
//
#include <hip/hip_runtime.h>
#include <math.h>

// ---------------- constants ----------------
#define N_NODES 20000
#define NPAD    20096          // 157*128
#define N_EDGES 200000
#define N_PAIRS 10000
#define PAIR_PAD 10368         // 162*64
#define DM_TILES 162
#define NBLK    79             // 79*256 = 20224 >= N_NODES

typedef __attribute__((ext_vector_type(8))) short s16x8;
typedef __attribute__((ext_vector_type(4))) float f32x4;

__device__ inline float wave_max(float v){
  for (int o = 32; o > 0; o >>= 1) v = fmaxf(v, __shfl_xor(v, o));
  return v;
}
__device__ inline float wave_sum(float v){
  for (int o = 32; o > 0; o >>= 1) v += __shfl_xor(v, o);
  return v;
}
__device__ inline float half_max(float v){
  for (int o = 16; o > 0; o >>= 1) v = fmaxf(v, __shfl_xor(v, o));
  return v;
}
__device__ inline float half_sum(float v){
  for (int o = 16; o > 0; o >>= 1) v += __shfl_xor(v, o);
  return v;
}
__device__ inline short f2bf(float x){
  union { float f; unsigned u; } v; v.f = x;
  unsigned r = (v.u + 0x7FFFu + ((v.u >> 16) & 1u)) >> 16;
  return (short)r;
}
__device__ inline float bf2f(short s){
  union { unsigned u; float f; } v; v.u = ((unsigned)(unsigned short)s) << 16;
  return v.f;
}
__device__ inline int ntype(int s){ return (s < 8000) ? 0 : ((s < 14000) ? 1 : 2); }
__device__ inline float elu1(float x){ return (x > 0.f) ? x : expm1f(x); }

// mean/norm buffer slot: chunk-in-head c24 (0..23), elem i (0..7); stride 9 -> conflict-free
#define MB(c24, i) ((c24) * 9 + (i))

// ---------------- input linears (8 nodes/block) + ALL workspace zeroing + o_b slice 0 ----------------
__global__ void build_h(const float* __restrict__ f0, const float* __restrict__ w0, const float* __restrict__ b0,
                        const float* __restrict__ f1, const float* __restrict__ w1, const float* __restrict__ b1,
                        const float* __restrict__ f2, const float* __restrict__ w2, const float* __restrict__ b2,
                        short* __restrict__ Xb0, short* __restrict__ o_b,
                        int* __restrict__ cnt3, int* __restrict__ cnt5, int* __restrict__ pos5,
                        float* __restrict__ score, int* __restrict__ pairs,
                        float* __restrict__ eall, short* __restrict__ Xb12,
                        short* __restrict__ featb){
  const int blk = blockIdx.x, lane = threadIdx.x;
  const int gid = blk * 64 + lane;             // 0..159999
  // ---- zeroing (spread across grid) ----
  if (gid < 80000) cnt3[gid] = 0;
  if (gid < 5){ cnt5[gid * 16] = 0; pos5[gid * 16] = 0; }
  if (gid < 10016) score[gid] = 0.f;
  if (gid < PAIR_PAD) pairs[gid] = -1;
  for (int i = gid; i < 480000; i += 160000) eall[i] = 0.f;
  s16x8 z = {};
  if (gid < 4608){  // Xb12 pad rows: 3 * 96 * 256 shorts
    int t = (gid * 16) / 24576, off = (gid * 16) % 24576;
    short* p = Xb12 + ((size_t)(t * NPAD + N_NODES)) * 256 + off;
    *(s16x8*)p = z; *(s16x8*)(p + 8) = z;
  }
  if (gid < 1152){  // Xb0 pad rows
    int t = (gid * 16) / 6144, off = (gid * 16) % 6144;
    short* p = Xb0 + ((size_t)(t * NPAD + N_NODES)) * 64 + off;
    *(s16x8*)p = z; *(s16x8*)(p + 8) = z;
  }
  // ---- per-block type ----
  int t, C, nbase; const float *f, *w, *b;
  if (blk < 1000)       { t = 0; nbase = 0;     C = 256; f = f0; w = w0; b = b0; }
  else if (blk < 1750)  { t = 1; nbase = 8000;  C = 128; f = f1; w = w1; b = b1; }
  else                  { t = 2; nbase = 14000; C = 64;  f = f2; w = w2; b = b2; }
  const int n0 = blk * 8;
  const int n0l = n0 - nbase;
  __shared__ float xs[8 * 256];
  const float* fr = f + (size_t)n0l * C;
  for (int i = lane; i < 8 * C; i += 64) xs[i] = fr[i];
  __syncthreads();
  float acc[8];
#pragma unroll
  for (int j = 0; j < 8; j++) acc[j] = b[lane];
  for (int c = 0; c < C; c++){
    float wv = w[c * 64 + lane];
#pragma unroll
    for (int j = 0; j < 8; j++) acc[j] += xs[j * C + c] * wv;
  }
  for (int j = 0; j < 8; j++){
    int n = n0 + j;
    // off-slot feat_b zero (layer-0 typed proj skips those tiles; cnt>64 fallback reads full rows)
    {
      int h = lane >> 4, si = (lane >> 3) & 1, j8 = lane & 7;
      int s0 = (t == 0) ? 1 : 0;
      int s1 = (t == 2) ? 1 : 2;
      int toff = si ? s1 : s0;
      *(s16x8*)(featb + ((size_t)n * 4 + h) * 192 + toff * 64 + j8 * 8) = z;
    }
    for (int tt = 0; tt < 3; tt++)
      Xb0[((size_t)(tt * NPAD) + n) * 64 + lane] = f2bf((tt == t) ? acc[j] : 0.f);
    float ss = wave_sum(acc[j] * acc[j]);
    float sc = 1.f / fmaxf(sqrtf(ss), 1e-12f);
    for (int tt = 0; tt < 3; tt++)
      o_b[(size_t)n * 768 + tt * 256 + lane] = f2bf((tt == t) ? acc[j] * sc : 0.f);
  }
}

// ---------------- merged: typed edge/pair counting (blocks 0..781) + weight prep ----------------
__global__ void count_prep_k(const int* __restrict__ dst, const int* __restrict__ srcv,
                             int* __restrict__ cnt3,
                             const int* __restrict__ mid, int* __restrict__ cnt5,
                             const float* __restrict__ lW0, const float* __restrict__ lW1,
                             const float* __restrict__ lW2, const float* __restrict__ dmW,
                             short* __restrict__ Wt0, short* __restrict__ Wt1,
                             short* __restrict__ Wt2, short* __restrict__ Mt,
                             const float* __restrict__ ee0, const float* __restrict__ we0, const float* __restrict__ ae0,
                             const float* __restrict__ ee1, const float* __restrict__ we1, const float* __restrict__ ae1,
                             const float* __restrict__ ee2, const float* __restrict__ we2, const float* __restrict__ ae2,
                             float* __restrict__ ee5f){
  if (blockIdx.x < 782){
    int e = blockIdx.x * 256 + threadIdx.x;
    int lane = threadIdx.x & 63;
    if (e < N_EDGES){
      int tt = ntype(srcv[e]);
      atomicAdd(&cnt3[dst[e] * 4 + tt], 1);
    }
    int r_mine = (e < N_PAIRS) ? mid[e] : -1;
#pragma unroll
    for (int r = 0; r < 5; r++){
      unsigned long long mask = __ballot(r_mine == r);
      if (mask){
        int leader = __ffsll((long long)mask) - 1;
        if (lane == leader) atomicAdd(&cnt5[r * 16], __popcll(mask));
      }
    }
    return;
  }
  int lin = blockIdx.x - 782;
  int z = lin / 576;
  int rem = lin % 576;
  int by = rem / 24, bx = rem % 24;
  if (z == 10){
    int r = bx, L = by;
    if (r >= 5 || L >= 3) return;
    int H = (L == 2) ? 1 : 4;
    const float* eetab = (L == 0) ? ee0 : ((L == 1) ? ee1 : ee2);
    const float* We    = (L == 0) ? we0 : ((L == 1) ? we1 : we2);
    const float* ae    = (L == 0) ? ae0 : ((L == 1) ? ae1 : ae2);
    int h = threadIdx.x >> 6, lane = threadIdx.x & 63;
    if (h >= H) return;
    float v = 0.f;
    for (int k = 0; k < 64; k++) v += eetab[r * 64 + k] * We[k * H * 64 + h * 64 + lane];
    v *= ae[h * 64 + lane];
    v = wave_sum(v);
    if (lane == 0) ee5f[L * 32 + r * H + h] = v;
    return;
  }
  const float* s; short* d; int R, Cc, r0, c0;
  if (z < 5){
    s = dmW + (size_t)z * 589824; d = Mt + (size_t)z * 589824;
    R = 768; Cc = 768; r0 = bx * 32; c0 = by * 32;
  } else if (z < 8){
    if (bx >= 8 || by >= 8) return;
    int t = z - 5;
    s = lW1 + (size_t)t * 65536; d = Wt1 + (size_t)t * 65536;
    R = 256; Cc = 256; r0 = bx * 32; c0 = by * 32;
  } else if (z == 8){
    if (bx >= 6 || by >= 8) return;
    int t = bx >> 1;
    s = lW0 + (size_t)t * 16384; d = Wt0 + (size_t)t * 16384;
    R = 64; Cc = 256; r0 = (bx & 1) * 32; c0 = by * 32;
  } else {
    if (bx >= 8 || by >= 6) return;
    int t = by >> 1;
    s = lW2 + (size_t)t * 16384; d = Wt2 + (size_t)t * 16384;
    R = 256; Cc = 64; r0 = bx * 32; c0 = (by & 1) * 32;
  }
  __shared__ float tile[32][33];
  int tx = threadIdx.x & 31, ty = threadIdx.x >> 5;
  for (int i = 0; i < 32; i += 8){
    int r = r0 + ty + i;
    tile[ty + i][tx] = (r < R && c0 + tx < Cc) ? s[(size_t)r * Cc + c0 + tx] : 0.f;
  }
  __syncthreads();
  for (int i = 0; i < 32; i += 8){
    int c = c0 + ty + i;
    if (c < Cc && r0 + tx < R)
      d[(size_t)c * R + r0 + tx] = f2bf(tile[tx][ty + i]);
  }
}

// ---------------- hierarchical scan ----------------
__global__ void scan1_k(const int* __restrict__ cnt3, int* __restrict__ loc, int* __restrict__ bsum){
  __shared__ int s[256];
  int tid = threadIdx.x;
  int idx = blockIdx.x * 256 + tid;
  int v = (idx < N_NODES) ? (cnt3[idx * 4] + cnt3[idx * 4 + 1] + cnt3[idx * 4 + 2]) : 0;
  s[tid] = v;
  __syncthreads();
  for (int o = 1; o < 256; o <<= 1){
    int u = (tid >= o) ? s[tid - o] : 0;
    __syncthreads();
    s[tid] += u;
    __syncthreads();
  }
  if (idx < N_NODES) loc[idx] = s[tid] - v;
  if (tid == 255) bsum[blockIdx.x] = s[255];
}

__global__ void scan2_k(const int* __restrict__ bsum, int* __restrict__ bofs,
                        const int* __restrict__ cnt5, int* __restrict__ off5){
  __shared__ int s[128];
  int tid = threadIdx.x;
  int v = (tid < NBLK) ? bsum[tid] : 0;
  s[tid] = v;
  __syncthreads();
  for (int o = 1; o < 128; o <<= 1){
    int u = (tid >= o) ? s[tid - o] : 0;
    __syncthreads();
    s[tid] += u;
    __syncthreads();
  }
  if (tid < NBLK) bofs[tid] = s[tid] - v;
  if (tid == 0){
    int r0 = 0;
    for (int r = 0; r < 5; r++){ off5[r] = r0; r0 += ((cnt5[r * 16] + 63) >> 6) << 6; }
  }
}

__global__ void scan3_k(const int* __restrict__ loc, const int* __restrict__ bofs,
                        int* __restrict__ coff, int* __restrict__ cpos,
                        const int* __restrict__ cnt3){
  int idx = blockIdx.x * 256 + threadIdx.x;
  if (idx < N_NODES){
    int v = loc[idx] + bofs[blockIdx.x];
    coff[idx] = v;
    int c0 = cnt3[idx * 4], c1 = cnt3[idx * 4 + 1];
    cpos[idx * 4]     = v;
    cpos[idx * 4 + 1] = v + c0;
    cpos[idx * 4 + 2] = v + c0 + c1;
  }
  if (idx == 0) coff[N_NODES] = N_EDGES;
}

__global__ void scatter_k(const int* __restrict__ dst, const int* __restrict__ srcv,
                          const int* __restrict__ efeat, int* __restrict__ cpos,
                          int* __restrict__ src_sorted, int* __restrict__ et_sorted,
                          const int* __restrict__ mid, const int* __restrict__ off5,
                          int* __restrict__ pos5, int* __restrict__ pairs){
  int e = blockIdx.x * 256 + threadIdx.x;
  int lane = threadIdx.x & 63;
  if (e < N_EDGES){
    int s = srcv[e];
    int tt = ntype(s);
    int p = atomicAdd(&cpos[dst[e] * 4 + tt], 1);
    src_sorted[p] = s;
    et_sorted[p] = efeat[e];
  }
  int r_mine = (e < N_PAIRS) ? mid[e] : -1;
#pragma unroll
  for (int r = 0; r < 5; r++){
    unsigned long long mask = __ballot(r_mine == r);
    if (mask){
      int cnt = __popcll(mask);
      int leader = __ffsll((long long)mask) - 1;
      int base = 0;
      if (lane == leader) base = atomicAdd(&pos5[r * 16], cnt);
      base = __shfl(base, leader);
      if (r_mine == r){
        int rank = __popcll(mask & ((1ull << lane) - 1ull));
        pairs[off5[r] + base + rank] = e;
      }
    }
  }
}

// ---------------- MFMA slot projection -> bf16 feat + fused el/er partials ----------------
// One ct per block (36 VGPR, high occupancy). The (tile, ct) encoding in blockIdx.x puts all
// 4 ct-instances of a tile at the SAME residue mod 8 -> same XCD -> A tile hits L2 3 of 4 times.
// LDS rows padded to 40 shorts (80 B) to spread banks on b128 reads/writes.
#define LDA 40
template<int C, int NO, int TYPED>
__global__ void mfma_proj(const short* __restrict__ Xb, const short* __restrict__ Wt,
                          short* __restrict__ featb, const float* __restrict__ al,
                          const float* __restrict__ ar, float* __restrict__ elf,
                          float* __restrict__ erf){
  constexpr int H = NO / 64;
  const int t = blockIdx.z;
  int tile, ct;
  if constexpr (H == 4){
    const int x = blockIdx.x;            // grp*32 + ct*8 + slot
    const int grp = x >> 5, sub = x & 31;
    ct = sub >> 3;
    tile = grp * 8 + (sub & 7);
  } else { tile = blockIdx.x; ct = 0; }
  if constexpr (TYPED){
    const int lo[3] = {0, 62, 109};
    const int hi[3] = {63, 110, 157};
    if (tile >= hi[t] - lo[t]) return;
    tile += lo[t];
  } else {
    if (tile >= NPAD / 128) return;
  }
  const int n0 = tile * 128;
  const int tid = threadIdx.x;
  const int w = tid >> 6, lane = tid & 63;
  const int quad = lane >> 4, ln = lane & 15;
  __shared__ __attribute__((aligned(16))) short A_s[128 * LDA];
  __shared__ __attribute__((aligned(16))) short B_s[64 * LDA];
  const short* Xt  = Xb + (size_t)t * NPAD * C;
  const short* Wtt = Wt + ((size_t)t * NO + ct * 64) * C;
  f32x4 acc[2][4] = {};
  for (int kk = 0; kk < C; kk += 32){
    {
      int row = tid >> 1, hk = tid & 1;
      const s16x8* g = (const s16x8*)(Xt + (size_t)(n0 + row) * C + kk + hk * 16);
      s16x8 v0 = g[0], v1 = g[1];
      *(s16x8*)(A_s + row * LDA + hk * 16) = v0;
      *(s16x8*)(A_s + row * LDA + hk * 16 + 8) = v1;
    }
    {
      int row = tid >> 2, chunk = tid & 3;
      s16x8 v = *(const s16x8*)(Wtt + (size_t)row * C + kk + chunk * 8);
      *(s16x8*)(B_s + row * LDA + chunk * 8) = v;
    }
    __syncthreads();
    s16x8 af0 = *(s16x8*)(A_s + (w * 32 + ln) * LDA + quad * 8);
    s16x8 af1 = *(s16x8*)(A_s + (w * 32 + 16 + ln) * LDA + quad * 8);
    s16x8 bf[4];
#pragma unroll
    for (int b = 0; b < 4; b++) bf[b] = *(s16x8*)(B_s + (b * 16 + ln) * LDA + quad * 8);
#pragma unroll
    for (int b = 0; b < 4; b++){
      acc[0][b] = __builtin_amdgcn_mfma_f32_16x16x32_bf16(af0, bf[b], acc[0][b], 0, 0, 0);
      acc[1][b] = __builtin_amdgcn_mfma_f32_16x16x32_bf16(af1, bf[b], acc[1][b], 0, 0, 0);
    }
    __syncthreads();
  }
#pragma unroll
  for (int ar_ = 0; ar_ < 2; ar_++){
#pragma unroll
    for (int i = 0; i < 4; i++){
      int n = n0 + w * 32 + ar_ * 16 + quad * 4 + i;
      if (n >= N_NODES) continue;
#pragma unroll
      for (int b = 0; b < 4; b++){
        int jj = b * 16 + ln;
        featb[((size_t)n * H + ct) * 192 + t * 64 + jj] = f2bf(acc[ar_][b][i]);
      }
    }
  }
  float alv[4], arv[4];
#pragma unroll
  for (int b = 0; b < 4; b++){
    alv[b] = al[ct * 192 + t * 64 + b * 16 + ln];
    arv[b] = ar[ct * 192 + t * 64 + b * 16 + ln];
  }
#pragma unroll
  for (int ar_ = 0; ar_ < 2; ar_++){
#pragma unroll
    for (int i = 0; i < 4; i++){
      float pe = 0.f, pr = 0.f;
#pragma unroll
      for (int b = 0; b < 4; b++){
        pe += acc[ar_][b][i] * alv[b];
        pr += acc[ar_][b][i] * arv[b];
      }
#pragma unroll
      for (int o = 1; o < 16; o <<= 1){
        pe += __shfl_xor(pe, o);
        pr += __shfl_xor(pr, o);
      }
      int n = n0 + w * 32 + ar_ * 16 + quad * 4 + i;
      if (ln == 0 && n < N_NODES){
        atomicAdd(&elf[n * H + ct], pe);
        atomicAdd(&erf[n * H + ct], pr);
      }
    }
  }
}

// ---------------- fused softmax + gather aggregation + emb: 2 nodes per wave ----------------
// outb stored directly from registers; per-slot l2-norm via small mb buffer (wave-ordered rounds).
// Gather loops unrolled for memory-level parallelism (12 / 6 / 6 loads in flight).
// __launch_bounds__(256, 4): min 4 waves/EU -> VGPR budget 128, letting the unrolled loads
// actually hold 12 s16x8 destinations in registers (round-7's cap at 60 VGPR serialized them).
template<int H, int MODE, int ACT, int TYPED>
__global__ __launch_bounds__(256, 4) void gat_fused(
    const int* __restrict__ csr_off, const int* __restrict__ src_sorted,
    const int* __restrict__ et_sorted,
    const float* __restrict__ el, const float* __restrict__ er, const float* __restrict__ ee5,
    const float* __restrict__ aprev, float* __restrict__ aout,
    const short* __restrict__ featb, short* __restrict__ outb,
    short* __restrict__ o_b, const int* __restrict__ cnt3, int kslice){
  const int wid = threadIdx.x >> 6, lane = threadIdx.x & 63;
  const int half = lane >> 5, hl = lane & 31;
  const int l32 = half << 5;
  const int n0 = blockIdx.x * 8 + wid * 2;        // wave owns nodes n0, n0+1; grid exact
  const int nme = n0 + half;                      // this half-wave's node
  __shared__ float a_s[4][64][H];
  __shared__ int   src_s[4][64];                  // pre-multiplied BYTE offsets into featb
  __shared__ float mb[4][2][216];                 // head-sum buffer, MB(c24,i) layout
  const char* fb = (const char*)featb;

  const int offm = csr_off[nme];
  const int cntm = csr_off[nme + 1] - offm;
  const int cnto = __shfl_xor(cntm, 32);
  const bool paired = (cntm <= 32) && (cnto <= 32);

  if (paired){
    // ---- softmax: edge e of node nme at lane l32+e ----
    float ern[H];
    if constexpr (H == 4){
      f32x4 ev = *(const f32x4*)(er + nme * 4);
#pragma unroll
      for (int h = 0; h < 4; h++) ern[h] = ev[h];
    } else ern[0] = er[nme];
    const int p = offm + hl;
    const bool valid = hl < cntm;
    int sidx = 0, r = 0;
    if (valid){ sidx = src_sorted[p]; r = et_sorted[p]; }
    int s0 = __shfl(sidx, l32);
    src_s[wid][lane] = (valid ? sidx : s0) * (H * 384);
    float lg[H];
#pragma unroll
    for (int h = 0; h < H; h++) lg[h] = -1e30f;
    if (valid){
      if constexpr (H == 4){
        f32x4 elv = *(const f32x4*)(el + sidx * 4);
        f32x4 eev = *(const f32x4*)(ee5 + r * 4);
#pragma unroll
        for (int h = 0; h < 4; h++){
          float v = elv[h] + ern[h] + eev[h];
          lg[h] = (v >= 0.f) ? v : 0.2f * v;
        }
      } else {
        float v = el[sidx] + ern[0] + ee5[r];
        lg[0] = (v >= 0.f) ? v : 0.2f * v;
      }
    }
    float ap[4] = {};
    if (MODE > 0 && valid){
      f32x4 av4 = *(const f32x4*)(aprev + (size_t)p * 4);
#pragma unroll
      for (int q = 0; q < 4; q++) ap[q] = av4[q];
    }
    float av[H];
#pragma unroll
    for (int h = 0; h < H; h++){
      float mh = half_max(lg[h]);
      float ex = valid ? __expf(lg[h] - mh) : 0.f;
      float sh = half_sum(ex);
      float a = ex / sh;
      if (MODE == 1) a = 0.95f * a + 0.05f * ap[h];
      if (MODE == 2) a = 0.95f * a + 0.0125f * (ap[0] + ap[1] + ap[2] + ap[3]);
      av[h] = a;
      a_s[wid][lane][h] = valid ? a : 0.f;
    }
    if constexpr (MODE != 2){
      if (valid){
        f32x4 o = {av[0], av[1], av[2], av[3]};
        *(f32x4*)(aout + (size_t)p * 4) = o;
      }
    }

    if constexpr (TYPED && H == 4){
      // ---- layer 0: slot-sparse rows; one 2-edge segment per type per iter (6 loads in flight) ----
      const int hh = hl >> 3, j8 = hl & 7;
      const int sub = hh * 384 + j8 * 16;
      float acc[3][8] = {};
      const int b1 = cnt3[nme * 4], b2 = b1 + cnt3[nme * 4 + 1];
      const int base_[3] = {0, b1, b2};
      const int lim_[3]  = {b1, b2, cntm};
      int maxrun = lim_[0] - base_[0];
      maxrun = max(maxrun, lim_[1] - base_[1]);
      maxrun = max(maxrun, lim_[2] - base_[2]);
      for (int b = 0; b < maxrun; b += 2){
        int i0[3], i1[3]; float a0[3], a1[3];
#pragma unroll
        for (int t = 0; t < 3; t++){
          int e0 = base_[t] + b, e1 = e0 + 1;
          bool v0 = e0 < lim_[t], v1 = e1 < lim_[t];
          i0[t] = v0 ? e0 : 0; i1[t] = v1 ? e1 : 0;
          a0[t] = v0 ? a_s[wid][l32 + i0[t]][hh] : 0.f;
          a1[t] = v1 ? a_s[wid][l32 + i1[t]][hh] : 0.f;
        }
        s16x8 f0[3], f1[3];
#pragma unroll
        for (int t = 0; t < 3; t++){
          f0[t] = *(const s16x8*)(fb + src_s[wid][l32 + i0[t]] + sub + t * 128);
          f1[t] = *(const s16x8*)(fb + src_s[wid][l32 + i1[t]] + sub + t * 128);
        }
#pragma unroll
        for (int t = 0; t < 3; t++)
#pragma unroll
          for (int i = 0; i < 8; i++)
            acc[t][i] += a0[t] * bf2f(f0[t][i]) + a1[t] * bf2f(f1[t][i]);
      }
#pragma unroll
      for (int t = 0; t < 3; t++){
        if (ACT){
#pragma unroll
          for (int i = 0; i < 8; i++) acc[t][i] = elu1(acc[t][i]);
        }
        if (outb){
          s16x8 o;
#pragma unroll
          for (int i = 0; i < 8; i++) o[i] = f2bf(acc[t][i]);
          *(s16x8*)(outb + ((size_t)(t * NPAD) + nme) * 256 + hh * 64 + j8 * 8) = o;
        }
      }
      // mean rounds by head (chunk c = hh*24 + t*8 + j8 -> c24 = t*8 + j8)
#pragma unroll
      for (int rr = 0; rr < 4; rr++){
        if (hh == rr){
#pragma unroll
          for (int t = 0; t < 3; t++)
#pragma unroll
            for (int i = 0; i < 8; i++){
              if (rr == 0) mb[wid][half][MB(t * 8 + j8, i)] = acc[t][i];
              else         mb[wid][half][MB(t * 8 + j8, i)] += acc[t][i];
            }
        }
      }
    } else if constexpr (H == 4){
      // ---- dense rows: 96 chunks / 32 lanes = 3/lane, 4 edges/iter (12 loads in flight) ----
      const int p0 = hl, p1 = hl + 32, p2 = hl + 64;
      const int h0 = p0 / 24, h1 = p1 / 24, h2 = p2 / 24;
      float acc0[8] = {}, acc1[8] = {}, acc2[8] = {};
      const int cnt4m = (cntm + 3) & ~3;
      for (int b = 0; b < cnt4m; b += 4){
        int e0 = l32 + b;
        int so0 = src_s[wid][e0],     so1 = src_s[wid][e0 + 1];
        int so2 = src_s[wid][e0 + 2], so3 = src_s[wid][e0 + 3];
        float a00 = a_s[wid][e0][h0],     a01 = a_s[wid][e0][h1],     a02 = a_s[wid][e0][h2];
        float a10 = a_s[wid][e0 + 1][h0], a11 = a_s[wid][e0 + 1][h1], a12 = a_s[wid][e0 + 1][h2];
        float a20 = a_s[wid][e0 + 2][h0], a21 = a_s[wid][e0 + 2][h1], a22 = a_s[wid][e0 + 2][h2];
        float a30 = a_s[wid][e0 + 3][h0], a31 = a_s[wid][e0 + 3][h1], a32 = a_s[wid][e0 + 3][h2];
        s16x8 f00 = *(const s16x8*)(fb + so0 + p0 * 16);
        s16x8 f01 = *(const s16x8*)(fb + so0 + p1 * 16);
        s16x8 f02 = *(const s16x8*)(fb + so0 + p2 * 16);
        s16x8 f10 = *(const s16x8*)(fb + so1 + p0 * 16);
        s16x8 f11 = *(const s16x8*)(fb + so1 + p1 * 16);
        s16x8 f12 = *(const s16x8*)(fb + so1 + p2 * 16);
        s16x8 f20 = *(const s16x8*)(fb + so2 + p0 * 16);
        s16x8 f21 = *(const s16x8*)(fb + so2 + p1 * 16);
        s16x8 f22 = *(const s16x8*)(fb + so2 + p2 * 16);
        s16x8 f30 = *(const s16x8*)(fb + so3 + p0 * 16);
        s16x8 f31 = *(const s16x8*)(fb + so3 + p1 * 16);
        s16x8 f32_ = *(const s16x8*)(fb + so3 + p2 * 16);
#pragma unroll
        for (int i = 0; i < 8; i++){
          acc0[i] += a00 * bf2f(f00[i]) + a10 * bf2f(f10[i]) + a20 * bf2f(f20[i]) + a30 * bf2f(f30[i]);
          acc1[i] += a01 * bf2f(f01[i]) + a11 * bf2f(f11[i]) + a21 * bf2f(f21[i]) + a31 * bf2f(f31[i]);
          acc2[i] += a02 * bf2f(f02[i]) + a12 * bf2f(f12[i]) + a22 * bf2f(f22[i]) + a32 * bf2f(f32_[i]);
        }
      }
      if (ACT){
#pragma unroll
        for (int i = 0; i < 8; i++){
          acc0[i] = elu1(acc0[i]); acc1[i] = elu1(acc1[i]); acc2[i] = elu1(acc2[i]);
        }
      }
      if (outb){
#pragma unroll
        for (int cc = 0; cc < 3; cc++){
          int c = hl + cc * 32;
          const float* vv = (cc == 0) ? acc0 : ((cc == 1) ? acc1 : acc2);
          int h = c / 24, rm = c % 24, t = rm >> 3, j = (rm & 7) * 8;
          s16x8 o;
#pragma unroll
          for (int i = 0; i < 8; i++) o[i] = f2bf(vv[i]);
          *(s16x8*)(outb + ((size_t)(t * NPAD) + nme) * 256 + h * 64 + j) = o;
        }
      }
      // mean rounds by head
      float* mbh = mb[wid][half];
      if (hl < 24){
#pragma unroll
        for (int i = 0; i < 8; i++) mbh[MB(hl, i)] = acc0[i];
      }
      if (hl >= 24){
#pragma unroll
        for (int i = 0; i < 8; i++) mbh[MB(hl - 24, i)] += acc0[i];
      } else if (hl < 16){
#pragma unroll
        for (int i = 0; i < 8; i++) mbh[MB(hl + 8, i)] += acc1[i];
      }
      if (hl >= 16){
#pragma unroll
        for (int i = 0; i < 8; i++) mbh[MB(hl - 16, i)] += acc1[i];
      } else if (hl < 8){
#pragma unroll
        for (int i = 0; i < 8; i++) mbh[MB(hl + 16, i)] += acc2[i];
      }
      if (hl >= 8){
#pragma unroll
        for (int i = 0; i < 8; i++) mbh[MB(hl - 8, i)] += acc2[i];
      }
    } else {
      // ---- H == 1: 8 edges/iter x 3 chunks/lane over 8-lane groups (6 loads in flight) ----
      const int e4 = hl >> 3, cb = hl & 7;
      float acc[3][8] = {};
      for (int b = 0; b < cntm; b += 8){
        int i0 = b + e4, i1 = b + 4 + e4;        // <= 31 always; pads a_s==0
        float a0 = a_s[wid][l32 + i0][0];
        float a1 = a_s[wid][l32 + i1][0];
        int so0 = src_s[wid][l32 + i0], so1 = src_s[wid][l32 + i1];
        s16x8 f0[3], f1[3];
#pragma unroll
        for (int c = 0; c < 3; c++){
          f0[c] = *(const s16x8*)(fb + so0 + (cb * 3 + c) * 16);
          f1[c] = *(const s16x8*)(fb + so1 + (cb * 3 + c) * 16);
        }
#pragma unroll
        for (int c = 0; c < 3; c++)
#pragma unroll
          for (int i = 0; i < 8; i++)
            acc[c][i] += a0 * bf2f(f0[c][i]) + a1 * bf2f(f1[c][i]);
      }
#pragma unroll
      for (int c = 0; c < 3; c++){
#pragma unroll
        for (int i = 0; i < 8; i++){
          float v = acc[c][i];
          v += __shfl_xor(v, 8); v += __shfl_xor(v, 16);
          if (ACT) v = elu1(v);
          if (e4 == 0) mb[wid][half][MB(cb * 3 + c, i)] = v;
        }
      }
    }
  } else {
    // ---- rare fallback: process both nodes sequentially with the full wave ----
    for (int k = 0; k < 2; k++){
      const int n = n0 + k;
      const int off = csr_off[n];
      const int cnt = csr_off[n + 1] - off;
      float* mbk = mb[wid][k];
      float v0[8], v1[8];
      float ern[H];
#pragma unroll
      for (int h = 0; h < H; h++) ern[h] = er[n * H + h];
      if (cnt <= 64){
        int p = off + lane;
        int sidx = 0, r = 0;
        if (lane < cnt){ sidx = src_sorted[p]; r = et_sorted[p]; }
        int src0 = __shfl(sidx, 0);
        src_s[wid][lane] = ((lane < cnt) ? sidx : src0) * (H * 384);
        float lg[H];
#pragma unroll
        for (int h = 0; h < H; h++) lg[h] = -1e30f;
        if (lane < cnt){
#pragma unroll
          for (int h = 0; h < H; h++){
            float v = el[sidx * H + h] + ern[h] + ee5[r * H + h];
            lg[h] = (v >= 0.f) ? v : 0.2f * v;
          }
        }
        float ap[4] = {};
        if (MODE > 0 && lane < cnt){
#pragma unroll
          for (int q = 0; q < 4; q++) ap[q] = aprev[(size_t)p * 4 + q];
        }
        float av[H];
#pragma unroll
        for (int h = 0; h < H; h++){
          float mh = wave_max(lg[h]);
          float ex = (lane < cnt) ? __expf(lg[h] - mh) : 0.f;
          float sh = wave_sum(ex);
          float a = ex / sh;
          if (MODE == 1) a = 0.95f * a + 0.05f * ap[h];
          if (MODE == 2) a = 0.95f * a + 0.0125f * (ap[0] + ap[1] + ap[2] + ap[3]);
          av[h] = a;
          a_s[wid][lane][h] = (lane < cnt) ? a : 0.f;
        }
        if constexpr (MODE != 2){
          if (lane < cnt){
            f32x4 o = {av[0], av[1], av[2], av[3]};
            *(f32x4*)(aout + (size_t)p * 4) = o;
          }
        }
        if constexpr (H == 4){
          const int p0 = lane;
          const int p1 = (lane < 32) ? lane + 64 : lane - 32;
          const int p2 = lane + 32;
          const int hA = p0 / 24, hB = p1 / 24, hC = p2 / 24;
          const int eo2 = lane >> 5;
          float acc0[8] = {}, acc1[8] = {}, acc2[8] = {};
          const int cnt4 = (cnt + 3) & ~3;
          for (int b = 0; b < cnt4; b += 4){
            int eB0 = b + eo2, eB1 = b + 2 + eo2;
            int oA0 = src_s[wid][b],     oB0 = src_s[wid][eB0], oC0 = src_s[wid][b + 1];
            int oA1 = src_s[wid][b + 2], oB1 = src_s[wid][eB1], oC1 = src_s[wid][b + 3];
            float aA0 = a_s[wid][b][hA],     aB0 = a_s[wid][eB0][hB], aC0 = a_s[wid][b + 1][hC];
            float aA1 = a_s[wid][b + 2][hA], aB1 = a_s[wid][eB1][hB], aC1 = a_s[wid][b + 3][hC];
            s16x8 fA0 = *(const s16x8*)(fb + oA0 + p0 * 16);
            s16x8 fB0 = *(const s16x8*)(fb + oB0 + p1 * 16);
            s16x8 fC0 = *(const s16x8*)(fb + oC0 + p2 * 16);
            s16x8 fA1 = *(const s16x8*)(fb + oA1 + p0 * 16);
            s16x8 fB1 = *(const s16x8*)(fb + oB1 + p1 * 16);
            s16x8 fC1 = *(const s16x8*)(fb + oC1 + p2 * 16);
#pragma unroll
            for (int i = 0; i < 8; i++){
              acc0[i] += aA0 * bf2f(fA0[i]) + aA1 * bf2f(fA1[i]);
              acc1[i] += aB0 * bf2f(fB0[i]) + aB1 * bf2f(fB1[i]);
              acc2[i] += aC0 * bf2f(fC0[i]) + aC1 * bf2f(fC1[i]);
            }
          }
#pragma unroll
          for (int i = 0; i < 8; i++){
            float x1 = (lane < 32) ? acc2[i] : acc1[i];
            float r1 = __shfl_xor(x1, 32);
            float t0 = acc0[i] + r1;
            v0[i] = ACT ? elu1(t0) : t0;
            float r2 = __shfl_xor(acc2[i], 32);
            if (lane < 32){
              float t1 = acc1[i] + r2;
              v1[i] = ACT ? elu1(t1) : t1;
            }
          }
        } else {
          const int eo = lane & 7, cb = lane >> 3;
          float acc[3][8] = {};
          for (int b = 0; b < cnt; b += 8){
            int e = b + eo;
            float a = a_s[wid][e][0];
            int so = src_s[wid][e];
#pragma unroll
            for (int c = 0; c < 3; c++){
              s16x8 fv = *(const s16x8*)(fb + so + (cb * 3 + c) * 16);
#pragma unroll
              for (int i = 0; i < 8; i++) acc[c][i] += a * bf2f(fv[i]);
            }
          }
#pragma unroll
          for (int c = 0; c < 3; c++){
#pragma unroll
            for (int i = 0; i < 8; i++){
              float v = acc[c][i];
              v += __shfl_xor(v, 1); v += __shfl_xor(v, 2); v += __shfl_xor(v, 4);
              if (ACT) v = elu1(v);
              if (eo == 0) mbk[MB(cb * 3 + c, i)] = v;
            }
          }
        }
      } else {
        // cnt > 64 serial path
        constexpr int NC = H * 192 / 8;
        const int c0 = lane, h0 = (c0 / 24) % H;
        const int c1 = lane + 64, h1 = (c1 / 24) % H;
        const bool act0 = (c0 < NC);
        const bool act1 = (H == 4) && (lane < 32);
        float acc0[8] = {}, acc1[8] = {};
        float mh[H], sh[H];
#pragma unroll
        for (int h = 0; h < H; h++){ mh[h] = -1e30f; sh[h] = 0.f; }
        for (int b = lane; b < cnt; b += 64){
          int pp = off + b; int s = src_sorted[pp]; int r = et_sorted[pp];
#pragma unroll
          for (int h = 0; h < H; h++){
            float v = el[s * H + h] + ern[h] + ee5[r * H + h];
            v = (v >= 0.f) ? v : 0.2f * v;
            mh[h] = fmaxf(mh[h], v);
          }
        }
#pragma unroll
        for (int h = 0; h < H; h++) mh[h] = wave_max(mh[h]);
        for (int b = lane; b < cnt; b += 64){
          int pp = off + b; int s = src_sorted[pp]; int r = et_sorted[pp];
#pragma unroll
          for (int h = 0; h < H; h++){
            float v = el[s * H + h] + ern[h] + ee5[r * H + h];
            v = (v >= 0.f) ? v : 0.2f * v;
            sh[h] += __expf(v - mh[h]);
          }
        }
#pragma unroll
        for (int h = 0; h < H; h++) sh[h] = wave_sum(sh[h]);
        if (MODE != 2){
          for (int b = lane; b < cnt; b += 64){
            int pp = off + b; int s = src_sorted[pp]; int r = et_sorted[pp];
            float ap[4] = {};
            if (MODE > 0){
#pragma unroll
              for (int q = 0; q < 4; q++) ap[q] = aprev[(size_t)pp * 4 + q];
            }
            float av[4] = {};
#pragma unroll
            for (int h = 0; h < H; h++){
              float v = el[s * H + h] + ern[h] + ee5[r * H + h];
              v = (v >= 0.f) ? v : 0.2f * v;
              float a = __expf(v - mh[h]) / sh[h];
              if (MODE == 1) a = 0.95f * a + 0.05f * ap[h];
              av[h] = a;
            }
            f32x4 o = {av[0], av[1], av[2], av[3]};
            *(f32x4*)(aout + (size_t)pp * 4) = o;
          }
        }
        for (int b = 0; b < cnt; b++){
          int pp = off + b; int s = src_sorted[pp]; int r = et_sorted[pp];
          const short* row = featb + (size_t)s * (H * 192);
          float apm[4] = {};
          if (MODE > 0){
#pragma unroll
            for (int q = 0; q < 4; q++) apm[q] = aprev[(size_t)pp * 4 + q];
          }
          if (act0){
            float v = el[s * H + h0] + ern[h0] + ee5[r * H + h0];
            v = (v >= 0.f) ? v : 0.2f * v;
            float a = __expf(v - mh[h0]) / sh[h0];
            if (MODE == 1) a = 0.95f * a + 0.05f * apm[h0];
            if (MODE == 2) a = 0.95f * a + 0.0125f * (apm[0] + apm[1] + apm[2] + apm[3]);
            s16x8 vv = *(const s16x8*)(row + c0 * 8);
#pragma unroll
            for (int i = 0; i < 8; i++) acc0[i] += a * bf2f(vv[i]);
          }
          if (act1){
            float v = el[s * H + h1] + ern[h1] + ee5[r * H + h1];
            v = (v >= 0.f) ? v : 0.2f * v;
            float a = __expf(v - mh[h1]) / sh[h1];
            if (MODE == 1) a = 0.95f * a + 0.05f * apm[h1];
            s16x8 vv = *(const s16x8*)(row + c1 * 8);
#pragma unroll
            for (int i = 0; i < 8; i++) acc1[i] += a * bf2f(vv[i]);
          }
        }
        if constexpr (H == 4){
#pragma unroll
          for (int i = 0; i < 8; i++){
            v0[i] = ACT ? elu1(acc0[i]) : acc0[i];
            if (lane < 32) v1[i] = ACT ? elu1(acc1[i]) : acc1[i];
          }
        } else {
          if (lane < 24){
#pragma unroll
            for (int i = 0; i < 8; i++) mbk[MB(lane, i)] = ACT ? elu1(acc0[i]) : acc0[i];
          }
        }
      }
      // ---- shared H==4 fallback epilogue: outb from regs + mean rounds ----
      if constexpr (H == 4){
        if (outb){
          {
            int c = lane, h = c / 24, rm = c % 24, t = rm >> 3, j = (rm & 7) * 8;
            s16x8 o;
#pragma unroll
            for (int i = 0; i < 8; i++) o[i] = f2bf(v0[i]);
            *(s16x8*)(outb + ((size_t)(t * NPAD) + n) * 256 + h * 64 + j) = o;
          }
          if (lane < 32){
            int c = lane + 64, h = c / 24, rm = c % 24, t = rm >> 3, j = (rm & 7) * 8;
            s16x8 o;
#pragma unroll
            for (int i = 0; i < 8; i++) o[i] = f2bf(v1[i]);
            *(s16x8*)(outb + ((size_t)(t * NPAD) + n) * 256 + h * 64 + j) = o;
          }
        }
        if (lane < 24){
#pragma unroll
          for (int i = 0; i < 8; i++) mbk[MB(lane, i)] = v0[i];
        }
        if (lane >= 24 && lane < 48){
#pragma unroll
          for (int i = 0; i < 8; i++) mbk[MB(lane - 24, i)] += v0[i];
        }
        if (lane >= 48){
#pragma unroll
          for (int i = 0; i < 8; i++) mbk[MB(lane - 48, i)] += v0[i];
        } else if (lane < 8){
#pragma unroll
          for (int i = 0; i < 8; i++) mbk[MB(lane + 16, i)] += v1[i];
        }
        if (lane >= 8 && lane < 32){
#pragma unroll
          for (int i = 0; i < 8; i++) mbk[MB(lane - 8, i)] += v1[i];
        }
      }
    }
  }

  // ---- final per-slot l2 norm from mb (per half-wave, node nme) ----
  const int cb8 = hl >> 3, ib = hl & 7;
  const float* mbh = mb[wid][half];
  for (int t = 0; t < 3; t++){
    float va = mbh[MB(t * 8 + cb8, ib)];
    float vb = mbh[MB(t * 8 + cb8 + 4, ib)];
    if constexpr (H == 4){ va *= 0.25f; vb *= 0.25f; }
    float ss = half_sum(va * va + vb * vb);
    float sc = 1.f / fmaxf(sqrtf(ss), 1e-12f);
    short* ob = o_b + (size_t)nme * 768 + t * 256 + kslice * 64;
    ob[hl] = f2bf(va * sc);
    ob[hl + 32] = f2bf(vb * sc);
  }
}

// ---------------- DistMult via MFMA ----------------
__global__ void distmult_mfma(const short* __restrict__ o_b, const short* __restrict__ Mt,
                              const int* __restrict__ pairs, const int* __restrict__ left,
                              const int* __restrict__ right, const int* __restrict__ mid,
                              float* __restrict__ score){
  const int pt = blockIdx.x, ct = blockIdx.y;
  const int tid = threadIdx.x;
  const int w = tid >> 6, lane = tid & 63;
  const int quad = lane >> 4, ln = lane & 15;
  __shared__ __attribute__((aligned(16))) short smem[8192];
  short* A_s = smem;
  short* B_s = smem + 2048;
  __shared__ int pid_s[64];
  __shared__ int lbase[64];
  if (tid < 64){
    int p = pairs[pt * 64 + tid];
    pid_s[tid] = p;
    lbase[tid] = (p >= 0) ? left[p] * 768 : 0;
  }
  __syncthreads();
  int p0 = pid_s[0];
  if (p0 < 0) return;
  const int r = mid[p0];
  const short* Mr = Mt + (size_t)r * 768 * 768;
  f32x4 acc[8] = {};
  for (int kk = 0; kk < 768; kk += 32){
    {
      int row = tid >> 2, chunk = tid & 3;
      s16x8 v = *(const s16x8*)(o_b + (size_t)lbase[row] + kk + chunk * 8);
      *(s16x8*)(A_s + row * 32 + chunk * 8) = v;
    }
    {
      int row = tid >> 1, half = tid & 1;
      const s16x8* g = (const s16x8*)(Mr + (size_t)(ct * 128 + row) * 768 + kk + half * 16);
      s16x8 v0 = g[0], v1 = g[1];
      *(s16x8*)(B_s + row * 32 + half * 16) = v0;
      *(s16x8*)(B_s + row * 32 + half * 16 + 8) = v1;
    }
    __syncthreads();
    s16x8 af = *(s16x8*)(A_s + (w * 16 + ln) * 32 + quad * 8);
#pragma unroll
    for (int b = 0; b < 8; b++){
      s16x8 bf = *(s16x8*)(B_s + (b * 16 + ln) * 32 + quad * 8);
      acc[b] = __builtin_amdgcn_mfma_f32_16x16x32_bf16(af, bf, acc[b], 0, 0, 0);
    }
    __syncthreads();
  }
  short* RE_s = smem;
  {
    int row = tid >> 2, quarter = tid & 3;
    int p = pid_s[row];
    s16x8 v0 = {}, v1 = {}, v2 = {}, v3 = {};
    if (p >= 0){
      const s16x8* g = (const s16x8*)(o_b + (size_t)right[p] * 768 + ct * 128 + quarter * 32);
      v0 = g[0]; v1 = g[1]; v2 = g[2]; v3 = g[3];
    }
    __syncthreads();
    short* dst = RE_s + row * 128 + quarter * 32;
    *(s16x8*)(dst)      = v0;
    *(s16x8*)(dst + 8)  = v1;
    *(s16x8*)(dst + 16) = v2;
    *(s16x8*)(dst + 24) = v3;
  }
  __syncthreads();
#pragma unroll
  for (int i = 0; i < 4; i++){
    int row = w * 16 + quad * 4 + i;
    float s = 0.f;
#pragma unroll
    for (int b = 0; b < 8; b++)
      s += acc[b][i] * bf2f(RE_s[row * 128 + b * 16 + ln]);
    s += __shfl_xor(s, 1); s += __shfl_xor(s, 2);
    s += __shfl_xor(s, 4); s += __shfl_xor(s, 8);
    if (ln == 0){
      int p = pid_s[row];
      if (p >= 0) atomicAdd(&score[p], s);
    }
  }
}

__global__ void sigmoid_k(const float* __restrict__ score, float* __restrict__ out){
  int i = blockIdx.x * 256 + threadIdx.x;
  if (i < N_PAIRS) out[i] = 1.f / (1.f + __expf(-score[i]));
}

// ---------------- launcher ----------------
extern "C" void kernel_launch(void* const* d_in, const int* in_sizes, int n_in,
                              void* d_out, int out_size, void* d_ws, size_t ws_size,
                              hipStream_t stream){
  const float* f0 = (const float*)d_in[0];
  const float* w0 = (const float*)d_in[1];
  const float* b0 = (const float*)d_in[2];
  const float* f1 = (const float*)d_in[3];
  const float* w1 = (const float*)d_in[4];
  const float* b1 = (const float*)d_in[5];
  const float* f2 = (const float*)d_in[6];
  const float* w2_ = (const float*)d_in[7];
  const float* b2 = (const float*)d_in[8];
  const float* lW[3]  = {(const float*)d_in[9],  (const float*)d_in[15], (const float*)d_in[21]};
  const float* lal[3] = {(const float*)d_in[10], (const float*)d_in[16], (const float*)d_in[22]};
  const float* lar[3] = {(const float*)d_in[11], (const float*)d_in[17], (const float*)d_in[23]};
  const float* lee[3] = {(const float*)d_in[12], (const float*)d_in[18], (const float*)d_in[24]};
  const float* lwe[3] = {(const float*)d_in[13], (const float*)d_in[19], (const float*)d_in[25]};
  const float* lae[3] = {(const float*)d_in[14], (const float*)d_in[20], (const float*)d_in[26]};
  const float* dmW = (const float*)d_in[27];
  const int* efeat = (const int*)d_in[28];
  const int* srcv  = (const int*)d_in[29];
  const int* dstv  = (const int*)d_in[30];
  const int* left  = (const int*)d_in[31];
  const int* right = (const int*)d_in[32];
  const int* midv  = (const int*)d_in[33];
  float* out = (float*)d_out;

  // ---- workspace layout ----
  short* feat_b = (short*)d_ws;               // 15,360,000 shorts
  float* aA     = (float*)(feat_b + 15360000);// 800,000
  float* aB     = aA + 800000;                // 800,000
  float* eall   = aB + 800000;                // 480,000
  float* ee5f   = eall + 480000;              // 96
  float* score  = ee5f + 96;                  // 10,016
  int* cnt3     = (int*)(score + 10016);      // 80,000  (per dst x 4: typed counts)
  int* csr_off  = cnt3 + 80000;               // 20,004
  int* csr_pos  = csr_off + 20004;            // 80,000  (per dst x 4: typed scatter cursors)
  int* loc      = csr_pos + 80000;            // 20,000
  int* bsum     = loc + 20000;                // 128
  int* bofs     = bsum + 128;                 // 128
  int* src_sorted = bofs + 128;               // 200,000
  int* et_sorted  = src_sorted + 200000;      // 200,000
  int* cnt5     = et_sorted + 200000;         // 80
  int* off5     = cnt5 + 80;                  // 8
  int* pos5     = off5 + 8;                   // 80
  int* pairs    = pos5 + 80;                  // 10,368
  short* o_b    = (short*)(pairs + PAIR_PAD); // 15,360,000
  short* Xb0    = o_b + 15360000;             // 3,858,432
  short* Xb12   = Xb0 + 3858432;              // 15,433,728
  short* Wt0    = Xb12 + 15433728;            // 49,152
  short* Wt1    = Wt0 + 49152;                // 196,608
  short* Wt2    = Wt1 + 196608;               // 49,152
  short* Mt     = Wt2 + 49152;                // 2,949,120
  float* elf0 = eall, *erf0 = eall + 80000;
  float* elf1 = eall + 160000, *erf1 = eall + 240000;
  float* elf2 = eall + 320000, *erf2 = eall + 400000;

  build_h<<<2500, 64, 0, stream>>>(f0, w0, b0, f1, w1, b1, f2, w2_, b2, Xb0, o_b,
                                   cnt3, cnt5, pos5, score, pairs, eall, Xb12, feat_b);
  count_prep_k<<<782 + 6336, 256, 0, stream>>>(dstv, srcv, cnt3, midv, cnt5,
                                               lW[0], lW[1], lW[2], dmW, Wt0, Wt1, Wt2, Mt,
                                               lee[0], lwe[0], lae[0], lee[1], lwe[1], lae[1],
                                               lee[2], lwe[2], lae[2], ee5f);
  scan1_k<<<NBLK, 256, 0, stream>>>(cnt3, loc, bsum);
  scan2_k<<<1, 128, 0, stream>>>(bsum, bofs, cnt5, off5);
  scan3_k<<<NBLK, 256, 0, stream>>>(loc, bofs, csr_off, csr_pos, cnt3);
  scatter_k<<<782, 256, 0, stream>>>(dstv, srcv, efeat, csr_pos, src_sorted, et_sorted,
                                     midv, off5, pos5, pairs);

  // layer 0 (H=4, typed proj tiles, typed slot-gather, ELU) -> emb slice 1
  // grid.x = 4 ct * 64-slot groups (per-t tile counts 63/48/48, guarded in-kernel)
  { dim3 g(256, 1, 3);
    mfma_proj<64, 256, 1><<<g, 256, 0, stream>>>(Xb0, Wt0, feat_b, lal[0], lar[0], elf0, erf0); }
  gat_fused<4, 0, 1, 1><<<2500, 256, 0, stream>>>(csr_off, src_sorted, et_sorted, elf0, erf0, ee5f,
                                                  nullptr, aA, feat_b, Xb12, o_b, cnt3, 1);

  // layer 1 (H=4, residual aA, ELU) -> emb slice 2
  // grid.x = 4 ct * 160 (157 tiles padded to 160; XCD-affine swizzle in-kernel)
  { dim3 g(640, 1, 3);
    mfma_proj<256, 256, 0><<<g, 256, 0, stream>>>(Xb12, Wt1, feat_b, lal[1], lar[1], elf1, erf1); }
  gat_fused<4, 1, 1, 0><<<2500, 256, 0, stream>>>(csr_off, src_sorted, et_sorted, elf1, erf1, ee5f + 32,
                                                  aA, aB, feat_b, Xb12, o_b, cnt3, 2);

  // layer 2 (H=1, blend vs mean of a1, no activation) -> emb slice 3
  { dim3 g(157, 1, 3);
    mfma_proj<256, 64, 0><<<g, 256, 0, stream>>>(Xb12, Wt2, feat_b, lal[2], lar[2], elf2, erf2); }
  gat_fused<1, 2, 0, 0><<<2500, 256, 0, stream>>>(csr_off, src_sorted, et_sorted, elf2, erf2, ee5f + 64,
                                                  aB, nullptr, feat_b, nullptr, o_b, cnt3, 3);

  // DistMult + sigmoid
  { dim3 g(DM_TILES, 6); distmult_mfma<<<g, 256, 0, stream>>>(o_b, Mt, pairs, left, right, midv, score); }
  sigmoid_k<<<40, 256, 0, stream>>>(score, out);
}

// Round 9
// 433.846 us; speedup vs baseline: 1.0446x; 1.0106x over previous
//
#include <hip/hip_runtime.h>
#include <math.h>

// ---------------- constants ----------------
#define N_NODES 20000
#define NPAD    20096          // 157*128
#define N_EDGES 200000
#define N_PAIRS 10000
#define PAIR_PAD 10368         // 162*64
#define DM_TILES 162
#define NBLK    79             // 79*256 = 20224 >= N_NODES

typedef __attribute__((ext_vector_type(8))) short s16x8;
typedef __attribute__((ext_vector_type(4))) float f32x4;

__device__ inline float wave_max(float v){
  for (int o = 32; o > 0; o >>= 1) v = fmaxf(v, __shfl_xor(v, o));
  return v;
}
__device__ inline float wave_sum(float v){
  for (int o = 32; o > 0; o >>= 1) v += __shfl_xor(v, o);
  return v;
}
__device__ inline float half_max(float v){
  for (int o = 16; o > 0; o >>= 1) v = fmaxf(v, __shfl_xor(v, o));
  return v;
}
__device__ inline float half_sum(float v){
  for (int o = 16; o > 0; o >>= 1) v += __shfl_xor(v, o);
  return v;
}
__device__ inline short f2bf(float x){
  union { float f; unsigned u; } v; v.f = x;
  unsigned r = (v.u + 0x7FFFu + ((v.u >> 16) & 1u)) >> 16;
  return (short)r;
}
__device__ inline float bf2f(short s){
  union { unsigned u; float f; } v; v.u = ((unsigned)(unsigned short)s) << 16;
  return v.f;
}
__device__ inline int ntype(int s){ return (s < 8000) ? 0 : ((s < 14000) ? 1 : 2); }
__device__ inline float elu1(float x){ return (x > 0.f) ? x : expm1f(x); }

// mean/norm buffer slot: chunk-in-head c24 (0..23), elem i (0..7); stride 9 -> conflict-free
#define MB(c24, i) ((c24) * 9 + (i))

// ---------------- input linears (8 nodes/block) + ALL workspace zeroing + o_b slice 0 ----------------
__global__ void build_h(const float* __restrict__ f0, const float* __restrict__ w0, const float* __restrict__ b0,
                        const float* __restrict__ f1, const float* __restrict__ w1, const float* __restrict__ b1,
                        const float* __restrict__ f2, const float* __restrict__ w2, const float* __restrict__ b2,
                        short* __restrict__ Xb0, short* __restrict__ o_b,
                        int* __restrict__ cnt3, int* __restrict__ cnt5, int* __restrict__ pos5,
                        float* __restrict__ score, int* __restrict__ pairs,
                        float* __restrict__ eall, short* __restrict__ Xb12,
                        short* __restrict__ featb){
  const int blk = blockIdx.x, lane = threadIdx.x;
  const int gid = blk * 64 + lane;             // 0..159999
  // ---- zeroing (spread across grid) ----
  if (gid < 80000) cnt3[gid] = 0;
  if (gid < 5){ cnt5[gid * 16] = 0; pos5[gid * 16] = 0; }
  if (gid < 10016) score[gid] = 0.f;
  if (gid < PAIR_PAD) pairs[gid] = -1;
  for (int i = gid; i < 480000; i += 160000) eall[i] = 0.f;
  s16x8 z = {};
  if (gid < 4608){  // Xb12 pad rows: 3 * 96 * 256 shorts
    int t = (gid * 16) / 24576, off = (gid * 16) % 24576;
    short* p = Xb12 + ((size_t)(t * NPAD + N_NODES)) * 256 + off;
    *(s16x8*)p = z; *(s16x8*)(p + 8) = z;
  }
  if (gid < 1152){  // Xb0 pad rows
    int t = (gid * 16) / 6144, off = (gid * 16) % 6144;
    short* p = Xb0 + ((size_t)(t * NPAD + N_NODES)) * 64 + off;
    *(s16x8*)p = z; *(s16x8*)(p + 8) = z;
  }
  // ---- per-block type ----
  int t, C, nbase; const float *f, *w, *b;
  if (blk < 1000)       { t = 0; nbase = 0;     C = 256; f = f0; w = w0; b = b0; }
  else if (blk < 1750)  { t = 1; nbase = 8000;  C = 128; f = f1; w = w1; b = b1; }
  else                  { t = 2; nbase = 14000; C = 64;  f = f2; w = w2; b = b2; }
  const int n0 = blk * 8;
  const int n0l = n0 - nbase;
  __shared__ float xs[8 * 256];
  const float* fr = f + (size_t)n0l * C;
  for (int i = lane; i < 8 * C; i += 64) xs[i] = fr[i];
  __syncthreads();
  float acc[8];
#pragma unroll
  for (int j = 0; j < 8; j++) acc[j] = b[lane];
  for (int c = 0; c < C; c++){
    float wv = w[c * 64 + lane];
#pragma unroll
    for (int j = 0; j < 8; j++) acc[j] += xs[j * C + c] * wv;
  }
  for (int j = 0; j < 8; j++){
    int n = n0 + j;
    // off-slot feat_b zero (layer-0 typed proj skips those tiles; cnt>64 fallback reads full rows)
    {
      int h = lane >> 4, si = (lane >> 3) & 1, j8 = lane & 7;
      int s0 = (t == 0) ? 1 : 0;
      int s1 = (t == 2) ? 1 : 2;
      int toff = si ? s1 : s0;
      *(s16x8*)(featb + ((size_t)n * 4 + h) * 192 + toff * 64 + j8 * 8) = z;
    }
    for (int tt = 0; tt < 3; tt++)
      Xb0[((size_t)(tt * NPAD) + n) * 64 + lane] = f2bf((tt == t) ? acc[j] : 0.f);
    float ss = wave_sum(acc[j] * acc[j]);
    float sc = 1.f / fmaxf(sqrtf(ss), 1e-12f);
    for (int tt = 0; tt < 3; tt++)
      o_b[(size_t)n * 768 + tt * 256 + lane] = f2bf((tt == t) ? acc[j] * sc : 0.f);
  }
}

// ---------------- merged: typed edge/pair counting (blocks 0..781) + weight prep ----------------
__global__ void count_prep_k(const int* __restrict__ dst, const int* __restrict__ srcv,
                             int* __restrict__ cnt3,
                             const int* __restrict__ mid, int* __restrict__ cnt5,
                             const float* __restrict__ lW0, const float* __restrict__ lW1,
                             const float* __restrict__ lW2, const float* __restrict__ dmW,
                             short* __restrict__ Wt0, short* __restrict__ Wt1,
                             short* __restrict__ Wt2, short* __restrict__ Mt,
                             const float* __restrict__ ee0, const float* __restrict__ we0, const float* __restrict__ ae0,
                             const float* __restrict__ ee1, const float* __restrict__ we1, const float* __restrict__ ae1,
                             const float* __restrict__ ee2, const float* __restrict__ we2, const float* __restrict__ ae2,
                             float* __restrict__ ee5f){
  if (blockIdx.x < 782){
    int e = blockIdx.x * 256 + threadIdx.x;
    int lane = threadIdx.x & 63;
    if (e < N_EDGES){
      int tt = ntype(srcv[e]);
      atomicAdd(&cnt3[dst[e] * 4 + tt], 1);
    }
    int r_mine = (e < N_PAIRS) ? mid[e] : -1;
#pragma unroll
    for (int r = 0; r < 5; r++){
      unsigned long long mask = __ballot(r_mine == r);
      if (mask){
        int leader = __ffsll((long long)mask) - 1;
        if (lane == leader) atomicAdd(&cnt5[r * 16], __popcll(mask));
      }
    }
    return;
  }
  int lin = blockIdx.x - 782;
  int z = lin / 576;
  int rem = lin % 576;
  int by = rem / 24, bx = rem % 24;
  if (z == 10){
    int r = bx, L = by;
    if (r >= 5 || L >= 3) return;
    int H = (L == 2) ? 1 : 4;
    const float* eetab = (L == 0) ? ee0 : ((L == 1) ? ee1 : ee2);
    const float* We    = (L == 0) ? we0 : ((L == 1) ? we1 : we2);
    const float* ae    = (L == 0) ? ae0 : ((L == 1) ? ae1 : ae2);
    int h = threadIdx.x >> 6, lane = threadIdx.x & 63;
    if (h >= H) return;
    float v = 0.f;
    for (int k = 0; k < 64; k++) v += eetab[r * 64 + k] * We[k * H * 64 + h * 64 + lane];
    v *= ae[h * 64 + lane];
    v = wave_sum(v);
    if (lane == 0) ee5f[L * 32 + r * H + h] = v;
    return;
  }
  const float* s; short* d; int R, Cc, r0, c0;
  if (z < 5){
    s = dmW + (size_t)z * 589824; d = Mt + (size_t)z * 589824;
    R = 768; Cc = 768; r0 = bx * 32; c0 = by * 32;
  } else if (z < 8){
    if (bx >= 8 || by >= 8) return;
    int t = z - 5;
    s = lW1 + (size_t)t * 65536; d = Wt1 + (size_t)t * 65536;
    R = 256; Cc = 256; r0 = bx * 32; c0 = by * 32;
  } else if (z == 8){
    if (bx >= 6 || by >= 8) return;
    int t = bx >> 1;
    s = lW0 + (size_t)t * 16384; d = Wt0 + (size_t)t * 16384;
    R = 64; Cc = 256; r0 = (bx & 1) * 32; c0 = by * 32;
  } else {
    if (bx >= 8 || by >= 6) return;
    int t = by >> 1;
    s = lW2 + (size_t)t * 16384; d = Wt2 + (size_t)t * 16384;
    R = 256; Cc = 64; r0 = bx * 32; c0 = (by & 1) * 32;
  }
  __shared__ float tile[32][33];
  int tx = threadIdx.x & 31, ty = threadIdx.x >> 5;
  for (int i = 0; i < 32; i += 8){
    int r = r0 + ty + i;
    tile[ty + i][tx] = (r < R && c0 + tx < Cc) ? s[(size_t)r * Cc + c0 + tx] : 0.f;
  }
  __syncthreads();
  for (int i = 0; i < 32; i += 8){
    int c = c0 + ty + i;
    if (c < Cc && r0 + tx < R)
      d[(size_t)c * R + r0 + tx] = f2bf(tile[tx][ty + i]);
  }
}

// ---------------- hierarchical scan ----------------
__global__ void scan1_k(const int* __restrict__ cnt3, int* __restrict__ loc, int* __restrict__ bsum){
  __shared__ int s[256];
  int tid = threadIdx.x;
  int idx = blockIdx.x * 256 + tid;
  int v = (idx < N_NODES) ? (cnt3[idx * 4] + cnt3[idx * 4 + 1] + cnt3[idx * 4 + 2]) : 0;
  s[tid] = v;
  __syncthreads();
  for (int o = 1; o < 256; o <<= 1){
    int u = (tid >= o) ? s[tid - o] : 0;
    __syncthreads();
    s[tid] += u;
    __syncthreads();
  }
  if (idx < N_NODES) loc[idx] = s[tid] - v;
  if (tid == 255) bsum[blockIdx.x] = s[255];
}

__global__ void scan2_k(const int* __restrict__ bsum, int* __restrict__ bofs,
                        const int* __restrict__ cnt5, int* __restrict__ off5){
  __shared__ int s[128];
  int tid = threadIdx.x;
  int v = (tid < NBLK) ? bsum[tid] : 0;
  s[tid] = v;
  __syncthreads();
  for (int o = 1; o < 128; o <<= 1){
    int u = (tid >= o) ? s[tid - o] : 0;
    __syncthreads();
    s[tid] += u;
    __syncthreads();
  }
  if (tid < NBLK) bofs[tid] = s[tid] - v;
  if (tid == 0){
    int r0 = 0;
    for (int r = 0; r < 5; r++){ off5[r] = r0; r0 += ((cnt5[r * 16] + 63) >> 6) << 6; }
  }
}

__global__ void scan3_k(const int* __restrict__ loc, const int* __restrict__ bofs,
                        int* __restrict__ coff, int* __restrict__ cpos,
                        const int* __restrict__ cnt3){
  int idx = blockIdx.x * 256 + threadIdx.x;
  if (idx < N_NODES){
    int v = loc[idx] + bofs[blockIdx.x];
    coff[idx] = v;
    int c0 = cnt3[idx * 4], c1 = cnt3[idx * 4 + 1];
    cpos[idx * 4]     = v;
    cpos[idx * 4 + 1] = v + c0;
    cpos[idx * 4 + 2] = v + c0 + c1;
  }
  if (idx == 0) coff[N_NODES] = N_EDGES;
}

__global__ void scatter_k(const int* __restrict__ dst, const int* __restrict__ srcv,
                          const int* __restrict__ efeat, int* __restrict__ cpos,
                          int* __restrict__ src_sorted, int* __restrict__ et_sorted,
                          const int* __restrict__ mid, const int* __restrict__ off5,
                          int* __restrict__ pos5, int* __restrict__ pairs){
  int e = blockIdx.x * 256 + threadIdx.x;
  int lane = threadIdx.x & 63;
  if (e < N_EDGES){
    int s = srcv[e];
    int tt = ntype(s);
    int p = atomicAdd(&cpos[dst[e] * 4 + tt], 1);
    src_sorted[p] = s;
    et_sorted[p] = efeat[e];
  }
  int r_mine = (e < N_PAIRS) ? mid[e] : -1;
#pragma unroll
  for (int r = 0; r < 5; r++){
    unsigned long long mask = __ballot(r_mine == r);
    if (mask){
      int cnt = __popcll(mask);
      int leader = __ffsll((long long)mask) - 1;
      int base = 0;
      if (lane == leader) base = atomicAdd(&pos5[r * 16], cnt);
      base = __shfl(base, leader);
      if (r_mine == r){
        int rank = __popcll(mask & ((1ull << lane) - 1ull));
        pairs[off5[r] + base + rank] = e;
      }
    }
  }
}

// ---------------- MFMA slot projection -> bf16 feat + fused el/er partials ----------------
// One ct per block (36 VGPR, high occupancy). The (tile, ct) encoding in blockIdx.x puts all
// 4 ct-instances of a tile at the SAME residue mod 8 -> same XCD -> A tile hits L2 3 of 4 times.
// LDS rows padded to 40 shorts (80 B) to spread banks on b128 reads/writes.
#define LDA 40
template<int C, int NO, int TYPED>
__global__ void mfma_proj(const short* __restrict__ Xb, const short* __restrict__ Wt,
                          short* __restrict__ featb, const float* __restrict__ al,
                          const float* __restrict__ ar, float* __restrict__ elf,
                          float* __restrict__ erf){
  constexpr int H = NO / 64;
  const int t = blockIdx.z;
  int tile, ct;
  if constexpr (H == 4){
    const int x = blockIdx.x;            // grp*32 + ct*8 + slot
    const int grp = x >> 5, sub = x & 31;
    ct = sub >> 3;
    tile = grp * 8 + (sub & 7);
  } else { tile = blockIdx.x; ct = 0; }
  if constexpr (TYPED){
    const int lo[3] = {0, 62, 109};
    const int hi[3] = {63, 110, 157};
    if (tile >= hi[t] - lo[t]) return;
    tile += lo[t];
  } else {
    if (tile >= NPAD / 128) return;
  }
  const int n0 = tile * 128;
  const int tid = threadIdx.x;
  const int w = tid >> 6, lane = tid & 63;
  const int quad = lane >> 4, ln = lane & 15;
  __shared__ __attribute__((aligned(16))) short A_s[128 * LDA];
  __shared__ __attribute__((aligned(16))) short B_s[64 * LDA];
  const short* Xt  = Xb + (size_t)t * NPAD * C;
  const short* Wtt = Wt + ((size_t)t * NO + ct * 64) * C;
  f32x4 acc[2][4] = {};
  for (int kk = 0; kk < C; kk += 32){
    {
      int row = tid >> 1, hk = tid & 1;
      const s16x8* g = (const s16x8*)(Xt + (size_t)(n0 + row) * C + kk + hk * 16);
      s16x8 v0 = g[0], v1 = g[1];
      *(s16x8*)(A_s + row * LDA + hk * 16) = v0;
      *(s16x8*)(A_s + row * LDA + hk * 16 + 8) = v1;
    }
    {
      int row = tid >> 2, chunk = tid & 3;
      s16x8 v = *(const s16x8*)(Wtt + (size_t)row * C + kk + chunk * 8);
      *(s16x8*)(B_s + row * LDA + chunk * 8) = v;
    }
    __syncthreads();
    s16x8 af0 = *(s16x8*)(A_s + (w * 32 + ln) * LDA + quad * 8);
    s16x8 af1 = *(s16x8*)(A_s + (w * 32 + 16 + ln) * LDA + quad * 8);
    s16x8 bf[4];
#pragma unroll
    for (int b = 0; b < 4; b++) bf[b] = *(s16x8*)(B_s + (b * 16 + ln) * LDA + quad * 8);
#pragma unroll
    for (int b = 0; b < 4; b++){
      acc[0][b] = __builtin_amdgcn_mfma_f32_16x16x32_bf16(af0, bf[b], acc[0][b], 0, 0, 0);
      acc[1][b] = __builtin_amdgcn_mfma_f32_16x16x32_bf16(af1, bf[b], acc[1][b], 0, 0, 0);
    }
    __syncthreads();
  }
#pragma unroll
  for (int ar_ = 0; ar_ < 2; ar_++){
#pragma unroll
    for (int i = 0; i < 4; i++){
      int n = n0 + w * 32 + ar_ * 16 + quad * 4 + i;
      if (n >= N_NODES) continue;
#pragma unroll
      for (int b = 0; b < 4; b++){
        int jj = b * 16 + ln;
        featb[((size_t)n * H + ct) * 192 + t * 64 + jj] = f2bf(acc[ar_][b][i]);
      }
    }
  }
  float alv[4], arv[4];
#pragma unroll
  for (int b = 0; b < 4; b++){
    alv[b] = al[ct * 192 + t * 64 + b * 16 + ln];
    arv[b] = ar[ct * 192 + t * 64 + b * 16 + ln];
  }
#pragma unroll
  for (int ar_ = 0; ar_ < 2; ar_++){
#pragma unroll
    for (int i = 0; i < 4; i++){
      float pe = 0.f, pr = 0.f;
#pragma unroll
      for (int b = 0; b < 4; b++){
        pe += acc[ar_][b][i] * alv[b];
        pr += acc[ar_][b][i] * arv[b];
      }
#pragma unroll
      for (int o = 1; o < 16; o <<= 1){
        pe += __shfl_xor(pe, o);
        pr += __shfl_xor(pr, o);
      }
      int n = n0 + w * 32 + ar_ * 16 + quad * 4 + i;
      if (ln == 0 && n < N_NODES){
        atomicAdd(&elf[n * H + ct], pe);
        atomicAdd(&erf[n * H + ct], pr);
      }
    }
  }
}

// ---------------- fused softmax + gather aggregation + emb: 2 nodes per wave ----------------
// outb stored directly from registers; per-slot l2-norm via small mb buffer (wave-ordered rounds).
// Dense H=4 gather path is an explicit 2-stage software pipeline (counted vmcnt, never drained).
template<int H, int MODE, int ACT, int TYPED>
__global__ __launch_bounds__(256, 4) void gat_fused(
    const int* __restrict__ csr_off, const int* __restrict__ src_sorted,
    const int* __restrict__ et_sorted,
    const float* __restrict__ el, const float* __restrict__ er, const float* __restrict__ ee5,
    const float* __restrict__ aprev, float* __restrict__ aout,
    const short* __restrict__ featb, short* __restrict__ outb,
    short* __restrict__ o_b, const int* __restrict__ cnt3, int kslice){
  const int wid = threadIdx.x >> 6, lane = threadIdx.x & 63;
  const int half = lane >> 5, hl = lane & 31;
  const int l32 = half << 5;
  const int n0 = blockIdx.x * 8 + wid * 2;        // wave owns nodes n0, n0+1; grid exact
  const int nme = n0 + half;                      // this half-wave's node
  __shared__ float a_s[4][64][H];
  __shared__ int   src_s[4][64];                  // pre-multiplied BYTE offsets into featb
  __shared__ float mb[4][2][216];                 // head-sum buffer, MB(c24,i) layout
  const char* fb = (const char*)featb;

  const int offm = csr_off[nme];
  const int cntm = csr_off[nme + 1] - offm;
  const int cnto = __shfl_xor(cntm, 32);
  const bool paired = (cntm <= 32) && (cnto <= 32);

  if (paired){
    // ---- softmax: edge e of node nme at lane l32+e ----
    float ern[H];
    if constexpr (H == 4){
      f32x4 ev = *(const f32x4*)(er + nme * 4);
#pragma unroll
      for (int h = 0; h < 4; h++) ern[h] = ev[h];
    } else ern[0] = er[nme];
    const int p = offm + hl;
    const bool valid = hl < cntm;
    int sidx = 0, r = 0;
    if (valid){ sidx = src_sorted[p]; r = et_sorted[p]; }
    int s0 = __shfl(sidx, l32);
    src_s[wid][lane] = (valid ? sidx : s0) * (H * 384);
    float lg[H];
#pragma unroll
    for (int h = 0; h < H; h++) lg[h] = -1e30f;
    if (valid){
      if constexpr (H == 4){
        f32x4 elv = *(const f32x4*)(el + sidx * 4);
        f32x4 eev = *(const f32x4*)(ee5 + r * 4);
#pragma unroll
        for (int h = 0; h < 4; h++){
          float v = elv[h] + ern[h] + eev[h];
          lg[h] = (v >= 0.f) ? v : 0.2f * v;
        }
      } else {
        float v = el[sidx] + ern[0] + ee5[r];
        lg[0] = (v >= 0.f) ? v : 0.2f * v;
      }
    }
    float ap[4] = {};
    if (MODE > 0 && valid){
      f32x4 av4 = *(const f32x4*)(aprev + (size_t)p * 4);
#pragma unroll
      for (int q = 0; q < 4; q++) ap[q] = av4[q];
    }
    float av[H];
#pragma unroll
    for (int h = 0; h < H; h++){
      float mh = half_max(lg[h]);
      float ex = valid ? __expf(lg[h] - mh) : 0.f;
      float sh = half_sum(ex);
      float a = ex / sh;
      if (MODE == 1) a = 0.95f * a + 0.05f * ap[h];
      if (MODE == 2) a = 0.95f * a + 0.0125f * (ap[0] + ap[1] + ap[2] + ap[3]);
      av[h] = a;
      a_s[wid][lane][h] = valid ? a : 0.f;
    }
    if constexpr (MODE != 2){
      if (valid){
        f32x4 o = {av[0], av[1], av[2], av[3]};
        *(f32x4*)(aout + (size_t)p * 4) = o;
      }
    }

    if constexpr (TYPED && H == 4){
      // ---- layer 0: slot-sparse rows; one 2-edge segment per type per iter (6 loads in flight) ----
      const int hh = hl >> 3, j8 = hl & 7;
      const int sub = hh * 384 + j8 * 16;
      float acc[3][8] = {};
      const int b1 = cnt3[nme * 4], b2 = b1 + cnt3[nme * 4 + 1];
      const int base_[3] = {0, b1, b2};
      const int lim_[3]  = {b1, b2, cntm};
      int maxrun = lim_[0] - base_[0];
      maxrun = max(maxrun, lim_[1] - base_[1]);
      maxrun = max(maxrun, lim_[2] - base_[2]);
      for (int b = 0; b < maxrun; b += 2){
        int i0[3], i1[3]; float a0[3], a1[3];
#pragma unroll
        for (int t = 0; t < 3; t++){
          int e0 = base_[t] + b, e1 = e0 + 1;
          bool v0 = e0 < lim_[t], v1 = e1 < lim_[t];
          i0[t] = v0 ? e0 : 0; i1[t] = v1 ? e1 : 0;
          a0[t] = v0 ? a_s[wid][l32 + i0[t]][hh] : 0.f;
          a1[t] = v1 ? a_s[wid][l32 + i1[t]][hh] : 0.f;
        }
        s16x8 f0[3], f1[3];
#pragma unroll
        for (int t = 0; t < 3; t++){
          f0[t] = *(const s16x8*)(fb + src_s[wid][l32 + i0[t]] + sub + t * 128);
          f1[t] = *(const s16x8*)(fb + src_s[wid][l32 + i1[t]] + sub + t * 128);
        }
#pragma unroll
        for (int t = 0; t < 3; t++)
#pragma unroll
          for (int i = 0; i < 8; i++)
            acc[t][i] += a0[t] * bf2f(f0[t][i]) + a1[t] * bf2f(f1[t][i]);
      }
#pragma unroll
      for (int t = 0; t < 3; t++){
        if (ACT){
#pragma unroll
          for (int i = 0; i < 8; i++) acc[t][i] = elu1(acc[t][i]);
        }
        if (outb){
          s16x8 o;
#pragma unroll
          for (int i = 0; i < 8; i++) o[i] = f2bf(acc[t][i]);
          *(s16x8*)(outb + ((size_t)(t * NPAD) + nme) * 256 + hh * 64 + j8 * 8) = o;
        }
      }
      // mean rounds by head (chunk c = hh*24 + t*8 + j8 -> c24 = t*8 + j8)
#pragma unroll
      for (int rr = 0; rr < 4; rr++){
        if (hh == rr){
#pragma unroll
          for (int t = 0; t < 3; t++)
#pragma unroll
            for (int i = 0; i < 8; i++){
              if (rr == 0) mb[wid][half][MB(t * 8 + j8, i)] = acc[t][i];
              else         mb[wid][half][MB(t * 8 + j8, i)] += acc[t][i];
            }
        }
      }
    } else if constexpr (H == 4){
      // ---- dense rows: 3 chunks/lane, 2-stage software pipeline over 2-edge groups ----
      const int p0 = hl, p1 = hl + 32, p2 = hl + 64;
      const int h0 = p0 / 24, h1 = p1 / 24, h2 = p2 / 24;
      float acc0[8] = {}, acc1[8] = {}, acc2[8] = {};
      const int cnt2m = (cntm + 1) & ~1;

      s16x8 xA0, xA1, xA2, xB0, xB1, xB2;
      s16x8 yA0, yA1, yA2, yB0, yB1, yB2;
      float wA0, wA1, wA2, wB0, wB1, wB2;
      float vA0, vA1, vA2, vB0, vB1, vB2;

#define DSTAGE(bb, XA0, XA1, XA2, XB0, XB1, XB2, WA0, WA1, WA2, WB0, WB1, WB2) \
      {                                                                        \
        bool lv0 = (bb) < cntm, lv1 = (bb) + 1 < cntm;                         \
        int eA = lv0 ? l32 + (bb) : l32;                                       \
        int eB = lv1 ? l32 + (bb) + 1 : l32;                                   \
        int soA = src_s[wid][eA], soB = src_s[wid][eB];                        \
        WA0 = lv0 ? a_s[wid][eA][h0] : 0.f;                                    \
        WA1 = lv0 ? a_s[wid][eA][h1] : 0.f;                                    \
        WA2 = lv0 ? a_s[wid][eA][h2] : 0.f;                                    \
        WB0 = lv1 ? a_s[wid][eB][h0] : 0.f;                                    \
        WB1 = lv1 ? a_s[wid][eB][h1] : 0.f;                                    \
        WB2 = lv1 ? a_s[wid][eB][h2] : 0.f;                                    \
        XA0 = *(const s16x8*)(fb + soA + p0 * 16);                             \
        XA1 = *(const s16x8*)(fb + soA + p1 * 16);                             \
        XA2 = *(const s16x8*)(fb + soA + p2 * 16);                             \
        XB0 = *(const s16x8*)(fb + soB + p0 * 16);                             \
        XB1 = *(const s16x8*)(fb + soB + p1 * 16);                             \
        XB2 = *(const s16x8*)(fb + soB + p2 * 16);                             \
      }

#define DFMA(XA0, XA1, XA2, XB0, XB1, XB2, WA0, WA1, WA2, WB0, WB1, WB2)       \
      {                                                                        \
        _Pragma("unroll")                                                      \
        for (int i = 0; i < 8; i++){                                           \
          acc0[i] += WA0 * bf2f(XA0[i]) + WB0 * bf2f(XB0[i]);                  \
          acc1[i] += WA1 * bf2f(XA1[i]) + WB1 * bf2f(XB1[i]);                  \
          acc2[i] += WA2 * bf2f(XA2[i]) + WB2 * bf2f(XB2[i]);                  \
        }                                                                      \
      }

      DSTAGE(0, xA0, xA1, xA2, xB0, xB1, xB2, wA0, wA1, wA2, wB0, wB1, wB2);
      for (int b = 0; b < cnt2m; b += 4){
        DSTAGE(b + 2, yA0, yA1, yA2, yB0, yB1, yB2, vA0, vA1, vA2, vB0, vB1, vB2);
        DFMA(xA0, xA1, xA2, xB0, xB1, xB2, wA0, wA1, wA2, wB0, wB1, wB2);
        DSTAGE(b + 4, xA0, xA1, xA2, xB0, xB1, xB2, wA0, wA1, wA2, wB0, wB1, wB2);
        DFMA(yA0, yA1, yA2, yB0, yB1, yB2, vA0, vA1, vA2, vB0, vB1, vB2);
      }
#undef DSTAGE
#undef DFMA

      if (ACT){
#pragma unroll
        for (int i = 0; i < 8; i++){
          acc0[i] = elu1(acc0[i]); acc1[i] = elu1(acc1[i]); acc2[i] = elu1(acc2[i]);
        }
      }
      if (outb){
#pragma unroll
        for (int cc = 0; cc < 3; cc++){
          int c = hl + cc * 32;
          const float* vv = (cc == 0) ? acc0 : ((cc == 1) ? acc1 : acc2);
          int h = c / 24, rm = c % 24, t = rm >> 3, j = (rm & 7) * 8;
          s16x8 o;
#pragma unroll
          for (int i = 0; i < 8; i++) o[i] = f2bf(vv[i]);
          *(s16x8*)(outb + ((size_t)(t * NPAD) + nme) * 256 + h * 64 + j) = o;
        }
      }
      // mean rounds by head
      float* mbh = mb[wid][half];
      if (hl < 24){
#pragma unroll
        for (int i = 0; i < 8; i++) mbh[MB(hl, i)] = acc0[i];
      }
      if (hl >= 24){
#pragma unroll
        for (int i = 0; i < 8; i++) mbh[MB(hl - 24, i)] += acc0[i];
      } else if (hl < 16){
#pragma unroll
        for (int i = 0; i < 8; i++) mbh[MB(hl + 8, i)] += acc1[i];
      }
      if (hl >= 16){
#pragma unroll
        for (int i = 0; i < 8; i++) mbh[MB(hl - 16, i)] += acc1[i];
      } else if (hl < 8){
#pragma unroll
        for (int i = 0; i < 8; i++) mbh[MB(hl + 16, i)] += acc2[i];
      }
      if (hl >= 8){
#pragma unroll
        for (int i = 0; i < 8; i++) mbh[MB(hl - 8, i)] += acc2[i];
      }
    } else {
      // ---- H == 1: 8 edges/iter x 3 chunks/lane over 8-lane groups (6 loads in flight) ----
      const int e4 = hl >> 3, cb = hl & 7;
      float acc[3][8] = {};
      for (int b = 0; b < cntm; b += 8){
        int i0 = b + e4, i1 = b + 4 + e4;        // <= 31 always; pads a_s==0
        float a0 = a_s[wid][l32 + i0][0];
        float a1 = a_s[wid][l32 + i1][0];
        int so0 = src_s[wid][l32 + i0], so1 = src_s[wid][l32 + i1];
        s16x8 f0[3], f1[3];
#pragma unroll
        for (int c = 0; c < 3; c++){
          f0[c] = *(const s16x8*)(fb + so0 + (cb * 3 + c) * 16);
          f1[c] = *(const s16x8*)(fb + so1 + (cb * 3 + c) * 16);
        }
#pragma unroll
        for (int c = 0; c < 3; c++)
#pragma unroll
          for (int i = 0; i < 8; i++)
            acc[c][i] += a0 * bf2f(f0[c][i]) + a1 * bf2f(f1[c][i]);
      }
#pragma unroll
      for (int c = 0; c < 3; c++){
#pragma unroll
        for (int i = 0; i < 8; i++){
          float v = acc[c][i];
          v += __shfl_xor(v, 8); v += __shfl_xor(v, 16);
          if (ACT) v = elu1(v);
          if (e4 == 0) mb[wid][half][MB(cb * 3 + c, i)] = v;
        }
      }
    }
  } else {
    // ---- rare fallback: process both nodes sequentially with the full wave ----
    for (int k = 0; k < 2; k++){
      const int n = n0 + k;
      const int off = csr_off[n];
      const int cnt = csr_off[n + 1] - off;
      float* mbk = mb[wid][k];
      float v0[8], v1[8];
      float ern[H];
#pragma unroll
      for (int h = 0; h < H; h++) ern[h] = er[n * H + h];
      if (cnt <= 64){
        int p = off + lane;
        int sidx = 0, r = 0;
        if (lane < cnt){ sidx = src_sorted[p]; r = et_sorted[p]; }
        int src0 = __shfl(sidx, 0);
        src_s[wid][lane] = ((lane < cnt) ? sidx : src0) * (H * 384);
        float lg[H];
#pragma unroll
        for (int h = 0; h < H; h++) lg[h] = -1e30f;
        if (lane < cnt){
#pragma unroll
          for (int h = 0; h < H; h++){
            float v = el[sidx * H + h] + ern[h] + ee5[r * H + h];
            lg[h] = (v >= 0.f) ? v : 0.2f * v;
          }
        }
        float ap[4] = {};
        if (MODE > 0 && lane < cnt){
#pragma unroll
          for (int q = 0; q < 4; q++) ap[q] = aprev[(size_t)p * 4 + q];
        }
        float av[H];
#pragma unroll
        for (int h = 0; h < H; h++){
          float mh = wave_max(lg[h]);
          float ex = (lane < cnt) ? __expf(lg[h] - mh) : 0.f;
          float sh = wave_sum(ex);
          float a = ex / sh;
          if (MODE == 1) a = 0.95f * a + 0.05f * ap[h];
          if (MODE == 2) a = 0.95f * a + 0.0125f * (ap[0] + ap[1] + ap[2] + ap[3]);
          av[h] = a;
          a_s[wid][lane][h] = (lane < cnt) ? a : 0.f;
        }
        if constexpr (MODE != 2){
          if (lane < cnt){
            f32x4 o = {av[0], av[1], av[2], av[3]};
            *(f32x4*)(aout + (size_t)p * 4) = o;
          }
        }
        if constexpr (H == 4){
          const int p0 = lane;
          const int p1 = (lane < 32) ? lane + 64 : lane - 32;
          const int p2 = lane + 32;
          const int hA = p0 / 24, hB = p1 / 24, hC = p2 / 24;
          const int eo2 = lane >> 5;
          float acc0[8] = {}, acc1[8] = {}, acc2[8] = {};
          const int cnt4 = (cnt + 3) & ~3;
          for (int b = 0; b < cnt4; b += 4){
            int eB0 = b + eo2, eB1 = b + 2 + eo2;
            int oA0 = src_s[wid][b],     oB0 = src_s[wid][eB0], oC0 = src_s[wid][b + 1];
            int oA1 = src_s[wid][b + 2], oB1 = src_s[wid][eB1], oC1 = src_s[wid][b + 3];
            float aA0 = a_s[wid][b][hA],     aB0 = a_s[wid][eB0][hB], aC0 = a_s[wid][b + 1][hC];
            float aA1 = a_s[wid][b + 2][hA], aB1 = a_s[wid][eB1][hB], aC1 = a_s[wid][b + 3][hC];
            s16x8 fA0 = *(const s16x8*)(fb + oA0 + p0 * 16);
            s16x8 fB0 = *(const s16x8*)(fb + oB0 + p1 * 16);
            s16x8 fC0 = *(const s16x8*)(fb + oC0 + p2 * 16);
            s16x8 fA1 = *(const s16x8*)(fb + oA1 + p0 * 16);
            s16x8 fB1 = *(const s16x8*)(fb + oB1 + p1 * 16);
            s16x8 fC1 = *(const s16x8*)(fb + oC1 + p2 * 16);
#pragma unroll
            for (int i = 0; i < 8; i++){
              acc0[i] += aA0 * bf2f(fA0[i]) + aA1 * bf2f(fA1[i]);
              acc1[i] += aB0 * bf2f(fB0[i]) + aB1 * bf2f(fB1[i]);
              acc2[i] += aC0 * bf2f(fC0[i]) + aC1 * bf2f(fC1[i]);
            }
          }
#pragma unroll
          for (int i = 0; i < 8; i++){
            float x1 = (lane < 32) ? acc2[i] : acc1[i];
            float r1 = __shfl_xor(x1, 32);
            float t0 = acc0[i] + r1;
            v0[i] = ACT ? elu1(t0) : t0;
            float r2 = __shfl_xor(acc2[i], 32);
            if (lane < 32){
              float t1 = acc1[i] + r2;
              v1[i] = ACT ? elu1(t1) : t1;
            }
          }
        } else {
          const int eo = lane & 7, cb = lane >> 3;
          float acc[3][8] = {};
          for (int b = 0; b < cnt; b += 8){
            int e = b + eo;
            float a = a_s[wid][e][0];
            int so = src_s[wid][e];
#pragma unroll
            for (int c = 0; c < 3; c++){
              s16x8 fv = *(const s16x8*)(fb + so + (cb * 3 + c) * 16);
#pragma unroll
              for (int i = 0; i < 8; i++) acc[c][i] += a * bf2f(fv[i]);
            }
          }
#pragma unroll
          for (int c = 0; c < 3; c++){
#pragma unroll
            for (int i = 0; i < 8; i++){
              float v = acc[c][i];
              v += __shfl_xor(v, 1); v += __shfl_xor(v, 2); v += __shfl_xor(v, 4);
              if (ACT) v = elu1(v);
              if (eo == 0) mbk[MB(cb * 3 + c, i)] = v;
            }
          }
        }
      } else {
        // cnt > 64 serial path
        constexpr int NC = H * 192 / 8;
        const int c0 = lane, h0 = (c0 / 24) % H;
        const int c1 = lane + 64, h1 = (c1 / 24) % H;
        const bool act0 = (c0 < NC);
        const bool act1 = (H == 4) && (lane < 32);
        float acc0[8] = {}, acc1[8] = {};
        float mh[H], sh[H];
#pragma unroll
        for (int h = 0; h < H; h++){ mh[h] = -1e30f; sh[h] = 0.f; }
        for (int b = lane; b < cnt; b += 64){
          int pp = off + b; int s = src_sorted[pp]; int r = et_sorted[pp];
#pragma unroll
          for (int h = 0; h < H; h++){
            float v = el[s * H + h] + ern[h] + ee5[r * H + h];
            v = (v >= 0.f) ? v : 0.2f * v;
            mh[h] = fmaxf(mh[h], v);
          }
        }
#pragma unroll
        for (int h = 0; h < H; h++) mh[h] = wave_max(mh[h]);
        for (int b = lane; b < cnt; b += 64){
          int pp = off + b; int s = src_sorted[pp]; int r = et_sorted[pp];
#pragma unroll
          for (int h = 0; h < H; h++){
            float v = el[s * H + h] + ern[h] + ee5[r * H + h];
            v = (v >= 0.f) ? v : 0.2f * v;
            sh[h] += __expf(v - mh[h]);
          }
        }
#pragma unroll
        for (int h = 0; h < H; h++) sh[h] = wave_sum(sh[h]);
        if (MODE != 2){
          for (int b = lane; b < cnt; b += 64){
            int pp = off + b; int s = src_sorted[pp]; int r = et_sorted[pp];
            float ap[4] = {};
            if (MODE > 0){
#pragma unroll
              for (int q = 0; q < 4; q++) ap[q] = aprev[(size_t)pp * 4 + q];
            }
            float av[4] = {};
#pragma unroll
            for (int h = 0; h < H; h++){
              float v = el[s * H + h] + ern[h] + ee5[r * H + h];
              v = (v >= 0.f) ? v : 0.2f * v;
              float a = __expf(v - mh[h]) / sh[h];
              if (MODE == 1) a = 0.95f * a + 0.05f * ap[h];
              av[h] = a;
            }
            f32x4 o = {av[0], av[1], av[2], av[3]};
            *(f32x4*)(aout + (size_t)pp * 4) = o;
          }
        }
        for (int b = 0; b < cnt; b++){
          int pp = off + b; int s = src_sorted[pp]; int r = et_sorted[pp];
          const short* row = featb + (size_t)s * (H * 192);
          float apm[4] = {};
          if (MODE > 0){
#pragma unroll
            for (int q = 0; q < 4; q++) apm[q] = aprev[(size_t)pp * 4 + q];
          }
          if (act0){
            float v = el[s * H + h0] + ern[h0] + ee5[r * H + h0];
            v = (v >= 0.f) ? v : 0.2f * v;
            float a = __expf(v - mh[h0]) / sh[h0];
            if (MODE == 1) a = 0.95f * a + 0.05f * apm[h0];
            if (MODE == 2) a = 0.95f * a + 0.0125f * (apm[0] + apm[1] + apm[2] + apm[3]);
            s16x8 vv = *(const s16x8*)(row + c0 * 8);
#pragma unroll
            for (int i = 0; i < 8; i++) acc0[i] += a * bf2f(vv[i]);
          }
          if (act1){
            float v = el[s * H + h1] + ern[h1] + ee5[r * H + h1];
            v = (v >= 0.f) ? v : 0.2f * v;
            float a = __expf(v - mh[h1]) / sh[h1];
            if (MODE == 1) a = 0.95f * a + 0.05f * apm[h1];
            s16x8 vv = *(const s16x8*)(row + c1 * 8);
#pragma unroll
            for (int i = 0; i < 8; i++) acc1[i] += a * bf2f(vv[i]);
          }
        }
        if constexpr (H == 4){
#pragma unroll
          for (int i = 0; i < 8; i++){
            v0[i] = ACT ? elu1(acc0[i]) : acc0[i];
            if (lane < 32) v1[i] = ACT ? elu1(acc1[i]) : acc1[i];
          }
        } else {
          if (lane < 24){
#pragma unroll
            for (int i = 0; i < 8; i++) mbk[MB(lane, i)] = ACT ? elu1(acc0[i]) : acc0[i];
          }
        }
      }
      // ---- shared H==4 fallback epilogue: outb from regs + mean rounds ----
      if constexpr (H == 4){
        if (outb){
          {
            int c = lane, h = c / 24, rm = c % 24, t = rm >> 3, j = (rm & 7) * 8;
            s16x8 o;
#pragma unroll
            for (int i = 0; i < 8; i++) o[i] = f2bf(v0[i]);
            *(s16x8*)(outb + ((size_t)(t * NPAD) + n) * 256 + h * 64 + j) = o;
          }
          if (lane < 32){
            int c = lane + 64, h = c / 24, rm = c % 24, t = rm >> 3, j = (rm & 7) * 8;
            s16x8 o;
#pragma unroll
            for (int i = 0; i < 8; i++) o[i] = f2bf(v1[i]);
            *(s16x8*)(outb + ((size_t)(t * NPAD) + n) * 256 + h * 64 + j) = o;
          }
        }
        if (lane < 24){
#pragma unroll
          for (int i = 0; i < 8; i++) mbk[MB(lane, i)] = v0[i];
        }
        if (lane >= 24 && lane < 48){
#pragma unroll
          for (int i = 0; i < 8; i++) mbk[MB(lane - 24, i)] += v0[i];
        }
        if (lane >= 48){
#pragma unroll
          for (int i = 0; i < 8; i++) mbk[MB(lane - 48, i)] += v0[i];
        } else if (lane < 8){
#pragma unroll
          for (int i = 0; i < 8; i++) mbk[MB(lane + 16, i)] += v1[i];
        }
        if (lane >= 8 && lane < 32){
#pragma unroll
          for (int i = 0; i < 8; i++) mbk[MB(lane - 8, i)] += v1[i];
        }
      }
    }
  }

  // ---- final per-slot l2 norm from mb (per half-wave, node nme) ----
  const int cb8 = hl >> 3, ib = hl & 7;
  const float* mbh = mb[wid][half];
  for (int t = 0; t < 3; t++){
    float va = mbh[MB(t * 8 + cb8, ib)];
    float vb = mbh[MB(t * 8 + cb8 + 4, ib)];
    if constexpr (H == 4){ va *= 0.25f; vb *= 0.25f; }
    float ss = half_sum(va * va + vb * vb);
    float sc = 1.f / fmaxf(sqrtf(ss), 1e-12f);
    short* ob = o_b + (size_t)nme * 768 + t * 256 + kslice * 64;
    ob[hl] = f2bf(va * sc);
    ob[hl + 32] = f2bf(vb * sc);
  }
}

// ---------------- DistMult via MFMA ----------------
__global__ void distmult_mfma(const short* __restrict__ o_b, const short* __restrict__ Mt,
                              const int* __restrict__ pairs, const int* __restrict__ left,
                              const int* __restrict__ right, const int* __restrict__ mid,
                              float* __restrict__ score){
  const int pt = blockIdx.x, ct = blockIdx.y;
  const int tid = threadIdx.x;
  const int w = tid >> 6, lane = tid & 63;
  const int quad = lane >> 4, ln = lane & 15;
  __shared__ __attribute__((aligned(16))) short smem[8192];
  short* A_s = smem;
  short* B_s = smem + 2048;
  __shared__ int pid_s[64];
  __shared__ int lbase[64];
  if (tid < 64){
    int p = pairs[pt * 64 + tid];
    pid_s[tid] = p;
    lbase[tid] = (p >= 0) ? left[p] * 768 : 0;
  }
  __syncthreads();
  int p0 = pid_s[0];
  if (p0 < 0) return;
  const int r = mid[p0];
  const short* Mr = Mt + (size_t)r * 768 * 768;
  f32x4 acc[8] = {};
  for (int kk = 0; kk < 768; kk += 32){
    {
      int row = tid >> 2, chunk = tid & 3;
      s16x8 v = *(const s16x8*)(o_b + (size_t)lbase[row] + kk + chunk * 8);
      *(s16x8*)(A_s + row * 32 + chunk * 8) = v;
    }
    {
      int row = tid >> 1, half = tid & 1;
      const s16x8* g = (const s16x8*)(Mr + (size_t)(ct * 128 + row) * 768 + kk + half * 16);
      s16x8 v0 = g[0], v1 = g[1];
      *(s16x8*)(B_s + row * 32 + half * 16) = v0;
      *(s16x8*)(B_s + row * 32 + half * 16 + 8) = v1;
    }
    __syncthreads();
    s16x8 af = *(s16x8*)(A_s + (w * 16 + ln) * 32 + quad * 8);
#pragma unroll
    for (int b = 0; b < 8; b++){
      s16x8 bf = *(s16x8*)(B_s + (b * 16 + ln) * 32 + quad * 8);
      acc[b] = __builtin_amdgcn_mfma_f32_16x16x32_bf16(af, bf, acc[b], 0, 0, 0);
    }
    __syncthreads();
  }
  short* RE_s = smem;
  {
    int row = tid >> 2, quarter = tid & 3;
    int p = pid_s[row];
    s16x8 v0 = {}, v1 = {}, v2 = {}, v3 = {};
    if (p >= 0){
      const s16x8* g = (const s16x8*)(o_b + (size_t)right[p] * 768 + ct * 128 + quarter * 32);
      v0 = g[0]; v1 = g[1]; v2 = g[2]; v3 = g[3];
    }
    __syncthreads();
    short* dst = RE_s + row * 128 + quarter * 32;
    *(s16x8*)(dst)      = v0;
    *(s16x8*)(dst + 8)  = v1;
    *(s16x8*)(dst + 16) = v2;
    *(s16x8*)(dst + 24) = v3;
  }
  __syncthreads();
#pragma unroll
  for (int i = 0; i < 4; i++){
    int row = w * 16 + quad * 4 + i;
    float s = 0.f;
#pragma unroll
    for (int b = 0; b < 8; b++)
      s += acc[b][i] * bf2f(RE_s[row * 128 + b * 16 + ln]);
    s += __shfl_xor(s, 1); s += __shfl_xor(s, 2);
    s += __shfl_xor(s, 4); s += __shfl_xor(s, 8);
    if (ln == 0){
      int p = pid_s[row];
      if (p >= 0) atomicAdd(&score[p], s);
    }
  }
}

__global__ void sigmoid_k(const float* __restrict__ score, float* __restrict__ out){
  int i = blockIdx.x * 256 + threadIdx.x;
  if (i < N_PAIRS) out[i] = 1.f / (1.f + __expf(-score[i]));
}

// ---------------- launcher ----------------
extern "C" void kernel_launch(void* const* d_in, const int* in_sizes, int n_in,
                              void* d_out, int out_size, void* d_ws, size_t ws_size,
                              hipStream_t stream){
  const float* f0 = (const float*)d_in[0];
  const float* w0 = (const float*)d_in[1];
  const float* b0 = (const float*)d_in[2];
  const float* f1 = (const float*)d_in[3];
  const float* w1 = (const float*)d_in[4];
  const float* b1 = (const float*)d_in[5];
  const float* f2 = (const float*)d_in[6];
  const float* w2_ = (const float*)d_in[7];
  const float* b2 = (const float*)d_in[8];
  const float* lW[3]  = {(const float*)d_in[9],  (const float*)d_in[15], (const float*)d_in[21]};
  const float* lal[3] = {(const float*)d_in[10], (const float*)d_in[16], (const float*)d_in[22]};
  const float* lar[3] = {(const float*)d_in[11], (const float*)d_in[17], (const float*)d_in[23]};
  const float* lee[3] = {(const float*)d_in[12], (const float*)d_in[18], (const float*)d_in[24]};
  const float* lwe[3] = {(const float*)d_in[13], (const float*)d_in[19], (const float*)d_in[25]};
  const float* lae[3] = {(const float*)d_in[14], (const float*)d_in[20], (const float*)d_in[26]};
  const float* dmW = (const float*)d_in[27];
  const int* efeat = (const int*)d_in[28];
  const int* srcv  = (const int*)d_in[29];
  const int* dstv  = (const int*)d_in[30];
  const int* left  = (const int*)d_in[31];
  const int* right = (const int*)d_in[32];
  const int* midv  = (const int*)d_in[33];
  float* out = (float*)d_out;

  // ---- workspace layout ----
  short* feat_b = (short*)d_ws;               // 15,360,000 shorts
  float* aA     = (float*)(feat_b + 15360000);// 800,000
  float* aB     = aA + 800000;                // 800,000
  float* eall   = aB + 800000;                // 480,000
  float* ee5f   = eall + 480000;              // 96
  float* score  = ee5f + 96;                  // 10,016
  int* cnt3     = (int*)(score + 10016);      // 80,000  (per dst x 4: typed counts)
  int* csr_off  = cnt3 + 80000;               // 20,004
  int* csr_pos  = csr_off + 20004;            // 80,000  (per dst x 4: typed scatter cursors)
  int* loc      = csr_pos + 80000;            // 20,000
  int* bsum     = loc + 20000;                // 128
  int* bofs     = bsum + 128;                 // 128
  int* src_sorted = bofs + 128;               // 200,000
  int* et_sorted  = src_sorted + 200000;      // 200,000
  int* cnt5     = et_sorted + 200000;         // 80
  int* off5     = cnt5 + 80;                  // 8
  int* pos5     = off5 + 8;                   // 80
  int* pairs    = pos5 + 80;                  // 10,368
  short* o_b    = (short*)(pairs + PAIR_PAD); // 15,360,000
  short* Xb0    = o_b + 15360000;             // 3,858,432
  short* Xb12   = Xb0 + 3858432;              // 15,433,728
  short* Wt0    = Xb12 + 15433728;            // 49,152
  short* Wt1    = Wt0 + 49152;                // 196,608
  short* Wt2    = Wt1 + 196608;               // 49,152
  short* Mt     = Wt2 + 49152;                // 2,949,120
  float* elf0 = eall, *erf0 = eall + 80000;
  float* elf1 = eall + 160000, *erf1 = eall + 240000;
  float* elf2 = eall + 320000, *erf2 = eall + 400000;

  build_h<<<2500, 64, 0, stream>>>(f0, w0, b0, f1, w1, b1, f2, w2_, b2, Xb0, o_b,
                                   cnt3, cnt5, pos5, score, pairs, eall, Xb12, feat_b);
  count_prep_k<<<782 + 6336, 256, 0, stream>>>(dstv, srcv, cnt3, midv, cnt5,
                                               lW[0], lW[1], lW[2], dmW, Wt0, Wt1, Wt2, Mt,
                                               lee[0], lwe[0], lae[0], lee[1], lwe[1], lae[1],
                                               lee[2], lwe[2], lae[2], ee5f);
  scan1_k<<<NBLK, 256, 0, stream>>>(cnt3, loc, bsum);
  scan2_k<<<1, 128, 0, stream>>>(bsum, bofs, cnt5, off5);
  scan3_k<<<NBLK, 256, 0, stream>>>(loc, bofs, csr_off, csr_pos, cnt3);
  scatter_k<<<782, 256, 0, stream>>>(dstv, srcv, efeat, csr_pos, src_sorted, et_sorted,
                                     midv, off5, pos5, pairs);

  // layer 0 (H=4, typed proj tiles, typed slot-gather, ELU) -> emb slice 1
  // grid.x = 4 ct * 64-slot groups (per-t tile counts 63/48/48, guarded in-kernel)
  { dim3 g(256, 1, 3);
    mfma_proj<64, 256, 1><<<g, 256, 0, stream>>>(Xb0, Wt0, feat_b, lal[0], lar[0], elf0, erf0); }
  gat_fused<4, 0, 1, 1><<<2500, 256, 0, stream>>>(csr_off, src_sorted, et_sorted, elf0, erf0, ee5f,
                                                  nullptr, aA, feat_b, Xb12, o_b, cnt3, 1);

  // layer 1 (H=4, residual aA, ELU) -> emb slice 2
  // grid.x = 4 ct * 160 (157 tiles padded to 160; XCD-affine swizzle in-kernel)
  { dim3 g(640, 1, 3);
    mfma_proj<256, 256, 0><<<g, 256, 0, stream>>>(Xb12, Wt1, feat_b, lal[1], lar[1], elf1, erf1); }
  gat_fused<4, 1, 1, 0><<<2500, 256, 0, stream>>>(csr_off, src_sorted, et_sorted, elf1, erf1, ee5f + 32,
                                                  aA, aB, feat_b, Xb12, o_b, cnt3, 2);

  // layer 2 (H=1, blend vs mean of a1, no activation) -> emb slice 3
  { dim3 g(157, 1, 3);
    mfma_proj<256, 64, 0><<<g, 256, 0, stream>>>(Xb12, Wt2, feat_b, lal[2], lar[2], elf2, erf2); }
  gat_fused<1, 2, 0, 0><<<2500, 256, 0, stream>>>(csr_off, src_sorted, et_sorted, elf2, erf2, ee5f + 64,
                                                  aB, nullptr, feat_b, nullptr, o_b, cnt3, 3);

  // DistMult + sigmoid
  { dim3 g(DM_TILES, 6); distmult_mfma<<<g, 256, 0, stream>>>(o_b, Mt, pairs, left, right, midv, score); }
  sigmoid_k<<<40, 256, 0, stream>>>(score, out);
}